// Round 1
// baseline (904.330 us; speedup 1.0000x reference)
//
#include <hip/hip_runtime.h>

__device__ __forceinline__ int rfl(int v) { return __builtin_amdgcn_readfirstlane(v); }

__device__ __forceinline__ int lower_bound_dev(const int* __restrict__ a, int n, int v) {
  int lo = 0, hi = n;
  while (lo < hi) { int mid = (lo + hi) >> 1; if (a[mid] < v) lo = mid + 1; else hi = mid; }
  return lo;
}

// ---------------- CSR build ----------------
__global__ void count_kernel(const int* __restrict__ dst, int* __restrict__ counts, int E) {
  int e = blockIdx.x * 256 + threadIdx.x;
  if (e < E) atomicAdd(&counts[dst[e]], 1);
}

__global__ __launch_bounds__(1024) void scan_kernel(const int* __restrict__ counts,
                                                    int* __restrict__ row_ptr,
                                                    int* __restrict__ nextp, int n) {
  __shared__ int part[1024];
  int tid = threadIdx.x;
  int per = (n + 1023) >> 10;
  int s0 = tid * per;
  int s = 0;
  for (int i = s0; i < s0 + per && i < n; i++) s += counts[i];
  part[tid] = s;
  __syncthreads();
  for (int off = 1; off < 1024; off <<= 1) {
    int v = 0;
    if (tid >= off) v = part[tid - off];
    __syncthreads();
    if (tid >= off) part[tid] += v;
    __syncthreads();
  }
  int run = (tid == 0) ? 0 : part[tid - 1];
  for (int i = s0; i < s0 + per && i < n; i++) {
    row_ptr[i] = run; nextp[i] = run; run += counts[i];
  }
  if (tid == 1023) row_ptr[n] = run;
}

__global__ void scatter_kernel(const int* __restrict__ dst, int* __restrict__ nextp,
                               int* __restrict__ perm, int E) {
  int e = blockIdx.x * 256 + threadIdx.x;
  if (e < E) { int p = atomicAdd(&nextp[dst[e]], 1); perm[p] = e; }
}

// ---------------- gate-embedding @ W3 table: [L*NG, 64] ----------------
__global__ void gew_kernel(const float* __restrict__ gate_emb, const float* __restrict__ W_msg,
                           float* __restrict__ geW, int nrows) {
  int tid = threadIdx.x;
  int lane = tid & 63;
  int row = blockIdx.x * 4 + (tid >> 6);
  if (row >= nrows) return;
  int l = row / 20, t = row % 20;
  const float* ge = gate_emb + ((size_t)l * 20 + t) * 16;
  const float* W3 = W_msg + (size_t)l * 88 * 64 + 72 * 64;
  float acc = 0.f;
#pragma unroll
  for (int k = 0; k < 16; k++) acc = fmaf(ge[k], W3[(size_t)k * 64 + lane], acc);
  geW[(size_t)row * 64 + lane] = acc;
}

// ---------------- node embed: h = LN(relu(x@W_embed+b)) ----------------
__global__ __launch_bounds__(256) void embed_kernel(const float* __restrict__ x,
                                                    const float* __restrict__ W,
                                                    const float* __restrict__ b,
                                                    const float* __restrict__ gamma,
                                                    const float* __restrict__ beta,
                                                    float* __restrict__ h, int n_nodes) {
  __shared__ float Ws[16 * 64];
  int tid = threadIdx.x;
  for (int i = tid; i < 16 * 64; i += 256) Ws[i] = W[i];
  __syncthreads();
  int lane = tid & 63;
  int n = blockIdx.x * 4 + (tid >> 6);
  if (n >= n_nodes) return;
  const float* xr = x + (size_t)n * 16;
  float acc = b[lane];
#pragma unroll
  for (int k = 0; k < 16; k++) acc = fmaf(xr[k], Ws[k * 64 + lane], acc);
  acc = fmaxf(acc, 0.f);
  float s = acc;
  for (int o = 32; o; o >>= 1) s += __shfl_xor(s, o);
  float mu = s * (1.f / 64.f);
  float d = acc - mu;
  float v = d * d;
  for (int o = 32; o; o >>= 1) v += __shfl_xor(v, o);
  float r = rsqrtf(v * (1.f / 64.f) + 1e-5f);
  h[(size_t)n * 64 + lane] = d * r * gamma[lane] + beta[lane];
}

// ---------------- tiled GEMM: C[N,64] = A[N,64] @ W[64,64] ----------------
__global__ __launch_bounds__(256) void nodelin_kernel(const float* __restrict__ A,
                                                      const float* __restrict__ W,
                                                      float* __restrict__ C, int n_nodes) {
  __shared__ float As[64 * 64];  // As[k][r]
  __shared__ float Bs[64 * 64];  // Bs[k][j]
  int tid = threadIdx.x;
  int n0 = blockIdx.x * 64;
#pragma unroll
  for (int i = 0; i < 4; i++) {
    int flat = (tid + i * 256) * 4;
    int r = flat >> 6, k = flat & 63;
    float4 f = make_float4(0.f, 0.f, 0.f, 0.f);
    int n = n0 + r;
    if (n < n_nodes) f = *(const float4*)(A + (size_t)n * 64 + k);
    As[(k + 0) * 64 + r] = f.x;
    As[(k + 1) * 64 + r] = f.y;
    As[(k + 2) * 64 + r] = f.z;
    As[(k + 3) * 64 + r] = f.w;
  }
#pragma unroll
  for (int i = 0; i < 4; i++) {
    int flat = (tid + i * 256) * 4;
    *(float4*)&Bs[flat] = *(const float4*)&W[flat];
  }
  __syncthreads();
  int tx = tid & 15, ty = tid >> 4;
  float acc[4][4] = {{0.f}};
#pragma unroll 4
  for (int k = 0; k < 64; k++) {
    float4 a = *(const float4*)&As[k * 64 + ty * 4];
    float4 bb = *(const float4*)&Bs[k * 64 + tx * 4];
    float av[4] = {a.x, a.y, a.z, a.w};
    float bv[4] = {bb.x, bb.y, bb.z, bb.w};
#pragma unroll
    for (int i = 0; i < 4; i++)
#pragma unroll
      for (int j = 0; j < 4; j++) acc[i][j] = fmaf(av[i], bv[j], acc[i][j]);
  }
#pragma unroll
  for (int i = 0; i < 4; i++) {
    int n = n0 + ty * 4 + i;
    if (n < n_nodes) {
      float4 o = make_float4(acc[i][0], acc[i][1], acc[i][2], acc[i][3]);
      *(float4*)&C[(size_t)n * 64 + tx * 4] = o;
    }
  }
}

// ---------------- edge stage: agg[n] = sum_{e in in(n)} relu(hW[src]+ea@W2+geW[t]+b) --------
__global__ __launch_bounds__(256) void edge_kernel(const float* __restrict__ hW,
                                                   const float* __restrict__ edge_attr,
                                                   const int* __restrict__ gt,
                                                   const int* __restrict__ src,
                                                   const int* __restrict__ perm,
                                                   const int* __restrict__ row_ptr,
                                                   const float* __restrict__ W_msg_l,
                                                   const float* __restrict__ b_msg_l,
                                                   const float* __restrict__ geW_l,
                                                   float* __restrict__ agg, int n_nodes) {
  __shared__ float geWs[20 * 64];
  int tid = threadIdx.x;
  for (int i = tid; i < 20 * 64; i += 256) geWs[i] = geW_l[i];
  __syncthreads();
  int lane = tid & 63;
  int n = blockIdx.x * 4 + (tid >> 6);
  if (n >= n_nodes) return;
  float w2[8];
#pragma unroll
  for (int k = 0; k < 8; k++) w2[k] = W_msg_l[(size_t)(64 + k) * 64 + lane];
  float bm = b_msg_l[lane];
  int beg = rfl(row_ptr[n]);
  int end = rfl(row_ptr[n + 1]);
  float acc = 0.f;
  for (int idx = beg; idx < end; idx++) {
    int e = rfl(perm[idx]);
    int s = rfl(src[e]);
    int t = rfl(gt[e]);
    float4 ea0 = *(const float4*)(edge_attr + (size_t)e * 8);
    float4 ea1 = *(const float4*)(edge_attr + (size_t)e * 8 + 4);
    float v = hW[(size_t)s * 64 + lane] + geWs[t * 64 + lane] + bm;
    v = fmaf(ea0.x, w2[0], v); v = fmaf(ea0.y, w2[1], v);
    v = fmaf(ea0.z, w2[2], v); v = fmaf(ea0.w, w2[3], v);
    v = fmaf(ea1.x, w2[4], v); v = fmaf(ea1.y, w2[5], v);
    v = fmaf(ea1.z, w2[6], v); v = fmaf(ea1.w, w2[7], v);
    acc += fmaxf(v, 0.f);
  }
  agg[(size_t)n * 64 + lane] = acc;
}

// ---------------- update: h = h + [h,agg] @ W_upd + b_upd ----------------
__global__ __launch_bounds__(256) void update_kernel(const float* __restrict__ h,
                                                     const float* __restrict__ agg,
                                                     const float* __restrict__ Wu,
                                                     const float* __restrict__ bu,
                                                     float* __restrict__ h_out, int n_nodes) {
  __shared__ float As[128 * 64];  // As[k][r]
  __shared__ float Bs[128 * 64];  // Bs[k][j]
  int tid = threadIdx.x;
  int n0 = blockIdx.x * 64;
#pragma unroll
  for (int i = 0; i < 8; i++) {
    int flat = (tid + i * 256) * 4;
    int r = flat >> 7, k = flat & 127;
    float4 f = make_float4(0.f, 0.f, 0.f, 0.f);
    int n = n0 + r;
    if (n < n_nodes) {
      const float* sp = (k < 64) ? (h + (size_t)n * 64 + k) : (agg + (size_t)n * 64 + (k - 64));
      f = *(const float4*)sp;
    }
    As[(k + 0) * 64 + r] = f.x;
    As[(k + 1) * 64 + r] = f.y;
    As[(k + 2) * 64 + r] = f.z;
    As[(k + 3) * 64 + r] = f.w;
  }
#pragma unroll
  for (int i = 0; i < 8; i++) {
    int flat = (tid + i * 256) * 4;
    *(float4*)&Bs[flat] = *(const float4*)&Wu[flat];
  }
  __syncthreads();
  int tx = tid & 15, ty = tid >> 4;
  float acc[4][4] = {{0.f}};
#pragma unroll 4
  for (int k = 0; k < 128; k++) {
    float4 a = *(const float4*)&As[k * 64 + ty * 4];
    float4 bb = *(const float4*)&Bs[k * 64 + tx * 4];
    float av[4] = {a.x, a.y, a.z, a.w};
    float bv[4] = {bb.x, bb.y, bb.z, bb.w};
#pragma unroll
    for (int i = 0; i < 4; i++)
#pragma unroll
      for (int j = 0; j < 4; j++) acc[i][j] = fmaf(av[i], bv[j], acc[i][j]);
  }
#pragma unroll
  for (int i = 0; i < 4; i++) {
    int n = n0 + ty * 4 + i;
    if (n < n_nodes) {
      float4 hv = *(const float4*)&h[(size_t)n * 64 + tx * 4];
      float4 bv4 = *(const float4*)&bu[tx * 4];
      float4 o;
      o.x = hv.x + acc[i][0] + bv4.x;
      o.y = hv.y + acc[i][1] + bv4.y;
      o.z = hv.z + acc[i][2] + bv4.z;
      o.w = hv.w + acc[i][3] + bv4.w;
      *(float4*)&h_out[(size_t)n * 64 + tx * 4] = o;
    }
  }
}

// ---------------- pooling: mean/max/sum per graph ----------------
__global__ __launch_bounds__(256) void pool_kernel(const float* __restrict__ h,
                                                   const int* __restrict__ batch,
                                                   float* __restrict__ pooled, int n_nodes) {
  int b = blockIdx.x;
  __shared__ int se[2];
  if (threadIdx.x == 0) se[0] = lower_bound_dev(batch, n_nodes, b);
  if (threadIdx.x == 1) se[1] = lower_bound_dev(batch, n_nodes, b + 1);
  __syncthreads();
  int start = se[0], end = se[1];
  int lane = threadIdx.x & 63, wave = threadIdx.x >> 6;
  float s = 0.f, m = -INFINITY;
  for (int i = start + wave; i < end; i += 4) {
    float v = h[(size_t)i * 64 + lane];
    s += v;
    m = fmaxf(m, v);
  }
  __shared__ float ss[4][64], mm[4][64];
  ss[wave][lane] = s;
  mm[wave][lane] = m;
  __syncthreads();
  if (wave == 0) {
    s = ss[0][lane] + ss[1][lane] + ss[2][lane] + ss[3][lane];
    m = fmaxf(fmaxf(mm[0][lane], mm[1][lane]), fmaxf(mm[2][lane], mm[3][lane]));
    int cnt = end - start;
    float mean = (cnt > 0) ? s / (float)cnt : 0.f;
    if (cnt == 0) { m = 0.f; s = 0.f; }
    pooled[(size_t)b * 192 + lane] = mean;
    pooled[(size_t)b * 192 + 64 + lane] = m;
    pooled[(size_t)b * 192 + 128 + lane] = s;
  }
}

// ---------------- head MLP per graph ----------------
__global__ __launch_bounds__(128) void mlp_kernel(
    const float* __restrict__ pooled, const float* __restrict__ glob,
    const float* __restrict__ W_gproj, const float* __restrict__ b_gproj,
    const float* __restrict__ g_gln, const float* __restrict__ b_gln,
    const float* __restrict__ W_c1, const float* __restrict__ b_c1,
    const float* __restrict__ g_cln, const float* __restrict__ b_cln,
    const float* __restrict__ W_c2, const float* __restrict__ b_c2,
    const float* __restrict__ W_head, const float* __restrict__ b_head,
    float* __restrict__ out) {
  int b = blockIdx.x;
  int tid = threadIdx.x;  // 128 threads
  __shared__ float c[256];
  __shared__ float c1s[128];
  __shared__ float c2s[64];
  __shared__ float sred[2][2];
  c[tid] = pooled[(size_t)b * 192 + tid];
  if (tid < 64) c[128 + tid] = pooled[(size_t)b * 192 + 128 + tid];
  if (tid < 64) {
    const float* gf = glob + (size_t)b * 32;
    float acc = b_gproj[tid];
#pragma unroll
    for (int k = 0; k < 32; k++) acc = fmaf(gf[k], W_gproj[(size_t)k * 64 + tid], acc);
    acc = fmaxf(acc, 0.f);
    float s = acc;
    for (int o = 32; o; o >>= 1) s += __shfl_xor(s, o);
    float mu = s * (1.f / 64.f);
    float d = acc - mu;
    float v = d * d;
    for (int o = 32; o; o >>= 1) v += __shfl_xor(v, o);
    float r = rsqrtf(v * (1.f / 64.f) + 1e-5f);
    c[192 + tid] = d * r * g_gln[tid] + b_gln[tid];
  }
  __syncthreads();
  float acc = b_c1[tid];
  for (int k = 0; k < 256; k++) acc = fmaf(c[k], W_c1[(size_t)k * 128 + tid], acc);
  acc = fmaxf(acc, 0.f);
  float s = acc;
  for (int o = 32; o; o >>= 1) s += __shfl_xor(s, o);
  if ((tid & 63) == 0) sred[0][tid >> 6] = s;
  __syncthreads();
  float mu = (sred[0][0] + sred[0][1]) * (1.f / 128.f);
  float d = acc - mu;
  float v = d * d;
  for (int o = 32; o; o >>= 1) v += __shfl_xor(v, o);
  if ((tid & 63) == 0) sred[1][tid >> 6] = v;
  __syncthreads();
  float var = (sred[1][0] + sred[1][1]) * (1.f / 128.f);
  c1s[tid] = d * rsqrtf(var + 1e-5f) * g_cln[tid] + b_cln[tid];
  __syncthreads();
  if (tid < 64) {
    float a2 = b_c2[tid];
    for (int k = 0; k < 128; k++) a2 = fmaf(c1s[k], W_c2[(size_t)k * 64 + tid], a2);
    c2s[tid] = fmaxf(a2, 0.f);
  }
  __syncthreads();
  if (tid < 9) {
    float a3 = b_head[tid];
#pragma unroll
    for (int k = 0; k < 64; k++) a3 = fmaf(c2s[k], W_head[(size_t)k * 9 + tid], a3);
    out[(size_t)b * 9 + tid] = a3;
  }
}

extern "C" void kernel_launch(void* const* d_in, const int* in_sizes, int n_in,
                              void* d_out, int out_size, void* d_ws, size_t ws_size,
                              hipStream_t stream) {
  const float* x       = (const float*)d_in[0];
  const int* edge_index= (const int*)d_in[1];
  const float* edge_attr=(const float*)d_in[2];
  const int* gtype     = (const int*)d_in[3];
  const int* batch     = (const int*)d_in[4];
  const float* glob    = (const float*)d_in[5];
  const float* W_embed = (const float*)d_in[6];
  const float* b_embed = (const float*)d_in[7];
  const float* g_eln   = (const float*)d_in[8];
  const float* b_eln   = (const float*)d_in[9];
  const float* gate_emb= (const float*)d_in[10];
  const float* W_msg   = (const float*)d_in[11];
  const float* b_msg   = (const float*)d_in[12];
  const float* W_upd   = (const float*)d_in[13];
  const float* b_upd   = (const float*)d_in[14];
  const float* W_gproj = (const float*)d_in[15];
  const float* b_gproj = (const float*)d_in[16];
  const float* g_gln   = (const float*)d_in[17];
  const float* b_gln   = (const float*)d_in[18];
  const float* W_c1    = (const float*)d_in[19];
  const float* b_c1    = (const float*)d_in[20];
  const float* g_cln   = (const float*)d_in[21];
  const float* b_cln   = (const float*)d_in[22];
  const float* W_c2    = (const float*)d_in[23];
  const float* b_c2    = (const float*)d_in[24];
  const float* W_head  = (const float*)d_in[25];
  const float* b_head  = (const float*)d_in[26];

  const int N = in_sizes[0] / 16;
  const int E = in_sizes[1] / 2;
  const int B = in_sizes[5] / 32;
  const int L = in_sizes[12] / 64;

  const int* src = edge_index;
  const int* dst = edge_index + E;

  char* ws = (char*)d_ws;
  size_t off = 0;
  auto alloc = [&](size_t bytes) -> void* {
    void* p = ws + off;
    off += (bytes + 255) & ~(size_t)255;
    return p;
  };
  float* h      = (float*)alloc((size_t)N * 64 * 4);
  float* hW     = (float*)alloc((size_t)N * 64 * 4);
  float* agg    = (float*)alloc((size_t)N * 64 * 4);
  float* geW    = (float*)alloc((size_t)L * 20 * 64 * 4);
  float* pooled = (float*)alloc((size_t)B * 192 * 4);
  int* counts   = (int*)alloc((size_t)N * 4);
  int* row_ptr  = (int*)alloc((size_t)(N + 1) * 4);
  int* nextp    = (int*)alloc((size_t)N * 4);
  int* perm     = (int*)alloc((size_t)E * 4);

  hipMemsetAsync(counts, 0, (size_t)N * 4, stream);
  count_kernel<<<(E + 255) / 256, 256, 0, stream>>>(dst, counts, E);
  scan_kernel<<<1, 1024, 0, stream>>>(counts, row_ptr, nextp, N);
  scatter_kernel<<<(E + 255) / 256, 256, 0, stream>>>(dst, nextp, perm, E);
  gew_kernel<<<(L * 20 + 3) / 4, 256, 0, stream>>>(gate_emb, W_msg, geW, L * 20);
  embed_kernel<<<(N + 3) / 4, 256, 0, stream>>>(x, W_embed, b_embed, g_eln, b_eln, h, N);

  for (int l = 0; l < L; l++) {
    nodelin_kernel<<<(N + 63) / 64, 256, 0, stream>>>(h, W_msg + (size_t)l * 88 * 64, hW, N);
    edge_kernel<<<(N + 3) / 4, 256, 0, stream>>>(hW, edge_attr, gtype, src, perm, row_ptr,
                                                 W_msg + (size_t)l * 88 * 64, b_msg + (size_t)l * 64,
                                                 geW + (size_t)l * 20 * 64, agg, N);
    update_kernel<<<(N + 63) / 64, 256, 0, stream>>>(h, agg, W_upd + (size_t)l * 128 * 64,
                                                     b_upd + (size_t)l * 64, h, N);
  }

  pool_kernel<<<B, 256, 0, stream>>>(h, batch, pooled, N);
  mlp_kernel<<<B, 128, 0, stream>>>(pooled, glob, W_gproj, b_gproj, g_gln, b_gln,
                                    W_c1, b_c1, g_cln, b_cln, W_c2, b_c2,
                                    W_head, b_head, (float*)d_out);
}

// Round 2
// 616.414 us; speedup vs baseline: 1.4671x; 1.4671x over previous
//
#include <hip/hip_runtime.h>

__device__ __forceinline__ int rfl(int v) { return __builtin_amdgcn_readfirstlane(v); }

__device__ __forceinline__ int lower_bound_dev(const int* __restrict__ a, int n, int v) {
  int lo = 0, hi = n;
  while (lo < hi) { int mid = (lo + hi) >> 1; if (a[mid] < v) lo = mid + 1; else hi = mid; }
  return lo;
}

// ---------------- CSR build ----------------
__global__ void count_kernel(const int* __restrict__ dst, int* __restrict__ counts, int E) {
  int e = blockIdx.x * 256 + threadIdx.x;
  if (e < E) atomicAdd(&counts[dst[e]], 1);
}

__global__ __launch_bounds__(1024) void scan_kernel(const int* __restrict__ counts,
                                                    int* __restrict__ row_ptr,
                                                    int* __restrict__ nextp, int n) {
  __shared__ int part[1024];
  int tid = threadIdx.x;
  int per = (n + 1023) >> 10;
  int s0 = tid * per;
  int s = 0;
  for (int i = s0; i < s0 + per && i < n; i++) s += counts[i];
  part[tid] = s;
  __syncthreads();
  for (int off = 1; off < 1024; off <<= 1) {
    int v = 0;
    if (tid >= off) v = part[tid - off];
    __syncthreads();
    if (tid >= off) part[tid] += v;
    __syncthreads();
  }
  int run = (tid == 0) ? 0 : part[tid - 1];
  for (int i = s0; i < s0 + per && i < n; i++) {
    row_ptr[i] = run; nextp[i] = run; run += counts[i];
  }
  if (tid == 1023) row_ptr[n] = run;
}

// scatter: build permuted (src,gate) pairs and permuted edge_attr in CSR order
__global__ void scatter_kernel(const int* __restrict__ src, const int* __restrict__ dst,
                               const int* __restrict__ gt, const float* __restrict__ edge_attr,
                               int* __restrict__ nextp, int2* __restrict__ epk,
                               float* __restrict__ eap, int E) {
  int e = blockIdx.x * 256 + threadIdx.x;
  if (e < E) {
    int p = atomicAdd(&nextp[dst[e]], 1);
    epk[p] = make_int2(src[e], gt[e]);
    const float4* s = (const float4*)(edge_attr + (size_t)e * 8);
    float4 a0 = s[0], a1 = s[1];
    float4* d = (float4*)(eap + (size_t)p * 8);
    d[0] = a0; d[1] = a1;
  }
}

// ---------------- gate-embedding @ W3 table: [L*NG, 64] ----------------
__global__ void gew_kernel(const float* __restrict__ gate_emb, const float* __restrict__ W_msg,
                           float* __restrict__ geW, int nrows) {
  int tid = threadIdx.x;
  int lane = tid & 63;
  int row = blockIdx.x * 4 + (tid >> 6);
  if (row >= nrows) return;
  int l = row / 20, t = row % 20;
  const float* ge = gate_emb + ((size_t)l * 20 + t) * 16;
  const float* W3 = W_msg + (size_t)l * 88 * 64 + 72 * 64;
  float acc = 0.f;
#pragma unroll
  for (int k = 0; k < 16; k++) acc = fmaf(ge[k], W3[(size_t)k * 64 + lane], acc);
  geW[(size_t)row * 64 + lane] = acc;
}

// ---------------- node embed: h = LN(relu(x@W_embed+b)) ----------------
__global__ __launch_bounds__(256) void embed_kernel(const float* __restrict__ x,
                                                    const float* __restrict__ W,
                                                    const float* __restrict__ b,
                                                    const float* __restrict__ gamma,
                                                    const float* __restrict__ beta,
                                                    float* __restrict__ h, int n_nodes) {
  __shared__ float Ws[16 * 64];
  int tid = threadIdx.x;
  for (int i = tid; i < 16 * 64; i += 256) Ws[i] = W[i];
  __syncthreads();
  int lane = tid & 63;
  int n = blockIdx.x * 4 + (tid >> 6);
  if (n >= n_nodes) return;
  const float* xr = x + (size_t)n * 16;
  float acc = b[lane];
#pragma unroll
  for (int k = 0; k < 16; k++) acc = fmaf(xr[k], Ws[k * 64 + lane], acc);
  acc = fmaxf(acc, 0.f);
  float s = acc;
  for (int o = 32; o; o >>= 1) s += __shfl_xor(s, o);
  float mu = s * (1.f / 64.f);
  float d = acc - mu;
  float v = d * d;
  for (int o = 32; o; o >>= 1) v += __shfl_xor(v, o);
  float r = rsqrtf(v * (1.f / 64.f) + 1e-5f);
  h[(size_t)n * 64 + lane] = d * r * gamma[lane] + beta[lane];
}

// ---------------- tiled GEMM: C[N,64] = A[N,64] @ W[64,64] (layer 0 hW) ------
__global__ __launch_bounds__(256) void nodelin_kernel(const float* __restrict__ A,
                                                      const float* __restrict__ W,
                                                      float* __restrict__ C, int n_nodes) {
  __shared__ float As[64 * 64];
  __shared__ float Bs[64 * 64];
  int tid = threadIdx.x;
  int n0 = blockIdx.x * 64;
#pragma unroll
  for (int i = 0; i < 4; i++) {
    int flat = (tid + i * 256) * 4;
    int r = flat >> 6, k = flat & 63;
    float4 f = make_float4(0.f, 0.f, 0.f, 0.f);
    int n = n0 + r;
    if (n < n_nodes) f = *(const float4*)(A + (size_t)n * 64 + k);
    As[(k + 0) * 64 + r] = f.x;
    As[(k + 1) * 64 + r] = f.y;
    As[(k + 2) * 64 + r] = f.z;
    As[(k + 3) * 64 + r] = f.w;
  }
#pragma unroll
  for (int i = 0; i < 4; i++) {
    int flat = (tid + i * 256) * 4;
    *(float4*)&Bs[flat] = *(const float4*)&W[flat];
  }
  __syncthreads();
  int tx = tid & 15, ty = tid >> 4;
  float acc[4][4] = {{0.f}};
#pragma unroll 4
  for (int k = 0; k < 64; k++) {
    float4 a = *(const float4*)&As[k * 64 + ty * 4];
    float4 bb = *(const float4*)&Bs[k * 64 + tx * 4];
    float av[4] = {a.x, a.y, a.z, a.w};
    float bv[4] = {bb.x, bb.y, bb.z, bb.w};
#pragma unroll
    for (int i = 0; i < 4; i++)
#pragma unroll
      for (int j = 0; j < 4; j++) acc[i][j] = fmaf(av[i], bv[j], acc[i][j]);
  }
#pragma unroll
  for (int i = 0; i < 4; i++) {
    int n = n0 + ty * 4 + i;
    if (n < n_nodes) {
      float4 o = make_float4(acc[i][0], acc[i][1], acc[i][2], acc[i][3]);
      *(float4*)&C[(size_t)n * 64 + tx * 4] = o;
    }
  }
}

// ---------------- edge stage (ILP-4): agg[n] = sum relu(hW[src]+ea@W2+geW[t]+b) --------
__global__ __launch_bounds__(256) void edge_kernel(const float* __restrict__ hW,
                                                   const int2* __restrict__ epk,
                                                   const float* __restrict__ eap,
                                                   const int* __restrict__ row_ptr,
                                                   const float* __restrict__ W_msg_l,
                                                   const float* __restrict__ b_msg_l,
                                                   const float* __restrict__ geW_l,
                                                   float* __restrict__ agg, int n_nodes) {
  __shared__ float geWs[20 * 64];
  int tid = threadIdx.x;
  for (int i = tid; i < 20 * 64; i += 256) geWs[i] = geW_l[i];
  __syncthreads();
  int lane = tid & 63;
  int n = blockIdx.x * 4 + (tid >> 6);
  if (n >= n_nodes) return;
  float w2[8];
#pragma unroll
  for (int k = 0; k < 8; k++) w2[k] = W_msg_l[(size_t)(64 + k) * 64 + lane];
  float bm = b_msg_l[lane];
  int beg = rfl(row_ptr[n]);
  int end = rfl(row_ptr[n + 1]);
  float acc = 0.f;
  int idx = beg;
  for (; idx + 4 <= end; idx += 4) {
    int2 p0 = epk[idx + 0], p1 = epk[idx + 1], p2 = epk[idx + 2], p3 = epk[idx + 3];
    int s0 = rfl(p0.x), t0 = rfl(p0.y);
    int s1 = rfl(p1.x), t1 = rfl(p1.y);
    int s2 = rfl(p2.x), t2 = rfl(p2.y);
    int s3 = rfl(p3.x), t3 = rfl(p3.y);
    float g0 = hW[(size_t)s0 * 64 + lane];
    float g1 = hW[(size_t)s1 * 64 + lane];
    float g2 = hW[(size_t)s2 * 64 + lane];
    float g3 = hW[(size_t)s3 * 64 + lane];
    const float4* ep = (const float4*)(eap + (size_t)idx * 8);
    float4 a00 = ep[0], a01 = ep[1], a10 = ep[2], a11 = ep[3];
    float4 a20 = ep[4], a21 = ep[5], a30 = ep[6], a31 = ep[7];
    float v0 = g0 + geWs[t0 * 64 + lane] + bm;
    v0 = fmaf(a00.x, w2[0], v0); v0 = fmaf(a00.y, w2[1], v0);
    v0 = fmaf(a00.z, w2[2], v0); v0 = fmaf(a00.w, w2[3], v0);
    v0 = fmaf(a01.x, w2[4], v0); v0 = fmaf(a01.y, w2[5], v0);
    v0 = fmaf(a01.z, w2[6], v0); v0 = fmaf(a01.w, w2[7], v0);
    float v1 = g1 + geWs[t1 * 64 + lane] + bm;
    v1 = fmaf(a10.x, w2[0], v1); v1 = fmaf(a10.y, w2[1], v1);
    v1 = fmaf(a10.z, w2[2], v1); v1 = fmaf(a10.w, w2[3], v1);
    v1 = fmaf(a11.x, w2[4], v1); v1 = fmaf(a11.y, w2[5], v1);
    v1 = fmaf(a11.z, w2[6], v1); v1 = fmaf(a11.w, w2[7], v1);
    float v2 = g2 + geWs[t2 * 64 + lane] + bm;
    v2 = fmaf(a20.x, w2[0], v2); v2 = fmaf(a20.y, w2[1], v2);
    v2 = fmaf(a20.z, w2[2], v2); v2 = fmaf(a20.w, w2[3], v2);
    v2 = fmaf(a21.x, w2[4], v2); v2 = fmaf(a21.y, w2[5], v2);
    v2 = fmaf(a21.z, w2[6], v2); v2 = fmaf(a21.w, w2[7], v2);
    float v3 = g3 + geWs[t3 * 64 + lane] + bm;
    v3 = fmaf(a30.x, w2[0], v3); v3 = fmaf(a30.y, w2[1], v3);
    v3 = fmaf(a30.z, w2[2], v3); v3 = fmaf(a30.w, w2[3], v3);
    v3 = fmaf(a31.x, w2[4], v3); v3 = fmaf(a31.y, w2[5], v3);
    v3 = fmaf(a31.z, w2[6], v3); v3 = fmaf(a31.w, w2[7], v3);
    acc += fmaxf(v0, 0.f) + fmaxf(v1, 0.f) + fmaxf(v2, 0.f) + fmaxf(v3, 0.f);
  }
  for (; idx < end; idx++) {
    int2 p = epk[idx];
    int s = rfl(p.x), t = rfl(p.y);
    float g = hW[(size_t)s * 64 + lane];
    const float4* ep = (const float4*)(eap + (size_t)idx * 8);
    float4 a0 = ep[0], a1 = ep[1];
    float v = g + geWs[t * 64 + lane] + bm;
    v = fmaf(a0.x, w2[0], v); v = fmaf(a0.y, w2[1], v);
    v = fmaf(a0.z, w2[2], v); v = fmaf(a0.w, w2[3], v);
    v = fmaf(a1.x, w2[4], v); v = fmaf(a1.y, w2[5], v);
    v = fmaf(a1.z, w2[6], v); v = fmaf(a1.w, w2[7], v);
    acc += fmaxf(v, 0.f);
  }
  agg[(size_t)n * 64 + lane] = acc;
}

// -------- fused update + next-layer hW: h=h+[h,agg]@Wu+bu ; hW = h@W1next --------
__global__ __launch_bounds__(256) void update_fused_kernel(const float* __restrict__ h,
                                                           const float* __restrict__ agg,
                                                           const float* __restrict__ Wu,
                                                           const float* __restrict__ bu,
                                                           const float* __restrict__ W1next,
                                                           float* __restrict__ h_out,
                                                           float* __restrict__ hW_out,
                                                           int n_nodes) {
  __shared__ float As[128 * 64];  // As[k][r]
  __shared__ float Bs[128 * 64];  // Bs[k][j]
  int tid = threadIdx.x;
  int n0 = blockIdx.x * 64;
#pragma unroll
  for (int i = 0; i < 8; i++) {
    int flat = (tid + i * 256) * 4;
    int r = flat >> 7, k = flat & 127;
    float4 f = make_float4(0.f, 0.f, 0.f, 0.f);
    int n = n0 + r;
    if (n < n_nodes) {
      const float* sp = (k < 64) ? (h + (size_t)n * 64 + k) : (agg + (size_t)n * 64 + (k - 64));
      f = *(const float4*)sp;
    }
    As[(k + 0) * 64 + r] = f.x;
    As[(k + 1) * 64 + r] = f.y;
    As[(k + 2) * 64 + r] = f.z;
    As[(k + 3) * 64 + r] = f.w;
  }
#pragma unroll
  for (int i = 0; i < 8; i++) {
    int flat = (tid + i * 256) * 4;
    *(float4*)&Bs[flat] = *(const float4*)&Wu[flat];
  }
  __syncthreads();
  int tx = tid & 15, ty = tid >> 4;
  float acc[4][4] = {{0.f}};
#pragma unroll 4
  for (int k = 0; k < 128; k++) {
    float4 a = *(const float4*)&As[k * 64 + ty * 4];
    float4 bb = *(const float4*)&Bs[k * 64 + tx * 4];
    float av[4] = {a.x, a.y, a.z, a.w};
    float bv[4] = {bb.x, bb.y, bb.z, bb.w};
#pragma unroll
    for (int i = 0; i < 4; i++)
#pragma unroll
      for (int j = 0; j < 4; j++) acc[i][j] = fmaf(av[i], bv[j], acc[i][j]);
  }
  float hnew[4][4];
  float4 bv4 = *(const float4*)&bu[tx * 4];
#pragma unroll
  for (int i = 0; i < 4; i++) {
    int n = n0 + ty * 4 + i;
    if (n < n_nodes) {
      float4 hv = *(const float4*)&h[(size_t)n * 64 + tx * 4];
      hnew[i][0] = hv.x + acc[i][0] + bv4.x;
      hnew[i][1] = hv.y + acc[i][1] + bv4.y;
      hnew[i][2] = hv.z + acc[i][2] + bv4.z;
      hnew[i][3] = hv.w + acc[i][3] + bv4.w;
      float4 o = make_float4(hnew[i][0], hnew[i][1], hnew[i][2], hnew[i][3]);
      *(float4*)&h_out[(size_t)n * 64 + tx * 4] = o;
    } else {
      hnew[i][0] = hnew[i][1] = hnew[i][2] = hnew[i][3] = 0.f;
    }
  }
  if (W1next) {
    __syncthreads();  // all GEMM1 LDS reads complete
    // stage h_new^T into As[k][r]: k = tx*4+j, r = ty*4+i
#pragma unroll
    for (int i = 0; i < 4; i++)
#pragma unroll
      for (int j = 0; j < 4; j++) As[(tx * 4 + j) * 64 + (ty * 4 + i)] = hnew[i][j];
#pragma unroll
    for (int i = 0; i < 4; i++) {
      int flat = (tid + i * 256) * 4;
      *(float4*)&Bs[flat] = *(const float4*)&W1next[flat];
    }
    __syncthreads();
    float acc2[4][4] = {{0.f}};
#pragma unroll 4
    for (int k = 0; k < 64; k++) {
      float4 a = *(const float4*)&As[k * 64 + ty * 4];
      float4 bb = *(const float4*)&Bs[k * 64 + tx * 4];
      float av[4] = {a.x, a.y, a.z, a.w};
      float bv[4] = {bb.x, bb.y, bb.z, bb.w};
#pragma unroll
      for (int i = 0; i < 4; i++)
#pragma unroll
        for (int j = 0; j < 4; j++) acc2[i][j] = fmaf(av[i], bv[j], acc2[i][j]);
    }
#pragma unroll
    for (int i = 0; i < 4; i++) {
      int n = n0 + ty * 4 + i;
      if (n < n_nodes) {
        float4 o = make_float4(acc2[i][0], acc2[i][1], acc2[i][2], acc2[i][3]);
        *(float4*)&hW_out[(size_t)n * 64 + tx * 4] = o;
      }
    }
  }
}

// ---------------- pooling: mean/max/sum per graph ----------------
__global__ __launch_bounds__(256) void pool_kernel(const float* __restrict__ h,
                                                   const int* __restrict__ batch,
                                                   float* __restrict__ pooled, int n_nodes) {
  int b = blockIdx.x;
  __shared__ int se[2];
  if (threadIdx.x == 0) se[0] = lower_bound_dev(batch, n_nodes, b);
  if (threadIdx.x == 1) se[1] = lower_bound_dev(batch, n_nodes, b + 1);
  __syncthreads();
  int start = se[0], end = se[1];
  int lane = threadIdx.x & 63, wave = threadIdx.x >> 6;
  float s = 0.f, m = -INFINITY;
  for (int i = start + wave; i < end; i += 4) {
    float v = h[(size_t)i * 64 + lane];
    s += v;
    m = fmaxf(m, v);
  }
  __shared__ float ss[4][64], mm[4][64];
  ss[wave][lane] = s;
  mm[wave][lane] = m;
  __syncthreads();
  if (wave == 0) {
    s = ss[0][lane] + ss[1][lane] + ss[2][lane] + ss[3][lane];
    m = fmaxf(fmaxf(mm[0][lane], mm[1][lane]), fmaxf(mm[2][lane], mm[3][lane]));
    int cnt = end - start;
    float mean = (cnt > 0) ? s / (float)cnt : 0.f;
    if (cnt == 0) { m = 0.f; s = 0.f; }
    pooled[(size_t)b * 192 + lane] = mean;
    pooled[(size_t)b * 192 + 64 + lane] = m;
    pooled[(size_t)b * 192 + 128 + lane] = s;
  }
}

// ---------------- head MLP per graph ----------------
__global__ __launch_bounds__(128) void mlp_kernel(
    const float* __restrict__ pooled, const float* __restrict__ glob,
    const float* __restrict__ W_gproj, const float* __restrict__ b_gproj,
    const float* __restrict__ g_gln, const float* __restrict__ b_gln,
    const float* __restrict__ W_c1, const float* __restrict__ b_c1,
    const float* __restrict__ g_cln, const float* __restrict__ b_cln,
    const float* __restrict__ W_c2, const float* __restrict__ b_c2,
    const float* __restrict__ W_head, const float* __restrict__ b_head,
    float* __restrict__ out) {
  int b = blockIdx.x;
  int tid = threadIdx.x;  // 128 threads
  __shared__ float c[256];
  __shared__ float c1s[128];
  __shared__ float c2s[64];
  __shared__ float sred[2][2];
  c[tid] = pooled[(size_t)b * 192 + tid];
  if (tid < 64) c[128 + tid] = pooled[(size_t)b * 192 + 128 + tid];
  if (tid < 64) {
    const float* gf = glob + (size_t)b * 32;
    float acc = b_gproj[tid];
#pragma unroll
    for (int k = 0; k < 32; k++) acc = fmaf(gf[k], W_gproj[(size_t)k * 64 + tid], acc);
    acc = fmaxf(acc, 0.f);
    float s = acc;
    for (int o = 32; o; o >>= 1) s += __shfl_xor(s, o);
    float mu = s * (1.f / 64.f);
    float d = acc - mu;
    float v = d * d;
    for (int o = 32; o; o >>= 1) v += __shfl_xor(v, o);
    float r = rsqrtf(v * (1.f / 64.f) + 1e-5f);
    c[192 + tid] = d * r * g_gln[tid] + b_gln[tid];
  }
  __syncthreads();
  float acc = b_c1[tid];
  for (int k = 0; k < 256; k++) acc = fmaf(c[k], W_c1[(size_t)k * 128 + tid], acc);
  acc = fmaxf(acc, 0.f);
  float s = acc;
  for (int o = 32; o; o >>= 1) s += __shfl_xor(s, o);
  if ((tid & 63) == 0) sred[0][tid >> 6] = s;
  __syncthreads();
  float mu = (sred[0][0] + sred[0][1]) * (1.f / 128.f);
  float d = acc - mu;
  float v = d * d;
  for (int o = 32; o; o >>= 1) v += __shfl_xor(v, o);
  if ((tid & 63) == 0) sred[1][tid >> 6] = v;
  __syncthreads();
  float var = (sred[1][0] + sred[1][1]) * (1.f / 128.f);
  c1s[tid] = d * rsqrtf(var + 1e-5f) * g_cln[tid] + b_cln[tid];
  __syncthreads();
  if (tid < 64) {
    float a2 = b_c2[tid];
    for (int k = 0; k < 128; k++) a2 = fmaf(c1s[k], W_c2[(size_t)k * 64 + tid], a2);
    c2s[tid] = fmaxf(a2, 0.f);
  }
  __syncthreads();
  if (tid < 9) {
    float a3 = b_head[tid];
#pragma unroll
    for (int k = 0; k < 64; k++) a3 = fmaf(c2s[k], W_head[(size_t)k * 9 + tid], a3);
    out[(size_t)b * 9 + tid] = a3;
  }
}

extern "C" void kernel_launch(void* const* d_in, const int* in_sizes, int n_in,
                              void* d_out, int out_size, void* d_ws, size_t ws_size,
                              hipStream_t stream) {
  const float* x       = (const float*)d_in[0];
  const int* edge_index= (const int*)d_in[1];
  const float* edge_attr=(const float*)d_in[2];
  const int* gtype     = (const int*)d_in[3];
  const int* batch     = (const int*)d_in[4];
  const float* glob    = (const float*)d_in[5];
  const float* W_embed = (const float*)d_in[6];
  const float* b_embed = (const float*)d_in[7];
  const float* g_eln   = (const float*)d_in[8];
  const float* b_eln   = (const float*)d_in[9];
  const float* gate_emb= (const float*)d_in[10];
  const float* W_msg   = (const float*)d_in[11];
  const float* b_msg   = (const float*)d_in[12];
  const float* W_upd   = (const float*)d_in[13];
  const float* b_upd   = (const float*)d_in[14];
  const float* W_gproj = (const float*)d_in[15];
  const float* b_gproj = (const float*)d_in[16];
  const float* g_gln   = (const float*)d_in[17];
  const float* b_gln   = (const float*)d_in[18];
  const float* W_c1    = (const float*)d_in[19];
  const float* b_c1    = (const float*)d_in[20];
  const float* g_cln   = (const float*)d_in[21];
  const float* b_cln   = (const float*)d_in[22];
  const float* W_c2    = (const float*)d_in[23];
  const float* b_c2    = (const float*)d_in[24];
  const float* W_head  = (const float*)d_in[25];
  const float* b_head  = (const float*)d_in[26];

  const int N = in_sizes[0] / 16;
  const int E = in_sizes[1] / 2;
  const int B = in_sizes[5] / 32;
  const int L = in_sizes[12] / 64;

  const int* src = edge_index;
  const int* dst = edge_index + E;

  char* ws = (char*)d_ws;
  size_t off = 0;
  auto alloc = [&](size_t bytes) -> void* {
    void* p = ws + off;
    off += (bytes + 255) & ~(size_t)255;
    return p;
  };
  float* h      = (float*)alloc((size_t)N * 64 * 4);
  float* hW     = (float*)alloc((size_t)N * 64 * 4);
  float* agg    = (float*)alloc((size_t)N * 64 * 4);
  float* geW    = (float*)alloc((size_t)L * 20 * 64 * 4);
  float* pooled = (float*)alloc((size_t)B * 192 * 4);
  int* counts   = (int*)alloc((size_t)N * 4);
  int* row_ptr  = (int*)alloc((size_t)(N + 1) * 4);
  int* nextp    = (int*)alloc((size_t)N * 4);
  int2* epk     = (int2*)alloc((size_t)E * 8);
  float* eap    = (float*)alloc((size_t)E * 8 * 4);

  hipMemsetAsync(counts, 0, (size_t)N * 4, stream);
  count_kernel<<<(E + 255) / 256, 256, 0, stream>>>(dst, counts, E);
  scan_kernel<<<1, 1024, 0, stream>>>(counts, row_ptr, nextp, N);
  scatter_kernel<<<(E + 255) / 256, 256, 0, stream>>>(src, dst, gtype, edge_attr,
                                                      nextp, epk, eap, E);
  gew_kernel<<<(L * 20 + 3) / 4, 256, 0, stream>>>(gate_emb, W_msg, geW, L * 20);
  embed_kernel<<<(N + 3) / 4, 256, 0, stream>>>(x, W_embed, b_embed, g_eln, b_eln, h, N);

  nodelin_kernel<<<(N + 63) / 64, 256, 0, stream>>>(h, W_msg, hW, N);
  for (int l = 0; l < L; l++) {
    edge_kernel<<<(N + 3) / 4, 256, 0, stream>>>(hW, epk, eap, row_ptr,
                                                 W_msg + (size_t)l * 88 * 64, b_msg + (size_t)l * 64,
                                                 geW + (size_t)l * 20 * 64, agg, N);
    const float* W1next = (l + 1 < L) ? (W_msg + (size_t)(l + 1) * 88 * 64) : nullptr;
    update_fused_kernel<<<(N + 63) / 64, 256, 0, stream>>>(h, agg, W_upd + (size_t)l * 128 * 64,
                                                           b_upd + (size_t)l * 64, W1next, h, hW, N);
  }

  pool_kernel<<<B, 256, 0, stream>>>(h, batch, pooled, N);
  mlp_kernel<<<B, 128, 0, stream>>>(pooled, glob, W_gproj, b_gproj, g_gln, b_gln,
                                    W_c1, b_c1, g_cln, b_cln, W_c2, b_c2,
                                    W_head, b_head, (float*)d_out);
}

// Round 3
// 517.446 us; speedup vs baseline: 1.7477x; 1.1913x over previous
//
#include <hip/hip_runtime.h>

__device__ __forceinline__ int rfl(int v) { return __builtin_amdgcn_readfirstlane(v); }

__device__ __forceinline__ int lower_bound_dev(const int* __restrict__ a, int n, int v) {
  int lo = 0, hi = n;
  while (lo < hi) { int mid = (lo + hi) >> 1; if (a[mid] < v) lo = mid + 1; else hi = mid; }
  return lo;
}

// ---------------- CSR build ----------------
__global__ void count_kernel(const int* __restrict__ dst, int* __restrict__ counts, int E) {
  int e = blockIdx.x * 256 + threadIdx.x;
  if (e < E) atomicAdd(&counts[dst[e]], 1);
}

// phase1: per-block (1024 elems) exclusive scan + block total
__global__ __launch_bounds__(256) void scan_phase1(const int* __restrict__ counts,
                                                   int* __restrict__ row_ptr,
                                                   int* __restrict__ blocksums, int n) {
  int tid = threadIdx.x;
  int i0 = blockIdx.x * 1024 + tid * 4;
  int4 c = make_int4(0, 0, 0, 0);
  if (i0 + 3 < n) {
    c = *(const int4*)(counts + i0);
  } else {
    if (i0 + 0 < n) c.x = counts[i0 + 0];
    if (i0 + 1 < n) c.y = counts[i0 + 1];
    if (i0 + 2 < n) c.z = counts[i0 + 2];
    if (i0 + 3 < n) c.w = counts[i0 + 3];
  }
  int s = c.x + c.y + c.z + c.w;
  int lane = tid & 63, wave = tid >> 6;
  int v = s;
  for (int o = 1; o < 64; o <<= 1) { int u = __shfl_up(v, o); if (lane >= o) v += u; }
  __shared__ int wsum[4];
  if (lane == 63) wsum[wave] = v;
  __syncthreads();
  int woff = 0;
  for (int w = 0; w < wave; w++) woff += wsum[w];
  int excl = woff + (v - s);
  if (tid == 255) blocksums[blockIdx.x] = woff + v;
  int p0 = excl, p1 = p0 + c.x, p2 = p1 + c.y, p3 = p2 + c.z;
  if (i0 + 3 < n) {
    *(int4*)(row_ptr + i0) = make_int4(p0, p1, p2, p3);
  } else {
    if (i0 + 0 < n) row_ptr[i0 + 0] = p0;
    if (i0 + 1 < n) row_ptr[i0 + 1] = p1;
    if (i0 + 2 < n) row_ptr[i0 + 2] = p2;
    if (i0 + 3 < n) row_ptr[i0 + 3] = p3;
  }
}

// phase2: single-wave exclusive scan of block sums (nb small)
__global__ __launch_bounds__(64) void scan_phase2(int* __restrict__ blocksums, int nb) {
  int carry = 0;
  for (int base = 0; base < nb; base += 64) {
    int i = base + (int)threadIdx.x;
    int v = (i < nb) ? blocksums[i] : 0;
    int inc = v;
    for (int o = 1; o < 64; o <<= 1) { int u = __shfl_up(inc, o); if ((int)threadIdx.x >= o) inc += u; }
    if (i < nb) blocksums[i] = carry + inc - v;
    carry += __shfl(inc, 63);
  }
}

// phase3: add block offsets, produce row_ptr + nextp
__global__ __launch_bounds__(256) void scan_phase3(int* __restrict__ row_ptr,
                                                   const int* __restrict__ blocksums,
                                                   int* __restrict__ nextp, int n, int E) {
  int i = blockIdx.x * 256 + threadIdx.x;
  if (i < n) {
    int v = row_ptr[i] + blocksums[i >> 10];
    row_ptr[i] = v;
    nextp[i] = v;
  }
  if (i == 0) row_ptr[n] = E;
}

// scatter: build permuted (src,gate) pairs and permuted edge_attr in CSR order
__global__ void scatter_kernel(const int* __restrict__ src, const int* __restrict__ dst,
                               const int* __restrict__ gt, const float* __restrict__ edge_attr,
                               int* __restrict__ nextp, int2* __restrict__ epk,
                               float* __restrict__ eap, int E) {
  int e = blockIdx.x * 256 + threadIdx.x;
  if (e < E) {
    int p = atomicAdd(&nextp[dst[e]], 1);
    epk[p] = make_int2(src[e], gt[e]);
    const float4* s = (const float4*)(edge_attr + (size_t)e * 8);
    float4 a0 = s[0], a1 = s[1];
    float4* d = (float4*)(eap + (size_t)p * 8);
    d[0] = a0; d[1] = a1;
  }
}

// ---------------- gate-embedding @ W3 table: [L*NG, 64] ----------------
__global__ void gew_kernel(const float* __restrict__ gate_emb, const float* __restrict__ W_msg,
                           float* __restrict__ geW, int nrows) {
  int tid = threadIdx.x;
  int lane = tid & 63;
  int row = blockIdx.x * 4 + (tid >> 6);
  if (row >= nrows) return;
  int l = row / 20, t = row % 20;
  const float* ge = gate_emb + ((size_t)l * 20 + t) * 16;
  const float* W3 = W_msg + (size_t)l * 88 * 64 + 72 * 64;
  float acc = 0.f;
#pragma unroll
  for (int k = 0; k < 16; k++) acc = fmaf(ge[k], W3[(size_t)k * 64 + lane], acc);
  geW[(size_t)row * 64 + lane] = acc;
}

// ---------------- node embed: h = LN(relu(x@W_embed+b)) ----------------
__global__ __launch_bounds__(256) void embed_kernel(const float* __restrict__ x,
                                                    const float* __restrict__ W,
                                                    const float* __restrict__ b,
                                                    const float* __restrict__ gamma,
                                                    const float* __restrict__ beta,
                                                    float* __restrict__ h, int n_nodes) {
  __shared__ float Ws[16 * 64];
  int tid = threadIdx.x;
  for (int i = tid; i < 16 * 64; i += 256) Ws[i] = W[i];
  __syncthreads();
  int lane = tid & 63;
  int n = blockIdx.x * 4 + (tid >> 6);
  if (n >= n_nodes) return;
  const float* xr = x + (size_t)n * 16;
  float acc = b[lane];
#pragma unroll
  for (int k = 0; k < 16; k++) acc = fmaf(xr[k], Ws[k * 64 + lane], acc);
  acc = fmaxf(acc, 0.f);
  float s = acc;
  for (int o = 32; o; o >>= 1) s += __shfl_xor(s, o);
  float mu = s * (1.f / 64.f);
  float d = acc - mu;
  float v = d * d;
  for (int o = 32; o; o >>= 1) v += __shfl_xor(v, o);
  float r = rsqrtf(v * (1.f / 64.f) + 1e-5f);
  h[(size_t)n * 64 + lane] = d * r * gamma[lane] + beta[lane];
}

// ---------------- tiled GEMM: C[N,64] = A[N,64] @ W[64,64] (layer 0 hW) ------
__global__ __launch_bounds__(256) void nodelin_kernel(const float* __restrict__ A,
                                                      const float* __restrict__ W,
                                                      float* __restrict__ C, int n_nodes) {
  __shared__ float As[64 * 64];
  __shared__ float Bs[64 * 64];
  int tid = threadIdx.x;
  int n0 = blockIdx.x * 64;
#pragma unroll
  for (int i = 0; i < 4; i++) {
    int flat = (tid + i * 256) * 4;
    int r = flat >> 6, k = flat & 63;
    float4 f = make_float4(0.f, 0.f, 0.f, 0.f);
    int n = n0 + r;
    if (n < n_nodes) f = *(const float4*)(A + (size_t)n * 64 + k);
    As[(k + 0) * 64 + r] = f.x;
    As[(k + 1) * 64 + r] = f.y;
    As[(k + 2) * 64 + r] = f.z;
    As[(k + 3) * 64 + r] = f.w;
  }
#pragma unroll
  for (int i = 0; i < 4; i++) {
    int flat = (tid + i * 256) * 4;
    *(float4*)&Bs[flat] = *(const float4*)&W[flat];
  }
  __syncthreads();
  int tx = tid & 15, ty = tid >> 4;
  float acc[4][4] = {{0.f}};
#pragma unroll 4
  for (int k = 0; k < 64; k++) {
    float4 a = *(const float4*)&As[k * 64 + ty * 4];
    float4 bb = *(const float4*)&Bs[k * 64 + tx * 4];
    float av[4] = {a.x, a.y, a.z, a.w};
    float bv[4] = {bb.x, bb.y, bb.z, bb.w};
#pragma unroll
    for (int i = 0; i < 4; i++)
#pragma unroll
      for (int j = 0; j < 4; j++) acc[i][j] = fmaf(av[i], bv[j], acc[i][j]);
  }
#pragma unroll
  for (int i = 0; i < 4; i++) {
    int n = n0 + ty * 4 + i;
    if (n < n_nodes) {
      float4 o = make_float4(acc[i][0], acc[i][1], acc[i][2], acc[i][3]);
      *(float4*)&C[(size_t)n * 64 + tx * 4] = o;
    }
  }
}

// ---------------- edge stage (ILP-4): agg[n] = sum relu(hW[src]+ea@W2+geW[t]+b) --------
__global__ __launch_bounds__(256) void edge_kernel(const float* __restrict__ hW,
                                                   const int2* __restrict__ epk,
                                                   const float* __restrict__ eap,
                                                   const int* __restrict__ row_ptr,
                                                   const float* __restrict__ W_msg_l,
                                                   const float* __restrict__ b_msg_l,
                                                   const float* __restrict__ geW_l,
                                                   float* __restrict__ agg, int n_nodes) {
  __shared__ float geWs[20 * 64];
  int tid = threadIdx.x;
  for (int i = tid; i < 20 * 64; i += 256) geWs[i] = geW_l[i];
  __syncthreads();
  int lane = tid & 63;
  int n = blockIdx.x * 4 + (tid >> 6);
  if (n >= n_nodes) return;
  float w2[8];
#pragma unroll
  for (int k = 0; k < 8; k++) w2[k] = W_msg_l[(size_t)(64 + k) * 64 + lane];
  float bm = b_msg_l[lane];
  int beg = rfl(row_ptr[n]);
  int end = rfl(row_ptr[n + 1]);
  float acc = 0.f;
  int idx = beg;
  for (; idx + 4 <= end; idx += 4) {
    int2 p0 = epk[idx + 0], p1 = epk[idx + 1], p2 = epk[idx + 2], p3 = epk[idx + 3];
    int s0 = rfl(p0.x), t0 = rfl(p0.y);
    int s1 = rfl(p1.x), t1 = rfl(p1.y);
    int s2 = rfl(p2.x), t2 = rfl(p2.y);
    int s3 = rfl(p3.x), t3 = rfl(p3.y);
    float g0 = hW[(size_t)s0 * 64 + lane];
    float g1 = hW[(size_t)s1 * 64 + lane];
    float g2 = hW[(size_t)s2 * 64 + lane];
    float g3 = hW[(size_t)s3 * 64 + lane];
    const float4* ep = (const float4*)(eap + (size_t)idx * 8);
    float4 a00 = ep[0], a01 = ep[1], a10 = ep[2], a11 = ep[3];
    float4 a20 = ep[4], a21 = ep[5], a30 = ep[6], a31 = ep[7];
    float v0 = g0 + geWs[t0 * 64 + lane] + bm;
    v0 = fmaf(a00.x, w2[0], v0); v0 = fmaf(a00.y, w2[1], v0);
    v0 = fmaf(a00.z, w2[2], v0); v0 = fmaf(a00.w, w2[3], v0);
    v0 = fmaf(a01.x, w2[4], v0); v0 = fmaf(a01.y, w2[5], v0);
    v0 = fmaf(a01.z, w2[6], v0); v0 = fmaf(a01.w, w2[7], v0);
    float v1 = g1 + geWs[t1 * 64 + lane] + bm;
    v1 = fmaf(a10.x, w2[0], v1); v1 = fmaf(a10.y, w2[1], v1);
    v1 = fmaf(a10.z, w2[2], v1); v1 = fmaf(a10.w, w2[3], v1);
    v1 = fmaf(a11.x, w2[4], v1); v1 = fmaf(a11.y, w2[5], v1);
    v1 = fmaf(a11.z, w2[6], v1); v1 = fmaf(a11.w, w2[7], v1);
    float v2 = g2 + geWs[t2 * 64 + lane] + bm;
    v2 = fmaf(a20.x, w2[0], v2); v2 = fmaf(a20.y, w2[1], v2);
    v2 = fmaf(a20.z, w2[2], v2); v2 = fmaf(a20.w, w2[3], v2);
    v2 = fmaf(a21.x, w2[4], v2); v2 = fmaf(a21.y, w2[5], v2);
    v2 = fmaf(a21.z, w2[6], v2); v2 = fmaf(a21.w, w2[7], v2);
    float v3 = g3 + geWs[t3 * 64 + lane] + bm;
    v3 = fmaf(a30.x, w2[0], v3); v3 = fmaf(a30.y, w2[1], v3);
    v3 = fmaf(a30.z, w2[2], v3); v3 = fmaf(a30.w, w2[3], v3);
    v3 = fmaf(a31.x, w2[4], v3); v3 = fmaf(a31.y, w2[5], v3);
    v3 = fmaf(a31.z, w2[6], v3); v3 = fmaf(a31.w, w2[7], v3);
    acc += fmaxf(v0, 0.f) + fmaxf(v1, 0.f) + fmaxf(v2, 0.f) + fmaxf(v3, 0.f);
  }
  for (; idx < end; idx++) {
    int2 p = epk[idx];
    int s = rfl(p.x), t = rfl(p.y);
    float g = hW[(size_t)s * 64 + lane];
    const float4* ep = (const float4*)(eap + (size_t)idx * 8);
    float4 a0 = ep[0], a1 = ep[1];
    float v = g + geWs[t * 64 + lane] + bm;
    v = fmaf(a0.x, w2[0], v); v = fmaf(a0.y, w2[1], v);
    v = fmaf(a0.z, w2[2], v); v = fmaf(a0.w, w2[3], v);
    v = fmaf(a1.x, w2[4], v); v = fmaf(a1.y, w2[5], v);
    v = fmaf(a1.z, w2[6], v); v = fmaf(a1.w, w2[7], v);
    acc += fmaxf(v, 0.f);
  }
  agg[(size_t)n * 64 + lane] = acc;
}

// -------- fused update + next-layer hW: h=h+[h,agg]@Wu+bu ; hW = h@W1next --------
__global__ __launch_bounds__(256) void update_fused_kernel(const float* __restrict__ h,
                                                           const float* __restrict__ agg,
                                                           const float* __restrict__ Wu,
                                                           const float* __restrict__ bu,
                                                           const float* __restrict__ W1next,
                                                           float* __restrict__ h_out,
                                                           float* __restrict__ hW_out,
                                                           int n_nodes) {
  __shared__ float As[128 * 64];  // As[k][r]
  __shared__ float Bs[128 * 64];  // Bs[k][j]
  int tid = threadIdx.x;
  int n0 = blockIdx.x * 64;
#pragma unroll
  for (int i = 0; i < 8; i++) {
    int flat = (tid + i * 256) * 4;
    int r = flat >> 7, k = flat & 127;
    float4 f = make_float4(0.f, 0.f, 0.f, 0.f);
    int n = n0 + r;
    if (n < n_nodes) {
      const float* sp = (k < 64) ? (h + (size_t)n * 64 + k) : (agg + (size_t)n * 64 + (k - 64));
      f = *(const float4*)sp;
    }
    As[(k + 0) * 64 + r] = f.x;
    As[(k + 1) * 64 + r] = f.y;
    As[(k + 2) * 64 + r] = f.z;
    As[(k + 3) * 64 + r] = f.w;
  }
#pragma unroll
  for (int i = 0; i < 8; i++) {
    int flat = (tid + i * 256) * 4;
    *(float4*)&Bs[flat] = *(const float4*)&Wu[flat];
  }
  __syncthreads();
  int tx = tid & 15, ty = tid >> 4;
  float acc[4][4] = {{0.f}};
#pragma unroll 4
  for (int k = 0; k < 128; k++) {
    float4 a = *(const float4*)&As[k * 64 + ty * 4];
    float4 bb = *(const float4*)&Bs[k * 64 + tx * 4];
    float av[4] = {a.x, a.y, a.z, a.w};
    float bv[4] = {bb.x, bb.y, bb.z, bb.w};
#pragma unroll
    for (int i = 0; i < 4; i++)
#pragma unroll
      for (int j = 0; j < 4; j++) acc[i][j] = fmaf(av[i], bv[j], acc[i][j]);
  }
  float hnew[4][4];
  float4 bv4 = *(const float4*)&bu[tx * 4];
#pragma unroll
  for (int i = 0; i < 4; i++) {
    int n = n0 + ty * 4 + i;
    if (n < n_nodes) {
      float4 hv = *(const float4*)&h[(size_t)n * 64 + tx * 4];
      hnew[i][0] = hv.x + acc[i][0] + bv4.x;
      hnew[i][1] = hv.y + acc[i][1] + bv4.y;
      hnew[i][2] = hv.z + acc[i][2] + bv4.z;
      hnew[i][3] = hv.w + acc[i][3] + bv4.w;
      float4 o = make_float4(hnew[i][0], hnew[i][1], hnew[i][2], hnew[i][3]);
      *(float4*)&h_out[(size_t)n * 64 + tx * 4] = o;
    } else {
      hnew[i][0] = hnew[i][1] = hnew[i][2] = hnew[i][3] = 0.f;
    }
  }
  if (W1next) {
    __syncthreads();  // all GEMM1 LDS reads complete
#pragma unroll
    for (int i = 0; i < 4; i++)
#pragma unroll
      for (int j = 0; j < 4; j++) As[(tx * 4 + j) * 64 + (ty * 4 + i)] = hnew[i][j];
#pragma unroll
    for (int i = 0; i < 4; i++) {
      int flat = (tid + i * 256) * 4;
      *(float4*)&Bs[flat] = *(const float4*)&W1next[flat];
    }
    __syncthreads();
    float acc2[4][4] = {{0.f}};
#pragma unroll 4
    for (int k = 0; k < 64; k++) {
      float4 a = *(const float4*)&As[k * 64 + ty * 4];
      float4 bb = *(const float4*)&Bs[k * 64 + tx * 4];
      float av[4] = {a.x, a.y, a.z, a.w};
      float bv[4] = {bb.x, bb.y, bb.z, bb.w};
#pragma unroll
      for (int i = 0; i < 4; i++)
#pragma unroll
        for (int j = 0; j < 4; j++) acc2[i][j] = fmaf(av[i], bv[j], acc2[i][j]);
    }
#pragma unroll
    for (int i = 0; i < 4; i++) {
      int n = n0 + ty * 4 + i;
      if (n < n_nodes) {
        float4 o = make_float4(acc2[i][0], acc2[i][1], acc2[i][2], acc2[i][3]);
        *(float4*)&hW_out[(size_t)n * 64 + tx * 4] = o;
      }
    }
  }
}

// ---------------- pooling: mean/max/sum per graph ----------------
__global__ __launch_bounds__(256) void pool_kernel(const float* __restrict__ h,
                                                   const int* __restrict__ batch,
                                                   float* __restrict__ pooled, int n_nodes) {
  int b = blockIdx.x;
  __shared__ int se[2];
  if (threadIdx.x == 0) se[0] = lower_bound_dev(batch, n_nodes, b);
  if (threadIdx.x == 1) se[1] = lower_bound_dev(batch, n_nodes, b + 1);
  __syncthreads();
  int start = se[0], end = se[1];
  int lane = threadIdx.x & 63, wave = threadIdx.x >> 6;
  float s = 0.f, m = -INFINITY;
  for (int i = start + wave; i < end; i += 4) {
    float v = h[(size_t)i * 64 + lane];
    s += v;
    m = fmaxf(m, v);
  }
  __shared__ float ss[4][64], mm[4][64];
  ss[wave][lane] = s;
  mm[wave][lane] = m;
  __syncthreads();
  if (wave == 0) {
    s = ss[0][lane] + ss[1][lane] + ss[2][lane] + ss[3][lane];
    m = fmaxf(fmaxf(mm[0][lane], mm[1][lane]), fmaxf(mm[2][lane], mm[3][lane]));
    int cnt = end - start;
    float mean = (cnt > 0) ? s / (float)cnt : 0.f;
    if (cnt == 0) { m = 0.f; s = 0.f; }
    pooled[(size_t)b * 192 + lane] = mean;
    pooled[(size_t)b * 192 + 64 + lane] = m;
    pooled[(size_t)b * 192 + 128 + lane] = s;
  }
}

// ---------------- head MLP per graph ----------------
__global__ __launch_bounds__(128) void mlp_kernel(
    const float* __restrict__ pooled, const float* __restrict__ glob,
    const float* __restrict__ W_gproj, const float* __restrict__ b_gproj,
    const float* __restrict__ g_gln, const float* __restrict__ b_gln,
    const float* __restrict__ W_c1, const float* __restrict__ b_c1,
    const float* __restrict__ g_cln, const float* __restrict__ b_cln,
    const float* __restrict__ W_c2, const float* __restrict__ b_c2,
    const float* __restrict__ W_head, const float* __restrict__ b_head,
    float* __restrict__ out) {
  int b = blockIdx.x;
  int tid = threadIdx.x;  // 128 threads
  __shared__ float c[256];
  __shared__ float c1s[128];
  __shared__ float c2s[64];
  __shared__ float sred[2][2];
  c[tid] = pooled[(size_t)b * 192 + tid];
  if (tid < 64) c[128 + tid] = pooled[(size_t)b * 192 + 128 + tid];
  if (tid < 64) {
    const float* gf = glob + (size_t)b * 32;
    float acc = b_gproj[tid];
#pragma unroll
    for (int k = 0; k < 32; k++) acc = fmaf(gf[k], W_gproj[(size_t)k * 64 + tid], acc);
    acc = fmaxf(acc, 0.f);
    float s = acc;
    for (int o = 32; o; o >>= 1) s += __shfl_xor(s, o);
    float mu = s * (1.f / 64.f);
    float d = acc - mu;
    float v = d * d;
    for (int o = 32; o; o >>= 1) v += __shfl_xor(v, o);
    float r = rsqrtf(v * (1.f / 64.f) + 1e-5f);
    c[192 + tid] = d * r * g_gln[tid] + b_gln[tid];
  }
  __syncthreads();
  float acc = b_c1[tid];
  for (int k = 0; k < 256; k++) acc = fmaf(c[k], W_c1[(size_t)k * 128 + tid], acc);
  acc = fmaxf(acc, 0.f);
  float s = acc;
  for (int o = 32; o; o >>= 1) s += __shfl_xor(s, o);
  if ((tid & 63) == 0) sred[0][tid >> 6] = s;
  __syncthreads();
  float mu = (sred[0][0] + sred[0][1]) * (1.f / 128.f);
  float d = acc - mu;
  float v = d * d;
  for (int o = 32; o; o >>= 1) v += __shfl_xor(v, o);
  if ((tid & 63) == 0) sred[1][tid >> 6] = v;
  __syncthreads();
  float var = (sred[1][0] + sred[1][1]) * (1.f / 128.f);
  c1s[tid] = d * rsqrtf(var + 1e-5f) * g_cln[tid] + b_cln[tid];
  __syncthreads();
  if (tid < 64) {
    float a2 = b_c2[tid];
    for (int k = 0; k < 128; k++) a2 = fmaf(c1s[k], W_c2[(size_t)k * 64 + tid], a2);
    c2s[tid] = fmaxf(a2, 0.f);
  }
  __syncthreads();
  if (tid < 9) {
    float a3 = b_head[tid];
#pragma unroll
    for (int k = 0; k < 64; k++) a3 = fmaf(c2s[k], W_head[(size_t)k * 9 + tid], a3);
    out[(size_t)b * 9 + tid] = a3;
  }
}

extern "C" void kernel_launch(void* const* d_in, const int* in_sizes, int n_in,
                              void* d_out, int out_size, void* d_ws, size_t ws_size,
                              hipStream_t stream) {
  const float* x       = (const float*)d_in[0];
  const int* edge_index= (const int*)d_in[1];
  const float* edge_attr=(const float*)d_in[2];
  const int* gtype     = (const int*)d_in[3];
  const int* batch     = (const int*)d_in[4];
  const float* glob    = (const float*)d_in[5];
  const float* W_embed = (const float*)d_in[6];
  const float* b_embed = (const float*)d_in[7];
  const float* g_eln   = (const float*)d_in[8];
  const float* b_eln   = (const float*)d_in[9];
  const float* gate_emb= (const float*)d_in[10];
  const float* W_msg   = (const float*)d_in[11];
  const float* b_msg   = (const float*)d_in[12];
  const float* W_upd   = (const float*)d_in[13];
  const float* b_upd   = (const float*)d_in[14];
  const float* W_gproj = (const float*)d_in[15];
  const float* b_gproj = (const float*)d_in[16];
  const float* g_gln   = (const float*)d_in[17];
  const float* b_gln   = (const float*)d_in[18];
  const float* W_c1    = (const float*)d_in[19];
  const float* b_c1    = (const float*)d_in[20];
  const float* g_cln   = (const float*)d_in[21];
  const float* b_cln   = (const float*)d_in[22];
  const float* W_c2    = (const float*)d_in[23];
  const float* b_c2    = (const float*)d_in[24];
  const float* W_head  = (const float*)d_in[25];
  const float* b_head  = (const float*)d_in[26];

  const int N = in_sizes[0] / 16;
  const int E = in_sizes[1] / 2;
  const int B = in_sizes[5] / 32;
  const int L = in_sizes[12] / 64;

  const int* src = edge_index;
  const int* dst = edge_index + E;

  char* ws = (char*)d_ws;
  size_t off = 0;
  auto alloc = [&](size_t bytes) -> void* {
    void* p = ws + off;
    off += (bytes + 255) & ~(size_t)255;
    return p;
  };
  float* h      = (float*)alloc((size_t)N * 64 * 4);
  float* hW     = (float*)alloc((size_t)N * 64 * 4);
  float* agg    = (float*)alloc((size_t)N * 64 * 4);
  float* geW    = (float*)alloc((size_t)L * 20 * 64 * 4);
  float* pooled = (float*)alloc((size_t)B * 192 * 4);
  int* counts   = (int*)alloc((size_t)N * 4);
  int* row_ptr  = (int*)alloc((size_t)(N + 1) * 4);
  int* nextp    = (int*)alloc((size_t)N * 4);
  int nb = (N + 1023) / 1024;
  int* blocksums= (int*)alloc((size_t)nb * 4);
  int2* epk     = (int2*)alloc((size_t)E * 8);
  float* eap    = (float*)alloc((size_t)E * 8 * 4);

  hipMemsetAsync(counts, 0, (size_t)N * 4, stream);
  count_kernel<<<(E + 255) / 256, 256, 0, stream>>>(dst, counts, E);
  scan_phase1<<<nb, 256, 0, stream>>>(counts, row_ptr, blocksums, N);
  scan_phase2<<<1, 64, 0, stream>>>(blocksums, nb);
  scan_phase3<<<(N + 255) / 256, 256, 0, stream>>>(row_ptr, blocksums, nextp, N, E);
  scatter_kernel<<<(E + 255) / 256, 256, 0, stream>>>(src, dst, gtype, edge_attr,
                                                      nextp, epk, eap, E);
  gew_kernel<<<(L * 20 + 3) / 4, 256, 0, stream>>>(gate_emb, W_msg, geW, L * 20);
  embed_kernel<<<(N + 3) / 4, 256, 0, stream>>>(x, W_embed, b_embed, g_eln, b_eln, h, N);

  nodelin_kernel<<<(N + 63) / 64, 256, 0, stream>>>(h, W_msg, hW, N);
  for (int l = 0; l < L; l++) {
    edge_kernel<<<(N + 3) / 4, 256, 0, stream>>>(hW, epk, eap, row_ptr,
                                                 W_msg + (size_t)l * 88 * 64, b_msg + (size_t)l * 64,
                                                 geW + (size_t)l * 20 * 64, agg, N);
    const float* W1next = (l + 1 < L) ? (W_msg + (size_t)(l + 1) * 88 * 64) : nullptr;
    update_fused_kernel<<<(N + 63) / 64, 256, 0, stream>>>(h, agg, W_upd + (size_t)l * 128 * 64,
                                                           b_upd + (size_t)l * 64, W1next, h, hW, N);
  }

  pool_kernel<<<B, 256, 0, stream>>>(h, batch, pooled, N);
  mlp_kernel<<<B, 128, 0, stream>>>(pooled, glob, W_gproj, b_gproj, g_gln, b_gln,
                                    W_c1, b_c1, g_cln, b_cln, W_c2, b_c2,
                                    W_head, b_head, (float*)d_out);
}

// Round 4
// 516.249 us; speedup vs baseline: 1.7517x; 1.0023x over previous
//
#include <hip/hip_runtime.h>

__device__ __forceinline__ int rfl(int v) { return __builtin_amdgcn_readfirstlane(v); }

__device__ __forceinline__ int lower_bound_dev(const int* __restrict__ a, int n, int v) {
  int lo = 0, hi = n;
  while (lo < hi) { int mid = (lo + hi) >> 1; if (a[mid] < v) lo = mid + 1; else hi = mid; }
  return lo;
}

// ---------------- CSR build ----------------
__global__ void count_kernel(const int* __restrict__ dst, int* __restrict__ counts, int E) {
  int e = blockIdx.x * 256 + threadIdx.x;
  if (e < E) atomicAdd(&counts[dst[e]], 1);
}

// phase1: per-block (1024 elems) exclusive scan + block total
__global__ __launch_bounds__(256) void scan_phase1(const int* __restrict__ counts,
                                                   int* __restrict__ row_ptr,
                                                   int* __restrict__ blocksums, int n) {
  int tid = threadIdx.x;
  int i0 = blockIdx.x * 1024 + tid * 4;
  int4 c = make_int4(0, 0, 0, 0);
  if (i0 + 3 < n) {
    c = *(const int4*)(counts + i0);
  } else {
    if (i0 + 0 < n) c.x = counts[i0 + 0];
    if (i0 + 1 < n) c.y = counts[i0 + 1];
    if (i0 + 2 < n) c.z = counts[i0 + 2];
    if (i0 + 3 < n) c.w = counts[i0 + 3];
  }
  int s = c.x + c.y + c.z + c.w;
  int lane = tid & 63, wave = tid >> 6;
  int v = s;
  for (int o = 1; o < 64; o <<= 1) { int u = __shfl_up(v, o); if (lane >= o) v += u; }
  __shared__ int wsum[4];
  if (lane == 63) wsum[wave] = v;
  __syncthreads();
  int woff = 0;
  for (int w = 0; w < wave; w++) woff += wsum[w];
  int excl = woff + (v - s);
  if (tid == 255) blocksums[blockIdx.x] = woff + v;
  int p0 = excl, p1 = p0 + c.x, p2 = p1 + c.y, p3 = p2 + c.z;
  if (i0 + 3 < n) {
    *(int4*)(row_ptr + i0) = make_int4(p0, p1, p2, p3);
  } else {
    if (i0 + 0 < n) row_ptr[i0 + 0] = p0;
    if (i0 + 1 < n) row_ptr[i0 + 1] = p1;
    if (i0 + 2 < n) row_ptr[i0 + 2] = p2;
    if (i0 + 3 < n) row_ptr[i0 + 3] = p3;
  }
}

// phase2: single-wave exclusive scan of block sums (nb small)
__global__ __launch_bounds__(64) void scan_phase2(int* __restrict__ blocksums, int nb) {
  int carry = 0;
  for (int base = 0; base < nb; base += 64) {
    int i = base + (int)threadIdx.x;
    int v = (i < nb) ? blocksums[i] : 0;
    int inc = v;
    for (int o = 1; o < 64; o <<= 1) { int u = __shfl_up(inc, o); if ((int)threadIdx.x >= o) inc += u; }
    if (i < nb) blocksums[i] = carry + inc - v;
    carry += __shfl(inc, 63);
  }
}

// phase3: add block offsets, produce row_ptr + nextp
__global__ __launch_bounds__(256) void scan_phase3(int* __restrict__ row_ptr,
                                                   const int* __restrict__ blocksums,
                                                   int* __restrict__ nextp, int n, int E) {
  int i = blockIdx.x * 256 + threadIdx.x;
  if (i < n) {
    int v = row_ptr[i] + blocksums[i >> 10];
    row_ptr[i] = v;
    nextp[i] = v;
  }
  if (i == 0) row_ptr[n] = E;
}

// pass A: scattered 4B perm writes only (line-mergeable: same-node slots contiguous)
__global__ void scatter_perm(const int* __restrict__ dst, int* __restrict__ nextp,
                             int* __restrict__ perm, int E) {
  int e = blockIdx.x * 256 + threadIdx.x;
  if (e < E) { int p = atomicAdd(&nextp[dst[e]], 1); perm[p] = e; }
}

// pass B: CSR-order gather; all writes sequential/coalesced. epack = (gate<<20)|src.
__global__ void gather_build(const int* __restrict__ perm, const int* __restrict__ src,
                             const int* __restrict__ gt, const float* __restrict__ edge_attr,
                             int* __restrict__ epack, float* __restrict__ eap, int E) {
  int idx = blockIdx.x * 256 + threadIdx.x;
  if (idx < E) {
    int e = perm[idx];
    epack[idx] = (gt[e] << 20) | src[e];
    const float4* s = (const float4*)(edge_attr + (size_t)e * 8);
    float4 a0 = s[0], a1 = s[1];
    float4* d = (float4*)(eap + (size_t)idx * 8);
    d[0] = a0; d[1] = a1;
  }
}

// ---------------- gate-embedding @ W3 table: [L*NG, 64] ----------------
__global__ void gew_kernel(const float* __restrict__ gate_emb, const float* __restrict__ W_msg,
                           float* __restrict__ geW, int nrows) {
  int tid = threadIdx.x;
  int lane = tid & 63;
  int row = blockIdx.x * 4 + (tid >> 6);
  if (row >= nrows) return;
  int l = row / 20, t = row % 20;
  const float* ge = gate_emb + ((size_t)l * 20 + t) * 16;
  const float* W3 = W_msg + (size_t)l * 88 * 64 + 72 * 64;
  float acc = 0.f;
#pragma unroll
  for (int k = 0; k < 16; k++) acc = fmaf(ge[k], W3[(size_t)k * 64 + lane], acc);
  geW[(size_t)row * 64 + lane] = acc;
}

// ---------------- node embed: h = LN(relu(x@W_embed+b)) ----------------
__global__ __launch_bounds__(256) void embed_kernel(const float* __restrict__ x,
                                                    const float* __restrict__ W,
                                                    const float* __restrict__ b,
                                                    const float* __restrict__ gamma,
                                                    const float* __restrict__ beta,
                                                    float* __restrict__ h, int n_nodes) {
  __shared__ float Ws[16 * 64];
  int tid = threadIdx.x;
  for (int i = tid; i < 16 * 64; i += 256) Ws[i] = W[i];
  __syncthreads();
  int lane = tid & 63;
  int n = blockIdx.x * 4 + (tid >> 6);
  if (n >= n_nodes) return;
  const float* xr = x + (size_t)n * 16;
  float acc = b[lane];
#pragma unroll
  for (int k = 0; k < 16; k++) acc = fmaf(xr[k], Ws[k * 64 + lane], acc);
  acc = fmaxf(acc, 0.f);
  float s = acc;
  for (int o = 32; o; o >>= 1) s += __shfl_xor(s, o);
  float mu = s * (1.f / 64.f);
  float d = acc - mu;
  float v = d * d;
  for (int o = 32; o; o >>= 1) v += __shfl_xor(v, o);
  float r = rsqrtf(v * (1.f / 64.f) + 1e-5f);
  h[(size_t)n * 64 + lane] = d * r * gamma[lane] + beta[lane];
}

// ---------------- tiled GEMM: C[N,64] = A[N,64] @ W[64,64] (layer 0 hW) ------
__global__ __launch_bounds__(256) void nodelin_kernel(const float* __restrict__ A,
                                                      const float* __restrict__ W,
                                                      float* __restrict__ C, int n_nodes) {
  __shared__ float As[64 * 64];
  __shared__ float Bs[64 * 64];
  int tid = threadIdx.x;
  int n0 = blockIdx.x * 64;
#pragma unroll
  for (int i = 0; i < 4; i++) {
    int flat = (tid + i * 256) * 4;
    int r = flat >> 6, k = flat & 63;
    float4 f = make_float4(0.f, 0.f, 0.f, 0.f);
    int n = n0 + r;
    if (n < n_nodes) f = *(const float4*)(A + (size_t)n * 64 + k);
    As[(k + 0) * 64 + r] = f.x;
    As[(k + 1) * 64 + r] = f.y;
    As[(k + 2) * 64 + r] = f.z;
    As[(k + 3) * 64 + r] = f.w;
  }
#pragma unroll
  for (int i = 0; i < 4; i++) {
    int flat = (tid + i * 256) * 4;
    *(float4*)&Bs[flat] = *(const float4*)&W[flat];
  }
  __syncthreads();
  int tx = tid & 15, ty = tid >> 4;
  float acc[4][4] = {{0.f}};
#pragma unroll 4
  for (int k = 0; k < 64; k++) {
    float4 a = *(const float4*)&As[k * 64 + ty * 4];
    float4 bb = *(const float4*)&Bs[k * 64 + tx * 4];
    float av[4] = {a.x, a.y, a.z, a.w};
    float bv[4] = {bb.x, bb.y, bb.z, bb.w};
#pragma unroll
    for (int i = 0; i < 4; i++)
#pragma unroll
      for (int j = 0; j < 4; j++) acc[i][j] = fmaf(av[i], bv[j], acc[i][j]);
  }
#pragma unroll
  for (int i = 0; i < 4; i++) {
    int n = n0 + ty * 4 + i;
    if (n < n_nodes) {
      float4 o = make_float4(acc[i][0], acc[i][1], acc[i][2], acc[i][3]);
      *(float4*)&C[(size_t)n * 64 + tx * 4] = o;
    }
  }
}

// -------- edge stage (ILP-4, no LDS): agg[n] = sum relu(hW[src]+ea@W2+geW[t]+b) --------
__global__ __launch_bounds__(256) void edge_kernel(const float* __restrict__ hW,
                                                   const int* __restrict__ epack,
                                                   const float* __restrict__ eap,
                                                   const int* __restrict__ row_ptr,
                                                   const float* __restrict__ W_msg_l,
                                                   const float* __restrict__ b_msg_l,
                                                   const float* __restrict__ geW_l,
                                                   float* __restrict__ agg, int n_nodes) {
  int tid = threadIdx.x;
  int lane = tid & 63;
  int n = blockIdx.x * 4 + (tid >> 6);
  if (n >= n_nodes) return;
  float w2[8];
#pragma unroll
  for (int k = 0; k < 8; k++) w2[k] = W_msg_l[(size_t)(64 + k) * 64 + lane];
  float bm = b_msg_l[lane];
  int beg = rfl(row_ptr[n]);
  int end = rfl(row_ptr[n + 1]);
  float acc = 0.f;
  int idx = beg;
  for (; idx + 4 <= end; idx += 4) {
    int p0 = rfl(epack[idx + 0]);
    int p1 = rfl(epack[idx + 1]);
    int p2 = rfl(epack[idx + 2]);
    int p3 = rfl(epack[idx + 3]);
    int s0 = p0 & 0xFFFFF, t0 = p0 >> 20;
    int s1 = p1 & 0xFFFFF, t1 = p1 >> 20;
    int s2 = p2 & 0xFFFFF, t2 = p2 >> 20;
    int s3 = p3 & 0xFFFFF, t3 = p3 >> 20;
    const float4* ep = (const float4*)(eap + (size_t)idx * 8);
    float4 a00 = ep[0], a01 = ep[1], a10 = ep[2], a11 = ep[3];
    float4 a20 = ep[4], a21 = ep[5], a30 = ep[6], a31 = ep[7];
    float g0 = hW[(size_t)s0 * 64 + lane];
    float g1 = hW[(size_t)s1 * 64 + lane];
    float g2 = hW[(size_t)s2 * 64 + lane];
    float g3 = hW[(size_t)s3 * 64 + lane];
    float e0 = geW_l[t0 * 64 + lane];
    float e1 = geW_l[t1 * 64 + lane];
    float e2 = geW_l[t2 * 64 + lane];
    float e3 = geW_l[t3 * 64 + lane];
    float v0 = g0 + e0 + bm;
    v0 = fmaf(a00.x, w2[0], v0); v0 = fmaf(a00.y, w2[1], v0);
    v0 = fmaf(a00.z, w2[2], v0); v0 = fmaf(a00.w, w2[3], v0);
    v0 = fmaf(a01.x, w2[4], v0); v0 = fmaf(a01.y, w2[5], v0);
    v0 = fmaf(a01.z, w2[6], v0); v0 = fmaf(a01.w, w2[7], v0);
    float v1 = g1 + e1 + bm;
    v1 = fmaf(a10.x, w2[0], v1); v1 = fmaf(a10.y, w2[1], v1);
    v1 = fmaf(a10.z, w2[2], v1); v1 = fmaf(a10.w, w2[3], v1);
    v1 = fmaf(a11.x, w2[4], v1); v1 = fmaf(a11.y, w2[5], v1);
    v1 = fmaf(a11.z, w2[6], v1); v1 = fmaf(a11.w, w2[7], v1);
    float v2 = g2 + e2 + bm;
    v2 = fmaf(a20.x, w2[0], v2); v2 = fmaf(a20.y, w2[1], v2);
    v2 = fmaf(a20.z, w2[2], v2); v2 = fmaf(a20.w, w2[3], v2);
    v2 = fmaf(a21.x, w2[4], v2); v2 = fmaf(a21.y, w2[5], v2);
    v2 = fmaf(a21.z, w2[6], v2); v2 = fmaf(a21.w, w2[7], v2);
    float v3 = g3 + e3 + bm;
    v3 = fmaf(a30.x, w2[0], v3); v3 = fmaf(a30.y, w2[1], v3);
    v3 = fmaf(a30.z, w2[2], v3); v3 = fmaf(a30.w, w2[3], v3);
    v3 = fmaf(a31.x, w2[4], v3); v3 = fmaf(a31.y, w2[5], v3);
    v3 = fmaf(a31.z, w2[6], v3); v3 = fmaf(a31.w, w2[7], v3);
    acc += fmaxf(v0, 0.f) + fmaxf(v1, 0.f) + fmaxf(v2, 0.f) + fmaxf(v3, 0.f);
  }
  for (; idx < end; idx++) {
    int p = rfl(epack[idx]);
    int s = p & 0xFFFFF, t = p >> 20;
    const float4* ep = (const float4*)(eap + (size_t)idx * 8);
    float4 a0 = ep[0], a1 = ep[1];
    float g = hW[(size_t)s * 64 + lane];
    float v = g + geW_l[t * 64 + lane] + bm;
    v = fmaf(a0.x, w2[0], v); v = fmaf(a0.y, w2[1], v);
    v = fmaf(a0.z, w2[2], v); v = fmaf(a0.w, w2[3], v);
    v = fmaf(a1.x, w2[4], v); v = fmaf(a1.y, w2[5], v);
    v = fmaf(a1.z, w2[6], v); v = fmaf(a1.w, w2[7], v);
    acc += fmaxf(v, 0.f);
  }
  agg[(size_t)n * 64 + lane] = acc;
}

// -------- fused update + next-layer hW: h=h+[h,agg]@Wu+bu ; hW = h@W1next --------
__global__ __launch_bounds__(256) void update_fused_kernel(const float* __restrict__ h,
                                                           const float* __restrict__ agg,
                                                           const float* __restrict__ Wu,
                                                           const float* __restrict__ bu,
                                                           const float* __restrict__ W1next,
                                                           float* __restrict__ h_out,
                                                           float* __restrict__ hW_out,
                                                           int n_nodes) {
  __shared__ float As[128 * 64];  // As[k][r]
  __shared__ float Bs[128 * 64];  // Bs[k][j]
  int tid = threadIdx.x;
  int n0 = blockIdx.x * 64;
#pragma unroll
  for (int i = 0; i < 8; i++) {
    int flat = (tid + i * 256) * 4;
    int r = flat >> 7, k = flat & 127;
    float4 f = make_float4(0.f, 0.f, 0.f, 0.f);
    int n = n0 + r;
    if (n < n_nodes) {
      const float* sp = (k < 64) ? (h + (size_t)n * 64 + k) : (agg + (size_t)n * 64 + (k - 64));
      f = *(const float4*)sp;
    }
    As[(k + 0) * 64 + r] = f.x;
    As[(k + 1) * 64 + r] = f.y;
    As[(k + 2) * 64 + r] = f.z;
    As[(k + 3) * 64 + r] = f.w;
  }
#pragma unroll
  for (int i = 0; i < 8; i++) {
    int flat = (tid + i * 256) * 4;
    *(float4*)&Bs[flat] = *(const float4*)&Wu[flat];
  }
  __syncthreads();
  int tx = tid & 15, ty = tid >> 4;
  float acc[4][4] = {{0.f}};
#pragma unroll 4
  for (int k = 0; k < 128; k++) {
    float4 a = *(const float4*)&As[k * 64 + ty * 4];
    float4 bb = *(const float4*)&Bs[k * 64 + tx * 4];
    float av[4] = {a.x, a.y, a.z, a.w};
    float bv[4] = {bb.x, bb.y, bb.z, bb.w};
#pragma unroll
    for (int i = 0; i < 4; i++)
#pragma unroll
      for (int j = 0; j < 4; j++) acc[i][j] = fmaf(av[i], bv[j], acc[i][j]);
  }
  float hnew[4][4];
  float4 bv4 = *(const float4*)&bu[tx * 4];
#pragma unroll
  for (int i = 0; i < 4; i++) {
    int n = n0 + ty * 4 + i;
    if (n < n_nodes) {
      float4 hv = *(const float4*)&h[(size_t)n * 64 + tx * 4];
      hnew[i][0] = hv.x + acc[i][0] + bv4.x;
      hnew[i][1] = hv.y + acc[i][1] + bv4.y;
      hnew[i][2] = hv.z + acc[i][2] + bv4.z;
      hnew[i][3] = hv.w + acc[i][3] + bv4.w;
      float4 o = make_float4(hnew[i][0], hnew[i][1], hnew[i][2], hnew[i][3]);
      *(float4*)&h_out[(size_t)n * 64 + tx * 4] = o;
    } else {
      hnew[i][0] = hnew[i][1] = hnew[i][2] = hnew[i][3] = 0.f;
    }
  }
  if (W1next) {
    __syncthreads();  // all GEMM1 LDS reads complete
#pragma unroll
    for (int i = 0; i < 4; i++)
#pragma unroll
      for (int j = 0; j < 4; j++) As[(tx * 4 + j) * 64 + (ty * 4 + i)] = hnew[i][j];
#pragma unroll
    for (int i = 0; i < 4; i++) {
      int flat = (tid + i * 256) * 4;
      *(float4*)&Bs[flat] = *(const float4*)&W1next[flat];
    }
    __syncthreads();
    float acc2[4][4] = {{0.f}};
#pragma unroll 4
    for (int k = 0; k < 64; k++) {
      float4 a = *(const float4*)&As[k * 64 + ty * 4];
      float4 bb = *(const float4*)&Bs[k * 64 + tx * 4];
      float av[4] = {a.x, a.y, a.z, a.w};
      float bv[4] = {bb.x, bb.y, bb.z, bb.w};
#pragma unroll
      for (int i = 0; i < 4; i++)
#pragma unroll
        for (int j = 0; j < 4; j++) acc2[i][j] = fmaf(av[i], bv[j], acc2[i][j]);
    }
#pragma unroll
    for (int i = 0; i < 4; i++) {
      int n = n0 + ty * 4 + i;
      if (n < n_nodes) {
        float4 o = make_float4(acc2[i][0], acc2[i][1], acc2[i][2], acc2[i][3]);
        *(float4*)&hW_out[(size_t)n * 64 + tx * 4] = o;
      }
    }
  }
}

// ---------------- pooling: mean/max/sum per graph ----------------
__global__ __launch_bounds__(256) void pool_kernel(const float* __restrict__ h,
                                                   const int* __restrict__ batch,
                                                   float* __restrict__ pooled, int n_nodes) {
  int b = blockIdx.x;
  __shared__ int se[2];
  if (threadIdx.x == 0) se[0] = lower_bound_dev(batch, n_nodes, b);
  if (threadIdx.x == 1) se[1] = lower_bound_dev(batch, n_nodes, b + 1);
  __syncthreads();
  int start = se[0], end = se[1];
  int lane = threadIdx.x & 63, wave = threadIdx.x >> 6;
  float s = 0.f, m = -INFINITY;
  for (int i = start + wave; i < end; i += 4) {
    float v = h[(size_t)i * 64 + lane];
    s += v;
    m = fmaxf(m, v);
  }
  __shared__ float ss[4][64], mm[4][64];
  ss[wave][lane] = s;
  mm[wave][lane] = m;
  __syncthreads();
  if (wave == 0) {
    s = ss[0][lane] + ss[1][lane] + ss[2][lane] + ss[3][lane];
    m = fmaxf(fmaxf(mm[0][lane], mm[1][lane]), fmaxf(mm[2][lane], mm[3][lane]));
    int cnt = end - start;
    float mean = (cnt > 0) ? s / (float)cnt : 0.f;
    if (cnt == 0) { m = 0.f; s = 0.f; }
    pooled[(size_t)b * 192 + lane] = mean;
    pooled[(size_t)b * 192 + 64 + lane] = m;
    pooled[(size_t)b * 192 + 128 + lane] = s;
  }
}

// ---------------- head MLP per graph ----------------
__global__ __launch_bounds__(128) void mlp_kernel(
    const float* __restrict__ pooled, const float* __restrict__ glob,
    const float* __restrict__ W_gproj, const float* __restrict__ b_gproj,
    const float* __restrict__ g_gln, const float* __restrict__ b_gln,
    const float* __restrict__ W_c1, const float* __restrict__ b_c1,
    const float* __restrict__ g_cln, const float* __restrict__ b_cln,
    const float* __restrict__ W_c2, const float* __restrict__ b_c2,
    const float* __restrict__ W_head, const float* __restrict__ b_head,
    float* __restrict__ out) {
  int b = blockIdx.x;
  int tid = threadIdx.x;  // 128 threads
  __shared__ float c[256];
  __shared__ float c1s[128];
  __shared__ float c2s[64];
  __shared__ float sred[2][2];
  c[tid] = pooled[(size_t)b * 192 + tid];
  if (tid < 64) c[128 + tid] = pooled[(size_t)b * 192 + 128 + tid];
  if (tid < 64) {
    const float* gf = glob + (size_t)b * 32;
    float acc = b_gproj[tid];
#pragma unroll
    for (int k = 0; k < 32; k++) acc = fmaf(gf[k], W_gproj[(size_t)k * 64 + tid], acc);
    acc = fmaxf(acc, 0.f);
    float s = acc;
    for (int o = 32; o; o >>= 1) s += __shfl_xor(s, o);
    float mu = s * (1.f / 64.f);
    float d = acc - mu;
    float v = d * d;
    for (int o = 32; o; o >>= 1) v += __shfl_xor(v, o);
    float r = rsqrtf(v * (1.f / 64.f) + 1e-5f);
    c[192 + tid] = d * r * g_gln[tid] + b_gln[tid];
  }
  __syncthreads();
  float acc = b_c1[tid];
  for (int k = 0; k < 256; k++) acc = fmaf(c[k], W_c1[(size_t)k * 128 + tid], acc);
  acc = fmaxf(acc, 0.f);
  float s = acc;
  for (int o = 32; o; o >>= 1) s += __shfl_xor(s, o);
  if ((tid & 63) == 0) sred[0][tid >> 6] = s;
  __syncthreads();
  float mu = (sred[0][0] + sred[0][1]) * (1.f / 128.f);
  float d = acc - mu;
  float v = d * d;
  for (int o = 32; o; o >>= 1) v += __shfl_xor(v, o);
  if ((tid & 63) == 0) sred[1][tid >> 6] = v;
  __syncthreads();
  float var = (sred[1][0] + sred[1][1]) * (1.f / 128.f);
  c1s[tid] = d * rsqrtf(var + 1e-5f) * g_cln[tid] + b_cln[tid];
  __syncthreads();
  if (tid < 64) {
    float a2 = b_c2[tid];
    for (int k = 0; k < 128; k++) a2 = fmaf(c1s[k], W_c2[(size_t)k * 64 + tid], a2);
    c2s[tid] = fmaxf(a2, 0.f);
  }
  __syncthreads();
  if (tid < 9) {
    float a3 = b_head[tid];
#pragma unroll
    for (int k = 0; k < 64; k++) a3 = fmaf(c2s[k], W_head[(size_t)k * 9 + tid], a3);
    out[(size_t)b * 9 + tid] = a3;
  }
}

extern "C" void kernel_launch(void* const* d_in, const int* in_sizes, int n_in,
                              void* d_out, int out_size, void* d_ws, size_t ws_size,
                              hipStream_t stream) {
  const float* x       = (const float*)d_in[0];
  const int* edge_index= (const int*)d_in[1];
  const float* edge_attr=(const float*)d_in[2];
  const int* gtype     = (const int*)d_in[3];
  const int* batch     = (const int*)d_in[4];
  const float* glob    = (const float*)d_in[5];
  const float* W_embed = (const float*)d_in[6];
  const float* b_embed = (const float*)d_in[7];
  const float* g_eln   = (const float*)d_in[8];
  const float* b_eln   = (const float*)d_in[9];
  const float* gate_emb= (const float*)d_in[10];
  const float* W_msg   = (const float*)d_in[11];
  const float* b_msg   = (const float*)d_in[12];
  const float* W_upd   = (const float*)d_in[13];
  const float* b_upd   = (const float*)d_in[14];
  const float* W_gproj = (const float*)d_in[15];
  const float* b_gproj = (const float*)d_in[16];
  const float* g_gln   = (const float*)d_in[17];
  const float* b_gln   = (const float*)d_in[18];
  const float* W_c1    = (const float*)d_in[19];
  const float* b_c1    = (const float*)d_in[20];
  const float* g_cln   = (const float*)d_in[21];
  const float* b_cln   = (const float*)d_in[22];
  const float* W_c2    = (const float*)d_in[23];
  const float* b_c2    = (const float*)d_in[24];
  const float* W_head  = (const float*)d_in[25];
  const float* b_head  = (const float*)d_in[26];

  const int N = in_sizes[0] / 16;
  const int E = in_sizes[1] / 2;
  const int B = in_sizes[5] / 32;
  const int L = in_sizes[12] / 64;

  const int* src = edge_index;
  const int* dst = edge_index + E;

  char* ws = (char*)d_ws;
  size_t off = 0;
  auto alloc = [&](size_t bytes) -> void* {
    void* p = ws + off;
    off += (bytes + 255) & ~(size_t)255;
    return p;
  };
  float* h      = (float*)alloc((size_t)N * 64 * 4);
  float* hW     = (float*)alloc((size_t)N * 64 * 4);
  float* agg    = (float*)alloc((size_t)N * 64 * 4);
  float* geW    = (float*)alloc((size_t)L * 20 * 64 * 4);
  float* pooled = (float*)alloc((size_t)B * 192 * 4);
  int* counts   = (int*)alloc((size_t)N * 4);
  int* row_ptr  = (int*)alloc((size_t)(N + 1) * 4);
  int* nextp    = (int*)alloc((size_t)N * 4);
  int nb = (N + 1023) / 1024;
  int* blocksums= (int*)alloc((size_t)nb * 4);
  int* perm     = (int*)alloc((size_t)E * 4);
  int* epack    = (int*)alloc((size_t)E * 4);
  float* eap    = (float*)alloc((size_t)E * 8 * 4);

  hipMemsetAsync(counts, 0, (size_t)N * 4, stream);
  count_kernel<<<(E + 255) / 256, 256, 0, stream>>>(dst, counts, E);
  scan_phase1<<<nb, 256, 0, stream>>>(counts, row_ptr, blocksums, N);
  scan_phase2<<<1, 64, 0, stream>>>(blocksums, nb);
  scan_phase3<<<(N + 255) / 256, 256, 0, stream>>>(row_ptr, blocksums, nextp, N, E);
  scatter_perm<<<(E + 255) / 256, 256, 0, stream>>>(dst, nextp, perm, E);
  gather_build<<<(E + 255) / 256, 256, 0, stream>>>(perm, src, gtype, edge_attr,
                                                    epack, eap, E);
  gew_kernel<<<(L * 20 + 3) / 4, 256, 0, stream>>>(gate_emb, W_msg, geW, L * 20);
  embed_kernel<<<(N + 3) / 4, 256, 0, stream>>>(x, W_embed, b_embed, g_eln, b_eln, h, N);

  nodelin_kernel<<<(N + 63) / 64, 256, 0, stream>>>(h, W_msg, hW, N);
  for (int l = 0; l < L; l++) {
    edge_kernel<<<(N + 3) / 4, 256, 0, stream>>>(hW, epack, eap, row_ptr,
                                                 W_msg + (size_t)l * 88 * 64, b_msg + (size_t)l * 64,
                                                 geW + (size_t)l * 20 * 64, agg, N);
    const float* W1next = (l + 1 < L) ? (W_msg + (size_t)(l + 1) * 88 * 64) : nullptr;
    update_fused_kernel<<<(N + 63) / 64, 256, 0, stream>>>(h, agg, W_upd + (size_t)l * 128 * 64,
                                                           b_upd + (size_t)l * 64, W1next, h, hW, N);
  }

  pool_kernel<<<B, 256, 0, stream>>>(h, batch, pooled, N);
  mlp_kernel<<<B, 128, 0, stream>>>(pooled, glob, W_gproj, b_gproj, g_gln, b_gln,
                                    W_c1, b_c1, g_cln, b_cln, W_c2, b_c2,
                                    W_head, b_head, (float*)d_out);
}

// Round 5
// 497.766 us; speedup vs baseline: 1.8168x; 1.0371x over previous
//
#include <hip/hip_runtime.h>

__device__ __forceinline__ int rfl(int v) { return __builtin_amdgcn_readfirstlane(v); }

__device__ __forceinline__ int lower_bound_dev(const int* __restrict__ a, int n, int v) {
  int lo = 0, hi = n;
  while (lo < hi) { int mid = (lo + hi) >> 1; if (a[mid] < v) lo = mid + 1; else hi = mid; }
  return lo;
}

// ---------------- CSR build ----------------
// count + pack (gate<<20)|src in original edge order (all coalesced)
__global__ void count_pack_kernel(const int* __restrict__ dst, const int* __restrict__ src,
                                  const int* __restrict__ gt, int* __restrict__ counts,
                                  int* __restrict__ epack0, int E) {
  int e = blockIdx.x * 256 + threadIdx.x;
  if (e < E) {
    atomicAdd(&counts[dst[e]], 1);
    epack0[e] = (gt[e] << 20) | src[e];
  }
}

// phase1: per-block (1024 elems) exclusive scan + block total
__global__ __launch_bounds__(256) void scan_phase1(const int* __restrict__ counts,
                                                   int* __restrict__ row_ptr,
                                                   int* __restrict__ blocksums, int n) {
  int tid = threadIdx.x;
  int i0 = blockIdx.x * 1024 + tid * 4;
  int4 c = make_int4(0, 0, 0, 0);
  if (i0 + 3 < n) {
    c = *(const int4*)(counts + i0);
  } else {
    if (i0 + 0 < n) c.x = counts[i0 + 0];
    if (i0 + 1 < n) c.y = counts[i0 + 1];
    if (i0 + 2 < n) c.z = counts[i0 + 2];
    if (i0 + 3 < n) c.w = counts[i0 + 3];
  }
  int s = c.x + c.y + c.z + c.w;
  int lane = tid & 63, wave = tid >> 6;
  int v = s;
  for (int o = 1; o < 64; o <<= 1) { int u = __shfl_up(v, o); if (lane >= o) v += u; }
  __shared__ int wsum[4];
  if (lane == 63) wsum[wave] = v;
  __syncthreads();
  int woff = 0;
  for (int w = 0; w < wave; w++) woff += wsum[w];
  int excl = woff + (v - s);
  if (tid == 255) blocksums[blockIdx.x] = woff + v;
  int p0 = excl, p1 = p0 + c.x, p2 = p1 + c.y, p3 = p2 + c.z;
  if (i0 + 3 < n) {
    *(int4*)(row_ptr + i0) = make_int4(p0, p1, p2, p3);
  } else {
    if (i0 + 0 < n) row_ptr[i0 + 0] = p0;
    if (i0 + 1 < n) row_ptr[i0 + 1] = p1;
    if (i0 + 2 < n) row_ptr[i0 + 2] = p2;
    if (i0 + 3 < n) row_ptr[i0 + 3] = p3;
  }
}

// phase2: single-wave exclusive scan of block sums (nb small)
__global__ __launch_bounds__(64) void scan_phase2(int* __restrict__ blocksums, int nb) {
  int carry = 0;
  for (int base = 0; base < nb; base += 64) {
    int i = base + (int)threadIdx.x;
    int v = (i < nb) ? blocksums[i] : 0;
    int inc = v;
    for (int o = 1; o < 64; o <<= 1) { int u = __shfl_up(inc, o); if ((int)threadIdx.x >= o) inc += u; }
    if (i < nb) blocksums[i] = carry + inc - v;
    carry += __shfl(inc, 63);
  }
}

// phase3: add block offsets, produce row_ptr + nextp
__global__ __launch_bounds__(256) void scan_phase3(int* __restrict__ row_ptr,
                                                   const int* __restrict__ blocksums,
                                                   int* __restrict__ nextp, int n, int E) {
  int i = blockIdx.x * 256 + threadIdx.x;
  if (i < n) {
    int v = row_ptr[i] + blocksums[i >> 10];
    row_ptr[i] = v;
    nextp[i] = v;
  }
  if (i == 0) row_ptr[n] = E;
}

// XCD-binned scatter: 8 dst-range phases; block b handles edge chunk b/8 filtered
// to phase b%8. Round-robin block->XCD dispatch keeps each perm region's writes
// on one XCD's L2 -> full-line write merging (correctness independent of mapping).
#define SP_EDGES_PER_BLOCK 2048
__global__ __launch_bounds__(256) void scatter_perm_binned(const int* __restrict__ dst,
                                                           int* __restrict__ nextp,
                                                           int* __restrict__ perm,
                                                           int E, int n_nodes) {
  int phase = blockIdx.x & 7;
  int chunk = blockIdx.x >> 3;
  int lo = (int)(((long long)phase * n_nodes) >> 3);
  int hi = (int)(((long long)(phase + 1) * n_nodes) >> 3);
  int base = chunk * SP_EDGES_PER_BLOCK + threadIdx.x * 8;
#pragma unroll
  for (int half = 0; half < 2; half++) {
    int b = base + half * 4;
    if (b >= E) break;
    int4 d;
    if (b + 3 < E) {
      d = *(const int4*)(dst + b);
    } else {
      d.x = dst[b];
      d.y = (b + 1 < E) ? dst[b + 1] : -1;
      d.z = (b + 2 < E) ? dst[b + 2] : -1;
      d.w = (b + 3 < E) ? dst[b + 3] : -1;
    }
    if (d.x >= lo && d.x < hi) { int p = atomicAdd(&nextp[d.x], 1); perm[p] = b + 0; }
    if (d.y >= lo && d.y < hi) { int p = atomicAdd(&nextp[d.y], 1); perm[p] = b + 1; }
    if (d.z >= lo && d.z < hi) { int p = atomicAdd(&nextp[d.z], 1); perm[p] = b + 2; }
    if (d.w >= lo && d.w < hi) { int p = atomicAdd(&nextp[d.w], 1); perm[p] = b + 3; }
  }
}

// pass B: CSR-order gather; all writes sequential/coalesced.
__global__ void gather_build(const int* __restrict__ perm, const int* __restrict__ epack0,
                             const float* __restrict__ edge_attr,
                             int* __restrict__ epack, float* __restrict__ eap, int E) {
  int idx = blockIdx.x * 256 + threadIdx.x;
  if (idx < E) {
    int e = perm[idx];
    epack[idx] = epack0[e];
    const float4* s = (const float4*)(edge_attr + (size_t)e * 8);
    float4 a0 = s[0], a1 = s[1];
    float4* d = (float4*)(eap + (size_t)idx * 8);
    d[0] = a0; d[1] = a1;
  }
}

// ---------------- gate-embedding @ W3 table: [L*NG, 64] ----------------
__global__ void gew_kernel(const float* __restrict__ gate_emb, const float* __restrict__ W_msg,
                           float* __restrict__ geW, int nrows) {
  int tid = threadIdx.x;
  int lane = tid & 63;
  int row = blockIdx.x * 4 + (tid >> 6);
  if (row >= nrows) return;
  int l = row / 20, t = row % 20;
  const float* ge = gate_emb + ((size_t)l * 20 + t) * 16;
  const float* W3 = W_msg + (size_t)l * 88 * 64 + 72 * 64;
  float acc = 0.f;
#pragma unroll
  for (int k = 0; k < 16; k++) acc = fmaf(ge[k], W3[(size_t)k * 64 + lane], acc);
  geW[(size_t)row * 64 + lane] = acc;
}

// ---------------- node embed: h = LN(relu(x@W_embed+b)) ----------------
__global__ __launch_bounds__(256) void embed_kernel(const float* __restrict__ x,
                                                    const float* __restrict__ W,
                                                    const float* __restrict__ b,
                                                    const float* __restrict__ gamma,
                                                    const float* __restrict__ beta,
                                                    float* __restrict__ h, int n_nodes) {
  __shared__ float Ws[16 * 64];
  int tid = threadIdx.x;
  for (int i = tid; i < 16 * 64; i += 256) Ws[i] = W[i];
  __syncthreads();
  int lane = tid & 63;
  int n = blockIdx.x * 4 + (tid >> 6);
  if (n >= n_nodes) return;
  const float* xr = x + (size_t)n * 16;
  float acc = b[lane];
#pragma unroll
  for (int k = 0; k < 16; k++) acc = fmaf(xr[k], Ws[k * 64 + lane], acc);
  acc = fmaxf(acc, 0.f);
  float s = acc;
  for (int o = 32; o; o >>= 1) s += __shfl_xor(s, o);
  float mu = s * (1.f / 64.f);
  float d = acc - mu;
  float v = d * d;
  for (int o = 32; o; o >>= 1) v += __shfl_xor(v, o);
  float r = rsqrtf(v * (1.f / 64.f) + 1e-5f);
  h[(size_t)n * 64 + lane] = d * r * gamma[lane] + beta[lane];
}

// ---------------- tiled GEMM: C[N,64] = A[N,64] @ W[64,64] (layer 0 hW) ------
__global__ __launch_bounds__(256) void nodelin_kernel(const float* __restrict__ A,
                                                      const float* __restrict__ W,
                                                      float* __restrict__ C, int n_nodes) {
  __shared__ float As[64 * 64];
  __shared__ float Bs[64 * 64];
  int tid = threadIdx.x;
  int n0 = blockIdx.x * 64;
#pragma unroll
  for (int i = 0; i < 4; i++) {
    int flat = (tid + i * 256) * 4;
    int r = flat >> 6, k = flat & 63;
    float4 f = make_float4(0.f, 0.f, 0.f, 0.f);
    int n = n0 + r;
    if (n < n_nodes) f = *(const float4*)(A + (size_t)n * 64 + k);
    As[(k + 0) * 64 + r] = f.x;
    As[(k + 1) * 64 + r] = f.y;
    As[(k + 2) * 64 + r] = f.z;
    As[(k + 3) * 64 + r] = f.w;
  }
#pragma unroll
  for (int i = 0; i < 4; i++) {
    int flat = (tid + i * 256) * 4;
    *(float4*)&Bs[flat] = *(const float4*)&W[flat];
  }
  __syncthreads();
  int tx = tid & 15, ty = tid >> 4;
  float acc[4][4] = {{0.f}};
#pragma unroll 4
  for (int k = 0; k < 64; k++) {
    float4 a = *(const float4*)&As[k * 64 + ty * 4];
    float4 bb = *(const float4*)&Bs[k * 64 + tx * 4];
    float av[4] = {a.x, a.y, a.z, a.w};
    float bv[4] = {bb.x, bb.y, bb.z, bb.w};
#pragma unroll
    for (int i = 0; i < 4; i++)
#pragma unroll
      for (int j = 0; j < 4; j++) acc[i][j] = fmaf(av[i], bv[j], acc[i][j]);
  }
#pragma unroll
  for (int i = 0; i < 4; i++) {
    int n = n0 + ty * 4 + i;
    if (n < n_nodes) {
      float4 o = make_float4(acc[i][0], acc[i][1], acc[i][2], acc[i][3]);
      *(float4*)&C[(size_t)n * 64 + tx * 4] = o;
    }
  }
}

// -------- edge stage (ILP-4, no LDS): agg[n] = sum relu(hW[src]+ea@W2+geW[t]+b) --------
__global__ __launch_bounds__(256) void edge_kernel(const float* __restrict__ hW,
                                                   const int* __restrict__ epack,
                                                   const float* __restrict__ eap,
                                                   const int* __restrict__ row_ptr,
                                                   const float* __restrict__ W_msg_l,
                                                   const float* __restrict__ b_msg_l,
                                                   const float* __restrict__ geW_l,
                                                   float* __restrict__ agg, int n_nodes) {
  int tid = threadIdx.x;
  int lane = tid & 63;
  int n = blockIdx.x * 4 + (tid >> 6);
  if (n >= n_nodes) return;
  float w2[8];
#pragma unroll
  for (int k = 0; k < 8; k++) w2[k] = W_msg_l[(size_t)(64 + k) * 64 + lane];
  float bm = b_msg_l[lane];
  int beg = rfl(row_ptr[n]);
  int end = rfl(row_ptr[n + 1]);
  float acc = 0.f;
  int idx = beg;
  for (; idx + 4 <= end; idx += 4) {
    int p0 = rfl(epack[idx + 0]);
    int p1 = rfl(epack[idx + 1]);
    int p2 = rfl(epack[idx + 2]);
    int p3 = rfl(epack[idx + 3]);
    int s0 = p0 & 0xFFFFF, t0 = p0 >> 20;
    int s1 = p1 & 0xFFFFF, t1 = p1 >> 20;
    int s2 = p2 & 0xFFFFF, t2 = p2 >> 20;
    int s3 = p3 & 0xFFFFF, t3 = p3 >> 20;
    const float4* ep = (const float4*)(eap + (size_t)idx * 8);
    float4 a00 = ep[0], a01 = ep[1], a10 = ep[2], a11 = ep[3];
    float4 a20 = ep[4], a21 = ep[5], a30 = ep[6], a31 = ep[7];
    float g0 = hW[(size_t)s0 * 64 + lane];
    float g1 = hW[(size_t)s1 * 64 + lane];
    float g2 = hW[(size_t)s2 * 64 + lane];
    float g3 = hW[(size_t)s3 * 64 + lane];
    float e0 = geW_l[t0 * 64 + lane];
    float e1 = geW_l[t1 * 64 + lane];
    float e2 = geW_l[t2 * 64 + lane];
    float e3 = geW_l[t3 * 64 + lane];
    float v0 = g0 + e0 + bm;
    v0 = fmaf(a00.x, w2[0], v0); v0 = fmaf(a00.y, w2[1], v0);
    v0 = fmaf(a00.z, w2[2], v0); v0 = fmaf(a00.w, w2[3], v0);
    v0 = fmaf(a01.x, w2[4], v0); v0 = fmaf(a01.y, w2[5], v0);
    v0 = fmaf(a01.z, w2[6], v0); v0 = fmaf(a01.w, w2[7], v0);
    float v1 = g1 + e1 + bm;
    v1 = fmaf(a10.x, w2[0], v1); v1 = fmaf(a10.y, w2[1], v1);
    v1 = fmaf(a10.z, w2[2], v1); v1 = fmaf(a10.w, w2[3], v1);
    v1 = fmaf(a11.x, w2[4], v1); v1 = fmaf(a11.y, w2[5], v1);
    v1 = fmaf(a11.z, w2[6], v1); v1 = fmaf(a11.w, w2[7], v1);
    float v2 = g2 + e2 + bm;
    v2 = fmaf(a20.x, w2[0], v2); v2 = fmaf(a20.y, w2[1], v2);
    v2 = fmaf(a20.z, w2[2], v2); v2 = fmaf(a20.w, w2[3], v2);
    v2 = fmaf(a21.x, w2[4], v2); v2 = fmaf(a21.y, w2[5], v2);
    v2 = fmaf(a21.z, w2[6], v2); v2 = fmaf(a21.w, w2[7], v2);
    float v3 = g3 + e3 + bm;
    v3 = fmaf(a30.x, w2[0], v3); v3 = fmaf(a30.y, w2[1], v3);
    v3 = fmaf(a30.z, w2[2], v3); v3 = fmaf(a30.w, w2[3], v3);
    v3 = fmaf(a31.x, w2[4], v3); v3 = fmaf(a31.y, w2[5], v3);
    v3 = fmaf(a31.z, w2[6], v3); v3 = fmaf(a31.w, w2[7], v3);
    acc += fmaxf(v0, 0.f) + fmaxf(v1, 0.f) + fmaxf(v2, 0.f) + fmaxf(v3, 0.f);
  }
  for (; idx < end; idx++) {
    int p = rfl(epack[idx]);
    int s = p & 0xFFFFF, t = p >> 20;
    const float4* ep = (const float4*)(eap + (size_t)idx * 8);
    float4 a0 = ep[0], a1 = ep[1];
    float g = hW[(size_t)s * 64 + lane];
    float v = g + geW_l[t * 64 + lane] + bm;
    v = fmaf(a0.x, w2[0], v); v = fmaf(a0.y, w2[1], v);
    v = fmaf(a0.z, w2[2], v); v = fmaf(a0.w, w2[3], v);
    v = fmaf(a1.x, w2[4], v); v = fmaf(a1.y, w2[5], v);
    v = fmaf(a1.z, w2[6], v); v = fmaf(a1.w, w2[7], v);
    acc += fmaxf(v, 0.f);
  }
  agg[(size_t)n * 64 + lane] = acc;
}

// -------- fused update + next-layer hW: h=h+[h,agg]@Wu+bu ; hW = h@W1next --------
__global__ __launch_bounds__(256) void update_fused_kernel(const float* __restrict__ h,
                                                           const float* __restrict__ agg,
                                                           const float* __restrict__ Wu,
                                                           const float* __restrict__ bu,
                                                           const float* __restrict__ W1next,
                                                           float* __restrict__ h_out,
                                                           float* __restrict__ hW_out,
                                                           int n_nodes) {
  __shared__ float As[128 * 64];  // As[k][r]
  __shared__ float Bs[128 * 64];  // Bs[k][j]
  int tid = threadIdx.x;
  int n0 = blockIdx.x * 64;
#pragma unroll
  for (int i = 0; i < 8; i++) {
    int flat = (tid + i * 256) * 4;
    int r = flat >> 7, k = flat & 127;
    float4 f = make_float4(0.f, 0.f, 0.f, 0.f);
    int n = n0 + r;
    if (n < n_nodes) {
      const float* sp = (k < 64) ? (h + (size_t)n * 64 + k) : (agg + (size_t)n * 64 + (k - 64));
      f = *(const float4*)sp;
    }
    As[(k + 0) * 64 + r] = f.x;
    As[(k + 1) * 64 + r] = f.y;
    As[(k + 2) * 64 + r] = f.z;
    As[(k + 3) * 64 + r] = f.w;
  }
#pragma unroll
  for (int i = 0; i < 8; i++) {
    int flat = (tid + i * 256) * 4;
    *(float4*)&Bs[flat] = *(const float4*)&Wu[flat];
  }
  __syncthreads();
  int tx = tid & 15, ty = tid >> 4;
  float acc[4][4] = {{0.f}};
#pragma unroll 4
  for (int k = 0; k < 128; k++) {
    float4 a = *(const float4*)&As[k * 64 + ty * 4];
    float4 bb = *(const float4*)&Bs[k * 64 + tx * 4];
    float av[4] = {a.x, a.y, a.z, a.w};
    float bv[4] = {bb.x, bb.y, bb.z, bb.w};
#pragma unroll
    for (int i = 0; i < 4; i++)
#pragma unroll
      for (int j = 0; j < 4; j++) acc[i][j] = fmaf(av[i], bv[j], acc[i][j]);
  }
  float hnew[4][4];
  float4 bv4 = *(const float4*)&bu[tx * 4];
#pragma unroll
  for (int i = 0; i < 4; i++) {
    int n = n0 + ty * 4 + i;
    if (n < n_nodes) {
      float4 hv = *(const float4*)&h[(size_t)n * 64 + tx * 4];
      hnew[i][0] = hv.x + acc[i][0] + bv4.x;
      hnew[i][1] = hv.y + acc[i][1] + bv4.y;
      hnew[i][2] = hv.z + acc[i][2] + bv4.z;
      hnew[i][3] = hv.w + acc[i][3] + bv4.w;
      float4 o = make_float4(hnew[i][0], hnew[i][1], hnew[i][2], hnew[i][3]);
      *(float4*)&h_out[(size_t)n * 64 + tx * 4] = o;
    } else {
      hnew[i][0] = hnew[i][1] = hnew[i][2] = hnew[i][3] = 0.f;
    }
  }
  if (W1next) {
    __syncthreads();  // all GEMM1 LDS reads complete
#pragma unroll
    for (int i = 0; i < 4; i++)
#pragma unroll
      for (int j = 0; j < 4; j++) As[(tx * 4 + j) * 64 + (ty * 4 + i)] = hnew[i][j];
#pragma unroll
    for (int i = 0; i < 4; i++) {
      int flat = (tid + i * 256) * 4;
      *(float4*)&Bs[flat] = *(const float4*)&W1next[flat];
    }
    __syncthreads();
    float acc2[4][4] = {{0.f}};
#pragma unroll 4
    for (int k = 0; k < 64; k++) {
      float4 a = *(const float4*)&As[k * 64 + ty * 4];
      float4 bb = *(const float4*)&Bs[k * 64 + tx * 4];
      float av[4] = {a.x, a.y, a.z, a.w};
      float bv[4] = {bb.x, bb.y, bb.z, bb.w};
#pragma unroll
      for (int i = 0; i < 4; i++)
#pragma unroll
        for (int j = 0; j < 4; j++) acc2[i][j] = fmaf(av[i], bv[j], acc2[i][j]);
    }
#pragma unroll
    for (int i = 0; i < 4; i++) {
      int n = n0 + ty * 4 + i;
      if (n < n_nodes) {
        float4 o = make_float4(acc2[i][0], acc2[i][1], acc2[i][2], acc2[i][3]);
        *(float4*)&hW_out[(size_t)n * 64 + tx * 4] = o;
      }
    }
  }
}

// ---------------- pooling: mean/max/sum per graph ----------------
__global__ __launch_bounds__(256) void pool_kernel(const float* __restrict__ h,
                                                   const int* __restrict__ batch,
                                                   float* __restrict__ pooled, int n_nodes) {
  int b = blockIdx.x;
  __shared__ int se[2];
  if (threadIdx.x == 0) se[0] = lower_bound_dev(batch, n_nodes, b);
  if (threadIdx.x == 1) se[1] = lower_bound_dev(batch, n_nodes, b + 1);
  __syncthreads();
  int start = se[0], end = se[1];
  int lane = threadIdx.x & 63, wave = threadIdx.x >> 6;
  float s = 0.f, m = -INFINITY;
  for (int i = start + wave; i < end; i += 4) {
    float v = h[(size_t)i * 64 + lane];
    s += v;
    m = fmaxf(m, v);
  }
  __shared__ float ss[4][64], mm[4][64];
  ss[wave][lane] = s;
  mm[wave][lane] = m;
  __syncthreads();
  if (wave == 0) {
    s = ss[0][lane] + ss[1][lane] + ss[2][lane] + ss[3][lane];
    m = fmaxf(fmaxf(mm[0][lane], mm[1][lane]), fmaxf(mm[2][lane], mm[3][lane]));
    int cnt = end - start;
    float mean = (cnt > 0) ? s / (float)cnt : 0.f;
    if (cnt == 0) { m = 0.f; s = 0.f; }
    pooled[(size_t)b * 192 + lane] = mean;
    pooled[(size_t)b * 192 + 64 + lane] = m;
    pooled[(size_t)b * 192 + 128 + lane] = s;
  }
}

// ---------------- head MLP per graph ----------------
__global__ __launch_bounds__(128) void mlp_kernel(
    const float* __restrict__ pooled, const float* __restrict__ glob,
    const float* __restrict__ W_gproj, const float* __restrict__ b_gproj,
    const float* __restrict__ g_gln, const float* __restrict__ b_gln,
    const float* __restrict__ W_c1, const float* __restrict__ b_c1,
    const float* __restrict__ g_cln, const float* __restrict__ b_cln,
    const float* __restrict__ W_c2, const float* __restrict__ b_c2,
    const float* __restrict__ W_head, const float* __restrict__ b_head,
    float* __restrict__ out) {
  int b = blockIdx.x;
  int tid = threadIdx.x;  // 128 threads
  __shared__ float c[256];
  __shared__ float c1s[128];
  __shared__ float c2s[64];
  __shared__ float sred[2][2];
  c[tid] = pooled[(size_t)b * 192 + tid];
  if (tid < 64) c[128 + tid] = pooled[(size_t)b * 192 + 128 + tid];
  if (tid < 64) {
    const float* gf = glob + (size_t)b * 32;
    float acc = b_gproj[tid];
#pragma unroll
    for (int k = 0; k < 32; k++) acc = fmaf(gf[k], W_gproj[(size_t)k * 64 + tid], acc);
    acc = fmaxf(acc, 0.f);
    float s = acc;
    for (int o = 32; o; o >>= 1) s += __shfl_xor(s, o);
    float mu = s * (1.f / 64.f);
    float d = acc - mu;
    float v = d * d;
    for (int o = 32; o; o >>= 1) v += __shfl_xor(v, o);
    float r = rsqrtf(v * (1.f / 64.f) + 1e-5f);
    c[192 + tid] = d * r * g_gln[tid] + b_gln[tid];
  }
  __syncthreads();
  float acc = b_c1[tid];
  for (int k = 0; k < 256; k++) acc = fmaf(c[k], W_c1[(size_t)k * 128 + tid], acc);
  acc = fmaxf(acc, 0.f);
  float s = acc;
  for (int o = 32; o; o >>= 1) s += __shfl_xor(s, o);
  if ((tid & 63) == 0) sred[0][tid >> 6] = s;
  __syncthreads();
  float mu = (sred[0][0] + sred[0][1]) * (1.f / 128.f);
  float d = acc - mu;
  float v = d * d;
  for (int o = 32; o; o >>= 1) v += __shfl_xor(v, o);
  if ((tid & 63) == 0) sred[1][tid >> 6] = v;
  __syncthreads();
  float var = (sred[1][0] + sred[1][1]) * (1.f / 128.f);
  c1s[tid] = d * rsqrtf(var + 1e-5f) * g_cln[tid] + b_cln[tid];
  __syncthreads();
  if (tid < 64) {
    float a2 = b_c2[tid];
    for (int k = 0; k < 128; k++) a2 = fmaf(c1s[k], W_c2[(size_t)k * 64 + tid], a2);
    c2s[tid] = fmaxf(a2, 0.f);
  }
  __syncthreads();
  if (tid < 9) {
    float a3 = b_head[tid];
#pragma unroll
    for (int k = 0; k < 64; k++) a3 = fmaf(c2s[k], W_head[(size_t)k * 9 + tid], a3);
    out[(size_t)b * 9 + tid] = a3;
  }
}

extern "C" void kernel_launch(void* const* d_in, const int* in_sizes, int n_in,
                              void* d_out, int out_size, void* d_ws, size_t ws_size,
                              hipStream_t stream) {
  const float* x       = (const float*)d_in[0];
  const int* edge_index= (const int*)d_in[1];
  const float* edge_attr=(const float*)d_in[2];
  const int* gtype     = (const int*)d_in[3];
  const int* batch     = (const int*)d_in[4];
  const float* glob    = (const float*)d_in[5];
  const float* W_embed = (const float*)d_in[6];
  const float* b_embed = (const float*)d_in[7];
  const float* g_eln   = (const float*)d_in[8];
  const float* b_eln   = (const float*)d_in[9];
  const float* gate_emb= (const float*)d_in[10];
  const float* W_msg   = (const float*)d_in[11];
  const float* b_msg   = (const float*)d_in[12];
  const float* W_upd   = (const float*)d_in[13];
  const float* b_upd   = (const float*)d_in[14];
  const float* W_gproj = (const float*)d_in[15];
  const float* b_gproj = (const float*)d_in[16];
  const float* g_gln   = (const float*)d_in[17];
  const float* b_gln   = (const float*)d_in[18];
  const float* W_c1    = (const float*)d_in[19];
  const float* b_c1    = (const float*)d_in[20];
  const float* g_cln   = (const float*)d_in[21];
  const float* b_cln   = (const float*)d_in[22];
  const float* W_c2    = (const float*)d_in[23];
  const float* b_c2    = (const float*)d_in[24];
  const float* W_head  = (const float*)d_in[25];
  const float* b_head  = (const float*)d_in[26];

  const int N = in_sizes[0] / 16;
  const int E = in_sizes[1] / 2;
  const int B = in_sizes[5] / 32;
  const int L = in_sizes[12] / 64;

  const int* src = edge_index;
  const int* dst = edge_index + E;

  char* ws = (char*)d_ws;
  size_t off = 0;
  auto alloc = [&](size_t bytes) -> void* {
    void* p = ws + off;
    off += (bytes + 255) & ~(size_t)255;
    return p;
  };
  float* h      = (float*)alloc((size_t)N * 64 * 4);
  float* hW     = (float*)alloc((size_t)N * 64 * 4);
  float* agg    = (float*)alloc((size_t)N * 64 * 4);
  float* geW    = (float*)alloc((size_t)L * 20 * 64 * 4);
  float* pooled = (float*)alloc((size_t)B * 192 * 4);
  int* counts   = (int*)alloc((size_t)N * 4);
  int* row_ptr  = (int*)alloc((size_t)(N + 1) * 4);
  int* nextp    = (int*)alloc((size_t)N * 4);
  int nb = (N + 1023) / 1024;
  int* blocksums= (int*)alloc((size_t)nb * 4);
  int* perm     = (int*)alloc((size_t)E * 4);
  int* epack0   = (int*)alloc((size_t)E * 4);
  int* epack    = (int*)alloc((size_t)E * 4);
  float* eap    = (float*)alloc((size_t)E * 8 * 4);

  hipMemsetAsync(counts, 0, (size_t)N * 4, stream);
  count_pack_kernel<<<(E + 255) / 256, 256, 0, stream>>>(dst, src, gtype, counts, epack0, E);
  scan_phase1<<<nb, 256, 0, stream>>>(counts, row_ptr, blocksums, N);
  scan_phase2<<<1, 64, 0, stream>>>(blocksums, nb);
  scan_phase3<<<(N + 255) / 256, 256, 0, stream>>>(row_ptr, blocksums, nextp, N, E);
  {
    int nchunks = (E + SP_EDGES_PER_BLOCK - 1) / SP_EDGES_PER_BLOCK;
    scatter_perm_binned<<<nchunks * 8, 256, 0, stream>>>(dst, nextp, perm, E, N);
  }
  gather_build<<<(E + 255) / 256, 256, 0, stream>>>(perm, epack0, edge_attr, epack, eap, E);
  gew_kernel<<<(L * 20 + 3) / 4, 256, 0, stream>>>(gate_emb, W_msg, geW, L * 20);
  embed_kernel<<<(N + 3) / 4, 256, 0, stream>>>(x, W_embed, b_embed, g_eln, b_eln, h, N);

  nodelin_kernel<<<(N + 63) / 64, 256, 0, stream>>>(h, W_msg, hW, N);
  for (int l = 0; l < L; l++) {
    edge_kernel<<<(N + 3) / 4, 256, 0, stream>>>(hW, epack, eap, row_ptr,
                                                 W_msg + (size_t)l * 88 * 64, b_msg + (size_t)l * 64,
                                                 geW + (size_t)l * 20 * 64, agg, N);
    const float* W1next = (l + 1 < L) ? (W_msg + (size_t)(l + 1) * 88 * 64) : nullptr;
    update_fused_kernel<<<(N + 63) / 64, 256, 0, stream>>>(h, agg, W_upd + (size_t)l * 128 * 64,
                                                           b_upd + (size_t)l * 64, W1next, h, hW, N);
  }

  pool_kernel<<<B, 256, 0, stream>>>(h, batch, pooled, N);
  mlp_kernel<<<B, 128, 0, stream>>>(pooled, glob, W_gproj, b_gproj, g_gln, b_gln,
                                    W_c1, b_c1, g_cln, b_cln, W_c2, b_c2,
                                    W_head, b_head, (float*)d_out);
}

// Round 6
// 468.457 us; speedup vs baseline: 1.9304x; 1.0626x over previous
//
#include <hip/hip_runtime.h>

__device__ __forceinline__ int rfl(int v) { return __builtin_amdgcn_readfirstlane(v); }

__device__ __forceinline__ int lower_bound_dev(const int* __restrict__ a, int n, int v) {
  int lo = 0, hi = n;
  while (lo < hi) { int mid = (lo + hi) >> 1; if (a[mid] < v) lo = mid + 1; else hi = mid; }
  return lo;
}

// ---------------- CSR build ----------------
// count + pack (gate<<20)|src in original edge order (all coalesced)
__global__ void count_pack_kernel(const int* __restrict__ dst, const int* __restrict__ src,
                                  const int* __restrict__ gt, int* __restrict__ counts,
                                  int* __restrict__ epack0, int E) {
  int e = blockIdx.x * 256 + threadIdx.x;
  if (e < E) {
    atomicAdd(&counts[dst[e]], 1);
    epack0[e] = (gt[e] << 20) | src[e];
  }
}

// phase1: per-block (1024 elems) exclusive scan + block total
__global__ __launch_bounds__(256) void scan_phase1(const int* __restrict__ counts,
                                                   int* __restrict__ row_ptr,
                                                   int* __restrict__ blocksums, int n) {
  int tid = threadIdx.x;
  int i0 = blockIdx.x * 1024 + tid * 4;
  int4 c = make_int4(0, 0, 0, 0);
  if (i0 + 3 < n) {
    c = *(const int4*)(counts + i0);
  } else {
    if (i0 + 0 < n) c.x = counts[i0 + 0];
    if (i0 + 1 < n) c.y = counts[i0 + 1];
    if (i0 + 2 < n) c.z = counts[i0 + 2];
    if (i0 + 3 < n) c.w = counts[i0 + 3];
  }
  int s = c.x + c.y + c.z + c.w;
  int lane = tid & 63, wave = tid >> 6;
  int v = s;
  for (int o = 1; o < 64; o <<= 1) { int u = __shfl_up(v, o); if (lane >= o) v += u; }
  __shared__ int wsum[4];
  if (lane == 63) wsum[wave] = v;
  __syncthreads();
  int woff = 0;
  for (int w = 0; w < wave; w++) woff += wsum[w];
  int excl = woff + (v - s);
  if (tid == 255) blocksums[blockIdx.x] = woff + v;
  int p0 = excl, p1 = p0 + c.x, p2 = p1 + c.y, p3 = p2 + c.z;
  if (i0 + 3 < n) {
    *(int4*)(row_ptr + i0) = make_int4(p0, p1, p2, p3);
  } else {
    if (i0 + 0 < n) row_ptr[i0 + 0] = p0;
    if (i0 + 1 < n) row_ptr[i0 + 1] = p1;
    if (i0 + 2 < n) row_ptr[i0 + 2] = p2;
    if (i0 + 3 < n) row_ptr[i0 + 3] = p3;
  }
}

// phase2: single-wave exclusive scan of block sums (nb small)
__global__ __launch_bounds__(64) void scan_phase2(int* __restrict__ blocksums, int nb) {
  int carry = 0;
  for (int base = 0; base < nb; base += 64) {
    int i = base + (int)threadIdx.x;
    int v = (i < nb) ? blocksums[i] : 0;
    int inc = v;
    for (int o = 1; o < 64; o <<= 1) { int u = __shfl_up(inc, o); if ((int)threadIdx.x >= o) inc += u; }
    if (i < nb) blocksums[i] = carry + inc - v;
    carry += __shfl(inc, 63);
  }
}

// phase3: add block offsets, produce row_ptr + nextp
__global__ __launch_bounds__(256) void scan_phase3(int* __restrict__ row_ptr,
                                                   const int* __restrict__ blocksums,
                                                   int* __restrict__ nextp, int n, int E) {
  int i = blockIdx.x * 256 + threadIdx.x;
  if (i < n) {
    int v = row_ptr[i] + blocksums[i >> 10];
    row_ptr[i] = v;
    nextp[i] = v;
  }
  if (i == 0) row_ptr[n] = E;
}

// XCD-binned scatter: 8 dst-range phases; block b handles edge chunk b/8 filtered
// to phase b%8. Round-robin block->XCD dispatch keeps each perm region's writes
// on one XCD's L2 -> full-line write merging (correctness independent of mapping).
#define SP_EDGES_PER_BLOCK 2048
__global__ __launch_bounds__(256) void scatter_perm_binned(const int* __restrict__ dst,
                                                           int* __restrict__ nextp,
                                                           int* __restrict__ perm,
                                                           int E, int n_nodes) {
  int phase = blockIdx.x & 7;
  int chunk = blockIdx.x >> 3;
  int lo = (int)(((long long)phase * n_nodes) >> 3);
  int hi = (int)(((long long)(phase + 1) * n_nodes) >> 3);
  int base = chunk * SP_EDGES_PER_BLOCK + threadIdx.x * 8;
#pragma unroll
  for (int half = 0; half < 2; half++) {
    int b = base + half * 4;
    if (b >= E) break;
    int4 d;
    if (b + 3 < E) {
      d = *(const int4*)(dst + b);
    } else {
      d.x = dst[b];
      d.y = (b + 1 < E) ? dst[b + 1] : -1;
      d.z = (b + 2 < E) ? dst[b + 2] : -1;
      d.w = (b + 3 < E) ? dst[b + 3] : -1;
    }
    if (d.x >= lo && d.x < hi) { int p = atomicAdd(&nextp[d.x], 1); perm[p] = b + 0; }
    if (d.y >= lo && d.y < hi) { int p = atomicAdd(&nextp[d.y], 1); perm[p] = b + 1; }
    if (d.z >= lo && d.z < hi) { int p = atomicAdd(&nextp[d.z], 1); perm[p] = b + 2; }
    if (d.w >= lo && d.w < hi) { int p = atomicAdd(&nextp[d.w], 1); perm[p] = b + 3; }
  }
}

// pass B: CSR-order gather; all writes sequential/coalesced.
__global__ void gather_build(const int* __restrict__ perm, const int* __restrict__ epack0,
                             const float* __restrict__ edge_attr,
                             int* __restrict__ epack, float* __restrict__ eap, int E) {
  int idx = blockIdx.x * 256 + threadIdx.x;
  if (idx < E) {
    int e = perm[idx];
    epack[idx] = epack0[e];
    const float4* s = (const float4*)(edge_attr + (size_t)e * 8);
    float4 a0 = s[0], a1 = s[1];
    float4* d = (float4*)(eap + (size_t)idx * 8);
    d[0] = a0; d[1] = a1;
  }
}

// ---------------- gate-embedding @ W3 table: [L*NG, 64] ----------------
__global__ void gew_kernel(const float* __restrict__ gate_emb, const float* __restrict__ W_msg,
                           float* __restrict__ geW, int nrows) {
  int tid = threadIdx.x;
  int lane = tid & 63;
  int row = blockIdx.x * 4 + (tid >> 6);
  if (row >= nrows) return;
  int l = row / 20, t = row % 20;
  const float* ge = gate_emb + ((size_t)l * 20 + t) * 16;
  const float* W3 = W_msg + (size_t)l * 88 * 64 + 72 * 64;
  float acc = 0.f;
#pragma unroll
  for (int k = 0; k < 16; k++) acc = fmaf(ge[k], W3[(size_t)k * 64 + lane], acc);
  geW[(size_t)row * 64 + lane] = acc;
}

// ---------------- node embed: h = LN(relu(x@W_embed+b)) ----------------
__global__ __launch_bounds__(256) void embed_kernel(const float* __restrict__ x,
                                                    const float* __restrict__ W,
                                                    const float* __restrict__ b,
                                                    const float* __restrict__ gamma,
                                                    const float* __restrict__ beta,
                                                    float* __restrict__ h, int n_nodes) {
  __shared__ float Ws[16 * 64];
  int tid = threadIdx.x;
  for (int i = tid; i < 16 * 64; i += 256) Ws[i] = W[i];
  __syncthreads();
  int lane = tid & 63;
  int n = blockIdx.x * 4 + (tid >> 6);
  if (n >= n_nodes) return;
  const float* xr = x + (size_t)n * 16;
  float acc = b[lane];
#pragma unroll
  for (int k = 0; k < 16; k++) acc = fmaf(xr[k], Ws[k * 64 + lane], acc);
  acc = fmaxf(acc, 0.f);
  float s = acc;
  for (int o = 32; o; o >>= 1) s += __shfl_xor(s, o);
  float mu = s * (1.f / 64.f);
  float d = acc - mu;
  float v = d * d;
  for (int o = 32; o; o >>= 1) v += __shfl_xor(v, o);
  float r = rsqrtf(v * (1.f / 64.f) + 1e-5f);
  h[(size_t)n * 64 + lane] = d * r * gamma[lane] + beta[lane];
}

// ---- tiled GEMM: C[N,64] = A[N,64] @ W[64,64]; swizzled-transposed A tile, W from L1 ----
__global__ __launch_bounds__(256) void nodelin_kernel(const float* __restrict__ A,
                                                      const float* __restrict__ W,
                                                      float* __restrict__ C, int n_nodes) {
  __shared__ float As[64 * 64];  // A[r][k] at As[k*64 + (r ^ (((k>>2)&7)<<2))]
  int tid = threadIdx.x;
  int n0 = blockIdx.x * 64;
#pragma unroll
  for (int i = 0; i < 4; i++) {
    int flat = (tid + i * 256) * 4;
    int r = flat >> 6, k = flat & 63;   // k multiple of 4
    float4 f = make_float4(0.f, 0.f, 0.f, 0.f);
    int n = n0 + r;
    if (n < n_nodes) f = *(const float4*)(A + (size_t)n * 64 + k);
    int rp = r ^ (((k >> 2) & 7) << 2);
    As[(k + 0) * 64 + rp] = f.x;
    As[(k + 1) * 64 + rp] = f.y;
    As[(k + 2) * 64 + rp] = f.z;
    As[(k + 3) * 64 + rp] = f.w;
  }
  __syncthreads();
  int tx = tid & 15, ty = tid >> 4;
  float acc[4][4] = {{0.f}};
  const float4* WV = (const float4*)W;
#pragma unroll 4
  for (int k = 0; k < 64; k++) {
    float4 a = *(const float4*)&As[k * 64 + ((ty * 4) ^ (((k >> 2) & 7) << 2))];
    float4 bb = WV[k * 16 + tx];
    float av[4] = {a.x, a.y, a.z, a.w};
    float bv[4] = {bb.x, bb.y, bb.z, bb.w};
#pragma unroll
    for (int i = 0; i < 4; i++)
#pragma unroll
      for (int j = 0; j < 4; j++) acc[i][j] = fmaf(av[i], bv[j], acc[i][j]);
  }
#pragma unroll
  for (int i = 0; i < 4; i++) {
    int n = n0 + ty * 4 + i;
    if (n < n_nodes) {
      float4 o = make_float4(acc[i][0], acc[i][1], acc[i][2], acc[i][3]);
      *(float4*)&C[(size_t)n * 64 + tx * 4] = o;
    }
  }
}

// -------- edge stage (ILP-4, no LDS): agg[n] = sum relu(hW[src]+ea@W2+geW[t]+b) --------
__global__ __launch_bounds__(256) void edge_kernel(const float* __restrict__ hW,
                                                   const int* __restrict__ epack,
                                                   const float* __restrict__ eap,
                                                   const int* __restrict__ row_ptr,
                                                   const float* __restrict__ W_msg_l,
                                                   const float* __restrict__ b_msg_l,
                                                   const float* __restrict__ geW_l,
                                                   float* __restrict__ agg, int n_nodes) {
  int tid = threadIdx.x;
  int lane = tid & 63;
  int n = blockIdx.x * 4 + (tid >> 6);
  if (n >= n_nodes) return;
  float w2[8];
#pragma unroll
  for (int k = 0; k < 8; k++) w2[k] = W_msg_l[(size_t)(64 + k) * 64 + lane];
  float bm = b_msg_l[lane];
  int beg = rfl(row_ptr[n]);
  int end = rfl(row_ptr[n + 1]);
  float acc = 0.f;
  int idx = beg;
  for (; idx + 4 <= end; idx += 4) {
    int p0 = rfl(epack[idx + 0]);
    int p1 = rfl(epack[idx + 1]);
    int p2 = rfl(epack[idx + 2]);
    int p3 = rfl(epack[idx + 3]);
    int s0 = p0 & 0xFFFFF, t0 = p0 >> 20;
    int s1 = p1 & 0xFFFFF, t1 = p1 >> 20;
    int s2 = p2 & 0xFFFFF, t2 = p2 >> 20;
    int s3 = p3 & 0xFFFFF, t3 = p3 >> 20;
    const float4* ep = (const float4*)(eap + (size_t)idx * 8);
    float4 a00 = ep[0], a01 = ep[1], a10 = ep[2], a11 = ep[3];
    float4 a20 = ep[4], a21 = ep[5], a30 = ep[6], a31 = ep[7];
    float g0 = hW[(size_t)s0 * 64 + lane];
    float g1 = hW[(size_t)s1 * 64 + lane];
    float g2 = hW[(size_t)s2 * 64 + lane];
    float g3 = hW[(size_t)s3 * 64 + lane];
    float e0 = geW_l[t0 * 64 + lane];
    float e1 = geW_l[t1 * 64 + lane];
    float e2 = geW_l[t2 * 64 + lane];
    float e3 = geW_l[t3 * 64 + lane];
    float v0 = g0 + e0 + bm;
    v0 = fmaf(a00.x, w2[0], v0); v0 = fmaf(a00.y, w2[1], v0);
    v0 = fmaf(a00.z, w2[2], v0); v0 = fmaf(a00.w, w2[3], v0);
    v0 = fmaf(a01.x, w2[4], v0); v0 = fmaf(a01.y, w2[5], v0);
    v0 = fmaf(a01.z, w2[6], v0); v0 = fmaf(a01.w, w2[7], v0);
    float v1 = g1 + e1 + bm;
    v1 = fmaf(a10.x, w2[0], v1); v1 = fmaf(a10.y, w2[1], v1);
    v1 = fmaf(a10.z, w2[2], v1); v1 = fmaf(a10.w, w2[3], v1);
    v1 = fmaf(a11.x, w2[4], v1); v1 = fmaf(a11.y, w2[5], v1);
    v1 = fmaf(a11.z, w2[6], v1); v1 = fmaf(a11.w, w2[7], v1);
    float v2 = g2 + e2 + bm;
    v2 = fmaf(a20.x, w2[0], v2); v2 = fmaf(a20.y, w2[1], v2);
    v2 = fmaf(a20.z, w2[2], v2); v2 = fmaf(a20.w, w2[3], v2);
    v2 = fmaf(a21.x, w2[4], v2); v2 = fmaf(a21.y, w2[5], v2);
    v2 = fmaf(a21.z, w2[6], v2); v2 = fmaf(a21.w, w2[7], v2);
    float v3 = g3 + e3 + bm;
    v3 = fmaf(a30.x, w2[0], v3); v3 = fmaf(a30.y, w2[1], v3);
    v3 = fmaf(a30.z, w2[2], v3); v3 = fmaf(a30.w, w2[3], v3);
    v3 = fmaf(a31.x, w2[4], v3); v3 = fmaf(a31.y, w2[5], v3);
    v3 = fmaf(a31.z, w2[6], v3); v3 = fmaf(a31.w, w2[7], v3);
    acc += fmaxf(v0, 0.f) + fmaxf(v1, 0.f) + fmaxf(v2, 0.f) + fmaxf(v3, 0.f);
  }
  for (; idx < end; idx++) {
    int p = rfl(epack[idx]);
    int s = p & 0xFFFFF, t = p >> 20;
    const float4* ep = (const float4*)(eap + (size_t)idx * 8);
    float4 a0 = ep[0], a1 = ep[1];
    float g = hW[(size_t)s * 64 + lane];
    float v = g + geW_l[t * 64 + lane] + bm;
    v = fmaf(a0.x, w2[0], v); v = fmaf(a0.y, w2[1], v);
    v = fmaf(a0.z, w2[2], v); v = fmaf(a0.w, w2[3], v);
    v = fmaf(a1.x, w2[4], v); v = fmaf(a1.y, w2[5], v);
    v = fmaf(a1.z, w2[6], v); v = fmaf(a1.w, w2[7], v);
    acc += fmaxf(v, 0.f);
  }
  agg[(size_t)n * 64 + lane] = acc;
}

// -------- fused update + next-layer hW: h=h+[h,agg]@Wu+bu ; hW = h@W1next --------
// A tile swizzled-transposed in LDS (32KB); weights read from global (L1-resident).
__global__ __launch_bounds__(256) void update_fused_kernel(const float* __restrict__ h,
                                                           const float* __restrict__ agg,
                                                           const float* __restrict__ Wu,
                                                           const float* __restrict__ bu,
                                                           const float* __restrict__ W1next,
                                                           float* __restrict__ h_out,
                                                           float* __restrict__ hW_out,
                                                           int n_nodes) {
  __shared__ float As[128 * 64];  // A[r][k] at As[k*64 + (r ^ (((k>>2)&7)<<2))]
  int tid = threadIdx.x;
  int n0 = blockIdx.x * 64;
#pragma unroll
  for (int i = 0; i < 8; i++) {
    int flat = (tid + i * 256) * 4;
    int r = flat >> 7, k = flat & 127;  // k multiple of 4
    float4 f = make_float4(0.f, 0.f, 0.f, 0.f);
    int n = n0 + r;
    if (n < n_nodes) {
      const float* sp = (k < 64) ? (h + (size_t)n * 64 + k) : (agg + (size_t)n * 64 + (k - 64));
      f = *(const float4*)sp;
    }
    int rp = r ^ (((k >> 2) & 7) << 2);
    As[(k + 0) * 64 + rp] = f.x;
    As[(k + 1) * 64 + rp] = f.y;
    As[(k + 2) * 64 + rp] = f.z;
    As[(k + 3) * 64 + rp] = f.w;
  }
  __syncthreads();
  int tx = tid & 15, ty = tid >> 4;
  float acc[4][4] = {{0.f}};
  const float4* WuV = (const float4*)Wu;
#pragma unroll 4
  for (int k = 0; k < 128; k++) {
    float4 a = *(const float4*)&As[k * 64 + ((ty * 4) ^ (((k >> 2) & 7) << 2))];
    float4 bb = WuV[k * 16 + tx];
    float av[4] = {a.x, a.y, a.z, a.w};
    float bv[4] = {bb.x, bb.y, bb.z, bb.w};
#pragma unroll
    for (int i = 0; i < 4; i++)
#pragma unroll
      for (int j = 0; j < 4; j++) acc[i][j] = fmaf(av[i], bv[j], acc[i][j]);
  }
  float hnew[4][4];
  float4 bv4 = *(const float4*)&bu[tx * 4];
#pragma unroll
  for (int i = 0; i < 4; i++) {
    int n = n0 + ty * 4 + i;
    if (n < n_nodes) {
      float4 hv = *(const float4*)&h[(size_t)n * 64 + tx * 4];
      hnew[i][0] = hv.x + acc[i][0] + bv4.x;
      hnew[i][1] = hv.y + acc[i][1] + bv4.y;
      hnew[i][2] = hv.z + acc[i][2] + bv4.z;
      hnew[i][3] = hv.w + acc[i][3] + bv4.w;
      float4 o = make_float4(hnew[i][0], hnew[i][1], hnew[i][2], hnew[i][3]);
      *(float4*)&h_out[(size_t)n * 64 + tx * 4] = o;
    } else {
      hnew[i][0] = hnew[i][1] = hnew[i][2] = hnew[i][3] = 0.f;
    }
  }
  if (W1next) {
    __syncthreads();  // all GEMM1 LDS reads complete
    // stage h_new row-major, padded: As2[r][k] at As[r*68 + k]  (64*68 = 4352 < 8192)
#pragma unroll
    for (int i = 0; i < 4; i++) {
      float4 o = make_float4(hnew[i][0], hnew[i][1], hnew[i][2], hnew[i][3]);
      *(float4*)&As[(ty * 4 + i) * 68 + tx * 4] = o;
    }
    __syncthreads();
    float acc2[4][4] = {{0.f}};
    const float4* W1V = (const float4*)W1next;
#pragma unroll 4
    for (int k = 0; k < 64; k++) {
      float av[4];
#pragma unroll
      for (int i = 0; i < 4; i++) av[i] = As[(ty * 4 + i) * 68 + k];
      float4 bb = W1V[k * 16 + tx];
      float bv[4] = {bb.x, bb.y, bb.z, bb.w};
#pragma unroll
      for (int i = 0; i < 4; i++)
#pragma unroll
        for (int j = 0; j < 4; j++) acc2[i][j] = fmaf(av[i], bv[j], acc2[i][j]);
    }
#pragma unroll
    for (int i = 0; i < 4; i++) {
      int n = n0 + ty * 4 + i;
      if (n < n_nodes) {
        float4 o = make_float4(acc2[i][0], acc2[i][1], acc2[i][2], acc2[i][3]);
        *(float4*)&hW_out[(size_t)n * 64 + tx * 4] = o;
      }
    }
  }
}

// ---------------- pooling: mean/max/sum per graph ----------------
__global__ __launch_bounds__(256) void pool_kernel(const float* __restrict__ h,
                                                   const int* __restrict__ batch,
                                                   float* __restrict__ pooled, int n_nodes) {
  int b = blockIdx.x;
  __shared__ int se[2];
  if (threadIdx.x == 0) se[0] = lower_bound_dev(batch, n_nodes, b);
  if (threadIdx.x == 1) se[1] = lower_bound_dev(batch, n_nodes, b + 1);
  __syncthreads();
  int start = se[0], end = se[1];
  int lane = threadIdx.x & 63, wave = threadIdx.x >> 6;
  float s = 0.f, m = -INFINITY;
  for (int i = start + wave; i < end; i += 4) {
    float v = h[(size_t)i * 64 + lane];
    s += v;
    m = fmaxf(m, v);
  }
  __shared__ float ss[4][64], mm[4][64];
  ss[wave][lane] = s;
  mm[wave][lane] = m;
  __syncthreads();
  if (wave == 0) {
    s = ss[0][lane] + ss[1][lane] + ss[2][lane] + ss[3][lane];
    m = fmaxf(fmaxf(mm[0][lane], mm[1][lane]), fmaxf(mm[2][lane], mm[3][lane]));
    int cnt = end - start;
    float mean = (cnt > 0) ? s / (float)cnt : 0.f;
    if (cnt == 0) { m = 0.f; s = 0.f; }
    pooled[(size_t)b * 192 + lane] = mean;
    pooled[(size_t)b * 192 + 64 + lane] = m;
    pooled[(size_t)b * 192 + 128 + lane] = s;
  }
}

// ---------------- head MLP per graph ----------------
__global__ __launch_bounds__(128) void mlp_kernel(
    const float* __restrict__ pooled, const float* __restrict__ glob,
    const float* __restrict__ W_gproj, const float* __restrict__ b_gproj,
    const float* __restrict__ g_gln, const float* __restrict__ b_gln,
    const float* __restrict__ W_c1, const float* __restrict__ b_c1,
    const float* __restrict__ g_cln, const float* __restrict__ b_cln,
    const float* __restrict__ W_c2, const float* __restrict__ b_c2,
    const float* __restrict__ W_head, const float* __restrict__ b_head,
    float* __restrict__ out) {
  int b = blockIdx.x;
  int tid = threadIdx.x;  // 128 threads
  __shared__ float c[256];
  __shared__ float c1s[128];
  __shared__ float c2s[64];
  __shared__ float sred[2][2];
  c[tid] = pooled[(size_t)b * 192 + tid];
  if (tid < 64) c[128 + tid] = pooled[(size_t)b * 192 + 128 + tid];
  if (tid < 64) {
    const float* gf = glob + (size_t)b * 32;
    float acc = b_gproj[tid];
#pragma unroll
    for (int k = 0; k < 32; k++) acc = fmaf(gf[k], W_gproj[(size_t)k * 64 + tid], acc);
    acc = fmaxf(acc, 0.f);
    float s = acc;
    for (int o = 32; o; o >>= 1) s += __shfl_xor(s, o);
    float mu = s * (1.f / 64.f);
    float d = acc - mu;
    float v = d * d;
    for (int o = 32; o; o >>= 1) v += __shfl_xor(v, o);
    float r = rsqrtf(v * (1.f / 64.f) + 1e-5f);
    c[192 + tid] = d * r * g_gln[tid] + b_gln[tid];
  }
  __syncthreads();
  float acc = b_c1[tid];
  for (int k = 0; k < 256; k++) acc = fmaf(c[k], W_c1[(size_t)k * 128 + tid], acc);
  acc = fmaxf(acc, 0.f);
  float s = acc;
  for (int o = 32; o; o >>= 1) s += __shfl_xor(s, o);
  if ((tid & 63) == 0) sred[0][tid >> 6] = s;
  __syncthreads();
  float mu = (sred[0][0] + sred[0][1]) * (1.f / 128.f);
  float d = acc - mu;
  float v = d * d;
  for (int o = 32; o; o >>= 1) v += __shfl_xor(v, o);
  if ((tid & 63) == 0) sred[1][tid >> 6] = v;
  __syncthreads();
  float var = (sred[1][0] + sred[1][1]) * (1.f / 128.f);
  c1s[tid] = d * rsqrtf(var + 1e-5f) * g_cln[tid] + b_cln[tid];
  __syncthreads();
  if (tid < 64) {
    float a2 = b_c2[tid];
    for (int k = 0; k < 128; k++) a2 = fmaf(c1s[k], W_c2[(size_t)k * 64 + tid], a2);
    c2s[tid] = fmaxf(a2, 0.f);
  }
  __syncthreads();
  if (tid < 9) {
    float a3 = b_head[tid];
#pragma unroll
    for (int k = 0; k < 64; k++) a3 = fmaf(c2s[k], W_head[(size_t)k * 9 + tid], a3);
    out[(size_t)b * 9 + tid] = a3;
  }
}

extern "C" void kernel_launch(void* const* d_in, const int* in_sizes, int n_in,
                              void* d_out, int out_size, void* d_ws, size_t ws_size,
                              hipStream_t stream) {
  const float* x       = (const float*)d_in[0];
  const int* edge_index= (const int*)d_in[1];
  const float* edge_attr=(const float*)d_in[2];
  const int* gtype     = (const int*)d_in[3];
  const int* batch     = (const int*)d_in[4];
  const float* glob    = (const float*)d_in[5];
  const float* W_embed = (const float*)d_in[6];
  const float* b_embed = (const float*)d_in[7];
  const float* g_eln   = (const float*)d_in[8];
  const float* b_eln   = (const float*)d_in[9];
  const float* gate_emb= (const float*)d_in[10];
  const float* W_msg   = (const float*)d_in[11];
  const float* b_msg   = (const float*)d_in[12];
  const float* W_upd   = (const float*)d_in[13];
  const float* b_upd   = (const float*)d_in[14];
  const float* W_gproj = (const float*)d_in[15];
  const float* b_gproj = (const float*)d_in[16];
  const float* g_gln   = (const float*)d_in[17];
  const float* b_gln   = (const float*)d_in[18];
  const float* W_c1    = (const float*)d_in[19];
  const float* b_c1    = (const float*)d_in[20];
  const float* g_cln   = (const float*)d_in[21];
  const float* b_cln   = (const float*)d_in[22];
  const float* W_c2    = (const float*)d_in[23];
  const float* b_c2    = (const float*)d_in[24];
  const float* W_head  = (const float*)d_in[25];
  const float* b_head  = (const float*)d_in[26];

  const int N = in_sizes[0] / 16;
  const int E = in_sizes[1] / 2;
  const int B = in_sizes[5] / 32;
  const int L = in_sizes[12] / 64;

  const int* src = edge_index;
  const int* dst = edge_index + E;

  char* ws = (char*)d_ws;
  size_t off = 0;
  auto alloc = [&](size_t bytes) -> void* {
    void* p = ws + off;
    off += (bytes + 255) & ~(size_t)255;
    return p;
  };
  float* h      = (float*)alloc((size_t)N * 64 * 4);
  float* hW     = (float*)alloc((size_t)N * 64 * 4);
  float* agg    = (float*)alloc((size_t)N * 64 * 4);
  float* geW    = (float*)alloc((size_t)L * 20 * 64 * 4);
  float* pooled = (float*)alloc((size_t)B * 192 * 4);
  int* counts   = (int*)alloc((size_t)N * 4);
  int* row_ptr  = (int*)alloc((size_t)(N + 1) * 4);
  int* nextp    = (int*)alloc((size_t)N * 4);
  int nb = (N + 1023) / 1024;
  int* blocksums= (int*)alloc((size_t)nb * 4);
  int* perm     = (int*)alloc((size_t)E * 4);
  int* epack0   = (int*)alloc((size_t)E * 4);
  int* epack    = (int*)alloc((size_t)E * 4);
  float* eap    = (float*)alloc((size_t)E * 8 * 4);

  hipMemsetAsync(counts, 0, (size_t)N * 4, stream);
  count_pack_kernel<<<(E + 255) / 256, 256, 0, stream>>>(dst, src, gtype, counts, epack0, E);
  scan_phase1<<<nb, 256, 0, stream>>>(counts, row_ptr, blocksums, N);
  scan_phase2<<<1, 64, 0, stream>>>(blocksums, nb);
  scan_phase3<<<(N + 255) / 256, 256, 0, stream>>>(row_ptr, blocksums, nextp, N, E);
  {
    int nchunks = (E + SP_EDGES_PER_BLOCK - 1) / SP_EDGES_PER_BLOCK;
    scatter_perm_binned<<<nchunks * 8, 256, 0, stream>>>(dst, nextp, perm, E, N);
  }
  gather_build<<<(E + 255) / 256, 256, 0, stream>>>(perm, epack0, edge_attr, epack, eap, E);
  gew_kernel<<<(L * 20 + 3) / 4, 256, 0, stream>>>(gate_emb, W_msg, geW, L * 20);
  embed_kernel<<<(N + 3) / 4, 256, 0, stream>>>(x, W_embed, b_embed, g_eln, b_eln, h, N);

  nodelin_kernel<<<(N + 63) / 64, 256, 0, stream>>>(h, W_msg, hW, N);
  for (int l = 0; l < L; l++) {
    edge_kernel<<<(N + 3) / 4, 256, 0, stream>>>(hW, epack, eap, row_ptr,
                                                 W_msg + (size_t)l * 88 * 64, b_msg + (size_t)l * 64,
                                                 geW + (size_t)l * 20 * 64, agg, N);
    const float* W1next = (l + 1 < L) ? (W_msg + (size_t)(l + 1) * 88 * 64) : nullptr;
    update_fused_kernel<<<(N + 63) / 64, 256, 0, stream>>>(h, agg, W_upd + (size_t)l * 128 * 64,
                                                           b_upd + (size_t)l * 64, W1next, h, hW, N);
  }

  pool_kernel<<<B, 256, 0, stream>>>(h, batch, pooled, N);
  mlp_kernel<<<B, 128, 0, stream>>>(pooled, glob, W_gproj, b_gproj, g_gln, b_gln,
                                    W_c1, b_c1, g_cln, b_cln, W_c2, b_c2,
                                    W_head, b_head, (float*)d_out);
}

// Round 7
// 467.028 us; speedup vs baseline: 1.9364x; 1.0031x over previous
//
#include <hip/hip_runtime.h>

__device__ __forceinline__ int rfl(int v) { return __builtin_amdgcn_readfirstlane(v); }

__device__ __forceinline__ int lower_bound_dev(const int* __restrict__ a, int n, int v) {
  int lo = 0, hi = n;
  while (lo < hi) { int mid = (lo + hi) >> 1; if (a[mid] < v) lo = mid + 1; else hi = mid; }
  return lo;
}

// ---------------- fast zero (replaces 40us rocclr fillBuffer) ----------------
__global__ void zero_kernel(int4* __restrict__ p, int n4) {
  int i = blockIdx.x * 256 + threadIdx.x;
  if (i < n4) p[i] = make_int4(0, 0, 0, 0);
}

// ---------------- CSR build ----------------
// count + pack (gate<<20)|src in original edge order (all coalesced)
__global__ void count_pack_kernel(const int* __restrict__ dst, const int* __restrict__ src,
                                  const int* __restrict__ gt, int* __restrict__ counts,
                                  int* __restrict__ epack0, int E) {
  int e = blockIdx.x * 256 + threadIdx.x;
  if (e < E) {
    atomicAdd(&counts[dst[e]], 1);
    epack0[e] = (gt[e] << 20) | src[e];
  }
}

// phase1: per-block (1024 elems) exclusive scan + block total
__global__ __launch_bounds__(256) void scan_phase1(const int* __restrict__ counts,
                                                   int* __restrict__ row_ptr,
                                                   int* __restrict__ blocksums, int n) {
  int tid = threadIdx.x;
  int i0 = blockIdx.x * 1024 + tid * 4;
  int4 c = make_int4(0, 0, 0, 0);
  if (i0 + 3 < n) {
    c = *(const int4*)(counts + i0);
  } else {
    if (i0 + 0 < n) c.x = counts[i0 + 0];
    if (i0 + 1 < n) c.y = counts[i0 + 1];
    if (i0 + 2 < n) c.z = counts[i0 + 2];
    if (i0 + 3 < n) c.w = counts[i0 + 3];
  }
  int s = c.x + c.y + c.z + c.w;
  int lane = tid & 63, wave = tid >> 6;
  int v = s;
  for (int o = 1; o < 64; o <<= 1) { int u = __shfl_up(v, o); if (lane >= o) v += u; }
  __shared__ int wsum[4];
  if (lane == 63) wsum[wave] = v;
  __syncthreads();
  int woff = 0;
  for (int w = 0; w < wave; w++) woff += wsum[w];
  int excl = woff + (v - s);
  if (tid == 255) blocksums[blockIdx.x] = woff + v;
  int p0 = excl, p1 = p0 + c.x, p2 = p1 + c.y, p3 = p2 + c.z;
  if (i0 + 3 < n) {
    *(int4*)(row_ptr + i0) = make_int4(p0, p1, p2, p3);
  } else {
    if (i0 + 0 < n) row_ptr[i0 + 0] = p0;
    if (i0 + 1 < n) row_ptr[i0 + 1] = p1;
    if (i0 + 2 < n) row_ptr[i0 + 2] = p2;
    if (i0 + 3 < n) row_ptr[i0 + 3] = p3;
  }
}

// phase2: single-wave exclusive scan of block sums (nb small)
__global__ __launch_bounds__(64) void scan_phase2(int* __restrict__ blocksums, int nb) {
  int carry = 0;
  for (int base = 0; base < nb; base += 64) {
    int i = base + (int)threadIdx.x;
    int v = (i < nb) ? blocksums[i] : 0;
    int inc = v;
    for (int o = 1; o < 64; o <<= 1) { int u = __shfl_up(inc, o); if ((int)threadIdx.x >= o) inc += u; }
    if (i < nb) blocksums[i] = carry + inc - v;
    carry += __shfl(inc, 63);
  }
}

// phase3: add block offsets, produce row_ptr + nextp
__global__ __launch_bounds__(256) void scan_phase3(int* __restrict__ row_ptr,
                                                   const int* __restrict__ blocksums,
                                                   int* __restrict__ nextp, int n, int E) {
  int i = blockIdx.x * 256 + threadIdx.x;
  if (i < n) {
    int v = row_ptr[i] + blocksums[i >> 10];
    row_ptr[i] = v;
    nextp[i] = v;
  }
  if (i == 0) row_ptr[n] = E;
}

// XCD-binned scatter: 8 dst-range phases; block b handles edge chunk b/8 filtered
// to phase b%8. Round-robin block->XCD dispatch keeps each perm region's writes
// on one XCD's L2 -> full-line write merging (correctness independent of mapping).
#define SP_EDGES_PER_BLOCK 2048
__global__ __launch_bounds__(256) void scatter_perm_binned(const int* __restrict__ dst,
                                                           int* __restrict__ nextp,
                                                           int* __restrict__ perm,
                                                           int E, int n_nodes) {
  int phase = blockIdx.x & 7;
  int chunk = blockIdx.x >> 3;
  int lo = (int)(((long long)phase * n_nodes) >> 3);
  int hi = (int)(((long long)(phase + 1) * n_nodes) >> 3);
  int base = chunk * SP_EDGES_PER_BLOCK + threadIdx.x * 8;
#pragma unroll
  for (int half = 0; half < 2; half++) {
    int b = base + half * 4;
    if (b >= E) break;
    int4 d;
    if (b + 3 < E) {
      d = *(const int4*)(dst + b);
    } else {
      d.x = dst[b];
      d.y = (b + 1 < E) ? dst[b + 1] : -1;
      d.z = (b + 2 < E) ? dst[b + 2] : -1;
      d.w = (b + 3 < E) ? dst[b + 3] : -1;
    }
    if (d.x >= lo && d.x < hi) { int p = atomicAdd(&nextp[d.x], 1); perm[p] = b + 0; }
    if (d.y >= lo && d.y < hi) { int p = atomicAdd(&nextp[d.y], 1); perm[p] = b + 1; }
    if (d.z >= lo && d.z < hi) { int p = atomicAdd(&nextp[d.z], 1); perm[p] = b + 2; }
    if (d.w >= lo && d.w < hi) { int p = atomicAdd(&nextp[d.w], 1); perm[p] = b + 3; }
  }
}

// pass B: CSR-order gather; all writes sequential/coalesced.
__global__ void gather_build(const int* __restrict__ perm, const int* __restrict__ epack0,
                             const float* __restrict__ edge_attr,
                             int* __restrict__ epack, float* __restrict__ eap, int E) {
  int idx = blockIdx.x * 256 + threadIdx.x;
  if (idx < E) {
    int e = perm[idx];
    epack[idx] = epack0[e];
    const float4* s = (const float4*)(edge_attr + (size_t)e * 8);
    float4 a0 = s[0], a1 = s[1];
    float4* d = (float4*)(eap + (size_t)idx * 8);
    d[0] = a0; d[1] = a1;
  }
}

// ---------------- gate-embedding @ W3 table: [L*NG, 64] ----------------
__global__ void gew_kernel(const float* __restrict__ gate_emb, const float* __restrict__ W_msg,
                           float* __restrict__ geW, int nrows) {
  int tid = threadIdx.x;
  int lane = tid & 63;
  int row = blockIdx.x * 4 + (tid >> 6);
  if (row >= nrows) return;
  int l = row / 20, t = row % 20;
  const float* ge = gate_emb + ((size_t)l * 20 + t) * 16;
  const float* W3 = W_msg + (size_t)l * 88 * 64 + 72 * 64;
  float acc = 0.f;
#pragma unroll
  for (int k = 0; k < 16; k++) acc = fmaf(ge[k], W3[(size_t)k * 64 + lane], acc);
  geW[(size_t)row * 64 + lane] = acc;
}

// ---------------- node embed: h = LN(relu(x@W_embed+b)) ----------------
__global__ __launch_bounds__(256) void embed_kernel(const float* __restrict__ x,
                                                    const float* __restrict__ W,
                                                    const float* __restrict__ b,
                                                    const float* __restrict__ gamma,
                                                    const float* __restrict__ beta,
                                                    float* __restrict__ h, int n_nodes) {
  __shared__ float Ws[16 * 64];
  int tid = threadIdx.x;
  for (int i = tid; i < 16 * 64; i += 256) Ws[i] = W[i];
  __syncthreads();
  int lane = tid & 63;
  int n = blockIdx.x * 4 + (tid >> 6);
  if (n >= n_nodes) return;
  const float* xr = x + (size_t)n * 16;
  float acc = b[lane];
#pragma unroll
  for (int k = 0; k < 16; k++) acc = fmaf(xr[k], Ws[k * 64 + lane], acc);
  acc = fmaxf(acc, 0.f);
  float s = acc;
  for (int o = 32; o; o >>= 1) s += __shfl_xor(s, o);
  float mu = s * (1.f / 64.f);
  float d = acc - mu;
  float v = d * d;
  for (int o = 32; o; o >>= 1) v += __shfl_xor(v, o);
  float r = rsqrtf(v * (1.f / 64.f) + 1e-5f);
  h[(size_t)n * 64 + lane] = d * r * gamma[lane] + beta[lane];
}

// ---- tiled GEMM: C[N,64] = A[N,64] @ W[64,64]; swizzled-transposed A tile, W from L1 ----
__global__ __launch_bounds__(256) void nodelin_kernel(const float* __restrict__ A,
                                                      const float* __restrict__ W,
                                                      float* __restrict__ C, int n_nodes) {
  __shared__ float As[64 * 64];  // A[r][k] at As[k*64 + (r ^ (((k>>2)&7)<<2))]
  int tid = threadIdx.x;
  int n0 = blockIdx.x * 64;
#pragma unroll
  for (int i = 0; i < 4; i++) {
    int flat = (tid + i * 256) * 4;
    int r = flat >> 6, k = flat & 63;   // k multiple of 4
    float4 f = make_float4(0.f, 0.f, 0.f, 0.f);
    int n = n0 + r;
    if (n < n_nodes) f = *(const float4*)(A + (size_t)n * 64 + k);
    int rp = r ^ (((k >> 2) & 7) << 2);
    As[(k + 0) * 64 + rp] = f.x;
    As[(k + 1) * 64 + rp] = f.y;
    As[(k + 2) * 64 + rp] = f.z;
    As[(k + 3) * 64 + rp] = f.w;
  }
  __syncthreads();
  int tx = tid & 15, ty = tid >> 4;
  float acc[4][4] = {{0.f}};
  const float4* WV = (const float4*)W;
#pragma unroll 4
  for (int k = 0; k < 64; k++) {
    float4 a = *(const float4*)&As[k * 64 + ((ty * 4) ^ (((k >> 2) & 7) << 2))];
    float4 bb = WV[k * 16 + tx];
    float av[4] = {a.x, a.y, a.z, a.w};
    float bv[4] = {bb.x, bb.y, bb.z, bb.w};
#pragma unroll
    for (int i = 0; i < 4; i++)
#pragma unroll
      for (int j = 0; j < 4; j++) acc[i][j] = fmaf(av[i], bv[j], acc[i][j]);
  }
#pragma unroll
  for (int i = 0; i < 4; i++) {
    int n = n0 + ty * 4 + i;
    if (n < n_nodes) {
      float4 o = make_float4(acc[i][0], acc[i][1], acc[i][2], acc[i][3]);
      *(float4*)&C[(size_t)n * 64 + tx * 4] = o;
    }
  }
}

// -------- edge stage (ILP-4, no LDS): agg[n] = sum relu(hW[src]+ea@W2+geW[t]+b) --------
__global__ __launch_bounds__(256) void edge_kernel(const float* __restrict__ hW,
                                                   const int* __restrict__ epack,
                                                   const float* __restrict__ eap,
                                                   const int* __restrict__ row_ptr,
                                                   const float* __restrict__ W_msg_l,
                                                   const float* __restrict__ b_msg_l,
                                                   const float* __restrict__ geW_l,
                                                   float* __restrict__ agg, int n_nodes) {
  int tid = threadIdx.x;
  int lane = tid & 63;
  int n = blockIdx.x * 4 + (tid >> 6);
  if (n >= n_nodes) return;
  float w2[8];
#pragma unroll
  for (int k = 0; k < 8; k++) w2[k] = W_msg_l[(size_t)(64 + k) * 64 + lane];
  float bm = b_msg_l[lane];
  int beg = rfl(row_ptr[n]);
  int end = rfl(row_ptr[n + 1]);
  float acc = 0.f;
  int idx = beg;
  for (; idx + 4 <= end; idx += 4) {
    int p0 = rfl(epack[idx + 0]);
    int p1 = rfl(epack[idx + 1]);
    int p2 = rfl(epack[idx + 2]);
    int p3 = rfl(epack[idx + 3]);
    int s0 = p0 & 0xFFFFF, t0 = p0 >> 20;
    int s1 = p1 & 0xFFFFF, t1 = p1 >> 20;
    int s2 = p2 & 0xFFFFF, t2 = p2 >> 20;
    int s3 = p3 & 0xFFFFF, t3 = p3 >> 20;
    const float4* ep = (const float4*)(eap + (size_t)idx * 8);
    float4 a00 = ep[0], a01 = ep[1], a10 = ep[2], a11 = ep[3];
    float4 a20 = ep[4], a21 = ep[5], a30 = ep[6], a31 = ep[7];
    float g0 = hW[(size_t)s0 * 64 + lane];
    float g1 = hW[(size_t)s1 * 64 + lane];
    float g2 = hW[(size_t)s2 * 64 + lane];
    float g3 = hW[(size_t)s3 * 64 + lane];
    float e0 = geW_l[t0 * 64 + lane];
    float e1 = geW_l[t1 * 64 + lane];
    float e2 = geW_l[t2 * 64 + lane];
    float e3 = geW_l[t3 * 64 + lane];
    float v0 = g0 + e0 + bm;
    v0 = fmaf(a00.x, w2[0], v0); v0 = fmaf(a00.y, w2[1], v0);
    v0 = fmaf(a00.z, w2[2], v0); v0 = fmaf(a00.w, w2[3], v0);
    v0 = fmaf(a01.x, w2[4], v0); v0 = fmaf(a01.y, w2[5], v0);
    v0 = fmaf(a01.z, w2[6], v0); v0 = fmaf(a01.w, w2[7], v0);
    float v1 = g1 + e1 + bm;
    v1 = fmaf(a10.x, w2[0], v1); v1 = fmaf(a10.y, w2[1], v1);
    v1 = fmaf(a10.z, w2[2], v1); v1 = fmaf(a10.w, w2[3], v1);
    v1 = fmaf(a11.x, w2[4], v1); v1 = fmaf(a11.y, w2[5], v1);
    v1 = fmaf(a11.z, w2[6], v1); v1 = fmaf(a11.w, w2[7], v1);
    float v2 = g2 + e2 + bm;
    v2 = fmaf(a20.x, w2[0], v2); v2 = fmaf(a20.y, w2[1], v2);
    v2 = fmaf(a20.z, w2[2], v2); v2 = fmaf(a20.w, w2[3], v2);
    v2 = fmaf(a21.x, w2[4], v2); v2 = fmaf(a21.y, w2[5], v2);
    v2 = fmaf(a21.z, w2[6], v2); v2 = fmaf(a21.w, w2[7], v2);
    float v3 = g3 + e3 + bm;
    v3 = fmaf(a30.x, w2[0], v3); v3 = fmaf(a30.y, w2[1], v3);
    v3 = fmaf(a30.z, w2[2], v3); v3 = fmaf(a30.w, w2[3], v3);
    v3 = fmaf(a31.x, w2[4], v3); v3 = fmaf(a31.y, w2[5], v3);
    v3 = fmaf(a31.z, w2[6], v3); v3 = fmaf(a31.w, w2[7], v3);
    acc += fmaxf(v0, 0.f) + fmaxf(v1, 0.f) + fmaxf(v2, 0.f) + fmaxf(v3, 0.f);
  }
  for (; idx < end; idx++) {
    int p = rfl(epack[idx]);
    int s = p & 0xFFFFF, t = p >> 20;
    const float4* ep = (const float4*)(eap + (size_t)idx * 8);
    float4 a0 = ep[0], a1 = ep[1];
    float g = hW[(size_t)s * 64 + lane];
    float v = g + geW_l[t * 64 + lane] + bm;
    v = fmaf(a0.x, w2[0], v); v = fmaf(a0.y, w2[1], v);
    v = fmaf(a0.z, w2[2], v); v = fmaf(a0.w, w2[3], v);
    v = fmaf(a1.x, w2[4], v); v = fmaf(a1.y, w2[5], v);
    v = fmaf(a1.z, w2[6], v); v = fmaf(a1.w, w2[7], v);
    acc += fmaxf(v, 0.f);
  }
  agg[(size_t)n * 64 + lane] = acc;
}

// -------- fused update + next-layer hW: h=h+[h,agg]@Wu+bu ; hW = h@W1next --------
// A tile swizzled-transposed in LDS (32KB); weights read from global (L1-resident).
__global__ __launch_bounds__(256) void update_fused_kernel(const float* __restrict__ h,
                                                           const float* __restrict__ agg,
                                                           const float* __restrict__ Wu,
                                                           const float* __restrict__ bu,
                                                           const float* __restrict__ W1next,
                                                           float* __restrict__ h_out,
                                                           float* __restrict__ hW_out,
                                                           int n_nodes) {
  __shared__ float As[128 * 64];  // A[r][k] at As[k*64 + (r ^ (((k>>2)&7)<<2))]
  int tid = threadIdx.x;
  int n0 = blockIdx.x * 64;
#pragma unroll
  for (int i = 0; i < 8; i++) {
    int flat = (tid + i * 256) * 4;
    int r = flat >> 7, k = flat & 127;  // k multiple of 4
    float4 f = make_float4(0.f, 0.f, 0.f, 0.f);
    int n = n0 + r;
    if (n < n_nodes) {
      const float* sp = (k < 64) ? (h + (size_t)n * 64 + k) : (agg + (size_t)n * 64 + (k - 64));
      f = *(const float4*)sp;
    }
    int rp = r ^ (((k >> 2) & 7) << 2);
    As[(k + 0) * 64 + rp] = f.x;
    As[(k + 1) * 64 + rp] = f.y;
    As[(k + 2) * 64 + rp] = f.z;
    As[(k + 3) * 64 + rp] = f.w;
  }
  __syncthreads();
  int tx = tid & 15, ty = tid >> 4;
  float acc[4][4] = {{0.f}};
  const float4* WuV = (const float4*)Wu;
#pragma unroll 4
  for (int k = 0; k < 128; k++) {
    float4 a = *(const float4*)&As[k * 64 + ((ty * 4) ^ (((k >> 2) & 7) << 2))];
    float4 bb = WuV[k * 16 + tx];
    float av[4] = {a.x, a.y, a.z, a.w};
    float bv[4] = {bb.x, bb.y, bb.z, bb.w};
#pragma unroll
    for (int i = 0; i < 4; i++)
#pragma unroll
      for (int j = 0; j < 4; j++) acc[i][j] = fmaf(av[i], bv[j], acc[i][j]);
  }
  float hnew[4][4];
  float4 bv4 = *(const float4*)&bu[tx * 4];
#pragma unroll
  for (int i = 0; i < 4; i++) {
    int n = n0 + ty * 4 + i;
    if (n < n_nodes) {
      float4 hv = *(const float4*)&h[(size_t)n * 64 + tx * 4];
      hnew[i][0] = hv.x + acc[i][0] + bv4.x;
      hnew[i][1] = hv.y + acc[i][1] + bv4.y;
      hnew[i][2] = hv.z + acc[i][2] + bv4.z;
      hnew[i][3] = hv.w + acc[i][3] + bv4.w;
      float4 o = make_float4(hnew[i][0], hnew[i][1], hnew[i][2], hnew[i][3]);
      *(float4*)&h_out[(size_t)n * 64 + tx * 4] = o;
    } else {
      hnew[i][0] = hnew[i][1] = hnew[i][2] = hnew[i][3] = 0.f;
    }
  }
  if (W1next) {
    __syncthreads();  // all GEMM1 LDS reads complete
    // stage h_new row-major, padded: As2[r][k] at As[r*68 + k]  (64*68 = 4352 < 8192)
#pragma unroll
    for (int i = 0; i < 4; i++) {
      float4 o = make_float4(hnew[i][0], hnew[i][1], hnew[i][2], hnew[i][3]);
      *(float4*)&As[(ty * 4 + i) * 68 + tx * 4] = o;
    }
    __syncthreads();
    float acc2[4][4] = {{0.f}};
    const float4* W1V = (const float4*)W1next;
#pragma unroll 4
    for (int k = 0; k < 64; k++) {
      float av[4];
#pragma unroll
      for (int i = 0; i < 4; i++) av[i] = As[(ty * 4 + i) * 68 + k];
      float4 bb = W1V[k * 16 + tx];
      float bv[4] = {bb.x, bb.y, bb.z, bb.w};
#pragma unroll
      for (int i = 0; i < 4; i++)
#pragma unroll
        for (int j = 0; j < 4; j++) acc2[i][j] = fmaf(av[i], bv[j], acc2[i][j]);
    }
#pragma unroll
    for (int i = 0; i < 4; i++) {
      int n = n0 + ty * 4 + i;
      if (n < n_nodes) {
        float4 o = make_float4(acc2[i][0], acc2[i][1], acc2[i][2], acc2[i][3]);
        *(float4*)&hW_out[(size_t)n * 64 + tx * 4] = o;
      }
    }
  }
}

// ---------------- pooling: mean/max/sum per graph ----------------
__global__ __launch_bounds__(256) void pool_kernel(const float* __restrict__ h,
                                                   const int* __restrict__ batch,
                                                   float* __restrict__ pooled, int n_nodes) {
  int b = blockIdx.x;
  __shared__ int se[2];
  if (threadIdx.x == 0) se[0] = lower_bound_dev(batch, n_nodes, b);
  if (threadIdx.x == 1) se[1] = lower_bound_dev(batch, n_nodes, b + 1);
  __syncthreads();
  int start = se[0], end = se[1];
  int lane = threadIdx.x & 63, wave = threadIdx.x >> 6;
  float s = 0.f, m = -INFINITY;
  for (int i = start + wave; i < end; i += 4) {
    float v = h[(size_t)i * 64 + lane];
    s += v;
    m = fmaxf(m, v);
  }
  __shared__ float ss[4][64], mm[4][64];
  ss[wave][lane] = s;
  mm[wave][lane] = m;
  __syncthreads();
  if (wave == 0) {
    s = ss[0][lane] + ss[1][lane] + ss[2][lane] + ss[3][lane];
    m = fmaxf(fmaxf(mm[0][lane], mm[1][lane]), fmaxf(mm[2][lane], mm[3][lane]));
    int cnt = end - start;
    float mean = (cnt > 0) ? s / (float)cnt : 0.f;
    if (cnt == 0) { m = 0.f; s = 0.f; }
    pooled[(size_t)b * 192 + lane] = mean;
    pooled[(size_t)b * 192 + 64 + lane] = m;
    pooled[(size_t)b * 192 + 128 + lane] = s;
  }
}

// ---------------- head MLP per graph ----------------
__global__ __launch_bounds__(128) void mlp_kernel(
    const float* __restrict__ pooled, const float* __restrict__ glob,
    const float* __restrict__ W_gproj, const float* __restrict__ b_gproj,
    const float* __restrict__ g_gln, const float* __restrict__ b_gln,
    const float* __restrict__ W_c1, const float* __restrict__ b_c1,
    const float* __restrict__ g_cln, const float* __restrict__ b_cln,
    const float* __restrict__ W_c2, const float* __restrict__ b_c2,
    const float* __restrict__ W_head, const float* __restrict__ b_head,
    float* __restrict__ out) {
  int b = blockIdx.x;
  int tid = threadIdx.x;  // 128 threads
  __shared__ float c[256];
  __shared__ float c1s[128];
  __shared__ float c2s[64];
  __shared__ float sred[2][2];
  c[tid] = pooled[(size_t)b * 192 + tid];
  if (tid < 64) c[128 + tid] = pooled[(size_t)b * 192 + 128 + tid];
  if (tid < 64) {
    const float* gf = glob + (size_t)b * 32;
    float acc = b_gproj[tid];
#pragma unroll
    for (int k = 0; k < 32; k++) acc = fmaf(gf[k], W_gproj[(size_t)k * 64 + tid], acc);
    acc = fmaxf(acc, 0.f);
    float s = acc;
    for (int o = 32; o; o >>= 1) s += __shfl_xor(s, o);
    float mu = s * (1.f / 64.f);
    float d = acc - mu;
    float v = d * d;
    for (int o = 32; o; o >>= 1) v += __shfl_xor(v, o);
    float r = rsqrtf(v * (1.f / 64.f) + 1e-5f);
    c[192 + tid] = d * r * g_gln[tid] + b_gln[tid];
  }
  __syncthreads();
  float acc = b_c1[tid];
  for (int k = 0; k < 256; k++) acc = fmaf(c[k], W_c1[(size_t)k * 128 + tid], acc);
  acc = fmaxf(acc, 0.f);
  float s = acc;
  for (int o = 32; o; o >>= 1) s += __shfl_xor(s, o);
  if ((tid & 63) == 0) sred[0][tid >> 6] = s;
  __syncthreads();
  float mu = (sred[0][0] + sred[0][1]) * (1.f / 128.f);
  float d = acc - mu;
  float v = d * d;
  for (int o = 32; o; o >>= 1) v += __shfl_xor(v, o);
  if ((tid & 63) == 0) sred[1][tid >> 6] = v;
  __syncthreads();
  float var = (sred[1][0] + sred[1][1]) * (1.f / 128.f);
  c1s[tid] = d * rsqrtf(var + 1e-5f) * g_cln[tid] + b_cln[tid];
  __syncthreads();
  if (tid < 64) {
    float a2 = b_c2[tid];
    for (int k = 0; k < 128; k++) a2 = fmaf(c1s[k], W_c2[(size_t)k * 64 + tid], a2);
    c2s[tid] = fmaxf(a2, 0.f);
  }
  __syncthreads();
  if (tid < 9) {
    float a3 = b_head[tid];
#pragma unroll
    for (int k = 0; k < 64; k++) a3 = fmaf(c2s[k], W_head[(size_t)k * 9 + tid], a3);
    out[(size_t)b * 9 + tid] = a3;
  }
}

extern "C" void kernel_launch(void* const* d_in, const int* in_sizes, int n_in,
                              void* d_out, int out_size, void* d_ws, size_t ws_size,
                              hipStream_t stream) {
  const float* x       = (const float*)d_in[0];
  const int* edge_index= (const int*)d_in[1];
  const float* edge_attr=(const float*)d_in[2];
  const int* gtype     = (const int*)d_in[3];
  const int* batch     = (const int*)d_in[4];
  const float* glob    = (const float*)d_in[5];
  const float* W_embed = (const float*)d_in[6];
  const float* b_embed = (const float*)d_in[7];
  const float* g_eln   = (const float*)d_in[8];
  const float* b_eln   = (const float*)d_in[9];
  const float* gate_emb= (const float*)d_in[10];
  const float* W_msg   = (const float*)d_in[11];
  const float* b_msg   = (const float*)d_in[12];
  const float* W_upd   = (const float*)d_in[13];
  const float* b_upd   = (const float*)d_in[14];
  const float* W_gproj = (const float*)d_in[15];
  const float* b_gproj = (const float*)d_in[16];
  const float* g_gln   = (const float*)d_in[17];
  const float* b_gln   = (const float*)d_in[18];
  const float* W_c1    = (const float*)d_in[19];
  const float* b_c1    = (const float*)d_in[20];
  const float* g_cln   = (const float*)d_in[21];
  const float* b_cln   = (const float*)d_in[22];
  const float* W_c2    = (const float*)d_in[23];
  const float* b_c2    = (const float*)d_in[24];
  const float* W_head  = (const float*)d_in[25];
  const float* b_head  = (const float*)d_in[26];

  const int N = in_sizes[0] / 16;
  const int E = in_sizes[1] / 2;
  const int B = in_sizes[5] / 32;
  const int L = in_sizes[12] / 64;

  const int* src = edge_index;
  const int* dst = edge_index + E;

  char* ws = (char*)d_ws;
  size_t off = 0;
  auto alloc = [&](size_t bytes) -> void* {
    void* p = ws + off;
    off += (bytes + 255) & ~(size_t)255;
    return p;
  };
  float* h      = (float*)alloc((size_t)N * 64 * 4);
  float* hW     = (float*)alloc((size_t)N * 64 * 4);
  float* agg    = (float*)alloc((size_t)N * 64 * 4);
  float* geW    = (float*)alloc((size_t)L * 20 * 64 * 4);
  float* pooled = (float*)alloc((size_t)B * 192 * 4);
  int nC4 = (N + 3) / 4;                       // counts padded to int4
  int* counts   = (int*)alloc((size_t)nC4 * 16);
  int* row_ptr  = (int*)alloc((size_t)(N + 1) * 4);
  int* nextp    = (int*)alloc((size_t)N * 4);
  int nb = (N + 1023) / 1024;
  int* blocksums= (int*)alloc((size_t)nb * 4);
  int* perm     = (int*)alloc((size_t)E * 4);
  int* epack0   = (int*)alloc((size_t)E * 4);
  int* epack    = (int*)alloc((size_t)E * 4);
  float* eap    = (float*)alloc((size_t)E * 8 * 4);

  zero_kernel<<<(nC4 + 255) / 256, 256, 0, stream>>>((int4*)counts, nC4);
  count_pack_kernel<<<(E + 255) / 256, 256, 0, stream>>>(dst, src, gtype, counts, epack0, E);
  scan_phase1<<<nb, 256, 0, stream>>>(counts, row_ptr, blocksums, N);
  scan_phase2<<<1, 64, 0, stream>>>(blocksums, nb);
  scan_phase3<<<(N + 255) / 256, 256, 0, stream>>>(row_ptr, blocksums, nextp, N, E);
  {
    int nchunks = (E + SP_EDGES_PER_BLOCK - 1) / SP_EDGES_PER_BLOCK;
    scatter_perm_binned<<<nchunks * 8, 256, 0, stream>>>(dst, nextp, perm, E, N);
  }
  gather_build<<<(E + 255) / 256, 256, 0, stream>>>(perm, epack0, edge_attr, epack, eap, E);
  gew_kernel<<<(L * 20 + 3) / 4, 256, 0, stream>>>(gate_emb, W_msg, geW, L * 20);
  embed_kernel<<<(N + 3) / 4, 256, 0, stream>>>(x, W_embed, b_embed, g_eln, b_eln, h, N);

  nodelin_kernel<<<(N + 63) / 64, 256, 0, stream>>>(h, W_msg, hW, N);
  for (int l = 0; l < L; l++) {
    edge_kernel<<<(N + 3) / 4, 256, 0, stream>>>(hW, epack, eap, row_ptr,
                                                 W_msg + (size_t)l * 88 * 64, b_msg + (size_t)l * 64,
                                                 geW + (size_t)l * 20 * 64, agg, N);
    const float* W1next = (l + 1 < L) ? (W_msg + (size_t)(l + 1) * 88 * 64) : nullptr;
    update_fused_kernel<<<(N + 63) / 64, 256, 0, stream>>>(h, agg, W_upd + (size_t)l * 128 * 64,
                                                           b_upd + (size_t)l * 64, W1next, h, hW, N);
  }

  pool_kernel<<<B, 256, 0, stream>>>(h, batch, pooled, N);
  mlp_kernel<<<B, 128, 0, stream>>>(pooled, glob, W_gproj, b_gproj, g_gln, b_gln,
                                    W_c1, b_c1, g_cln, b_cln, W_c2, b_c2,
                                    W_head, b_head, (float*)d_out);
}

// Round 8
// 462.779 us; speedup vs baseline: 1.9541x; 1.0092x over previous
//
#include <hip/hip_runtime.h>

__device__ __forceinline__ int rfl(int v) { return __builtin_amdgcn_readfirstlane(v); }

__device__ __forceinline__ int lower_bound_dev(const int* __restrict__ a, int n, int v) {
  int lo = 0, hi = n;
  while (lo < hi) { int mid = (lo + hi) >> 1; if (a[mid] < v) lo = mid + 1; else hi = mid; }
  return lo;
}

// ---------------- fast zero ----------------
__global__ void zero_kernel(int4* __restrict__ p, int n4) {
  int i = blockIdx.x * 256 + threadIdx.x;
  if (i < n4) p[i] = make_int4(0, 0, 0, 0);
}

// ---------------- CSR build ----------------
__global__ void count_pack_kernel(const int* __restrict__ dst, const int* __restrict__ src,
                                  const int* __restrict__ gt, int* __restrict__ counts,
                                  int* __restrict__ epack0, int E) {
  int e = blockIdx.x * 256 + threadIdx.x;
  if (e < E) {
    atomicAdd(&counts[dst[e]], 1);
    epack0[e] = (gt[e] << 20) | src[e];
  }
}

__global__ __launch_bounds__(256) void scan_phase1(const int* __restrict__ counts,
                                                   int* __restrict__ row_ptr,
                                                   int* __restrict__ blocksums, int n) {
  int tid = threadIdx.x;
  int i0 = blockIdx.x * 1024 + tid * 4;
  int4 c = make_int4(0, 0, 0, 0);
  if (i0 + 3 < n) {
    c = *(const int4*)(counts + i0);
  } else {
    if (i0 + 0 < n) c.x = counts[i0 + 0];
    if (i0 + 1 < n) c.y = counts[i0 + 1];
    if (i0 + 2 < n) c.z = counts[i0 + 2];
    if (i0 + 3 < n) c.w = counts[i0 + 3];
  }
  int s = c.x + c.y + c.z + c.w;
  int lane = tid & 63, wave = tid >> 6;
  int v = s;
  for (int o = 1; o < 64; o <<= 1) { int u = __shfl_up(v, o); if (lane >= o) v += u; }
  __shared__ int wsum[4];
  if (lane == 63) wsum[wave] = v;
  __syncthreads();
  int woff = 0;
  for (int w = 0; w < wave; w++) woff += wsum[w];
  int excl = woff + (v - s);
  if (tid == 255) blocksums[blockIdx.x] = woff + v;
  int p0 = excl, p1 = p0 + c.x, p2 = p1 + c.y, p3 = p2 + c.z;
  if (i0 + 3 < n) {
    *(int4*)(row_ptr + i0) = make_int4(p0, p1, p2, p3);
  } else {
    if (i0 + 0 < n) row_ptr[i0 + 0] = p0;
    if (i0 + 1 < n) row_ptr[i0 + 1] = p1;
    if (i0 + 2 < n) row_ptr[i0 + 2] = p2;
    if (i0 + 3 < n) row_ptr[i0 + 3] = p3;
  }
}

__global__ __launch_bounds__(64) void scan_phase2(int* __restrict__ blocksums, int nb) {
  int carry = 0;
  for (int base = 0; base < nb; base += 64) {
    int i = base + (int)threadIdx.x;
    int v = (i < nb) ? blocksums[i] : 0;
    int inc = v;
    for (int o = 1; o < 64; o <<= 1) { int u = __shfl_up(inc, o); if ((int)threadIdx.x >= o) inc += u; }
    if (i < nb) blocksums[i] = carry + inc - v;
    carry += __shfl(inc, 63);
  }
}

__global__ __launch_bounds__(256) void scan_phase3(int* __restrict__ row_ptr,
                                                   const int* __restrict__ blocksums,
                                                   int* __restrict__ nextp, int n, int E) {
  int i = blockIdx.x * 256 + threadIdx.x;
  if (i < n) {
    int v = row_ptr[i] + blocksums[i >> 10];
    row_ptr[i] = v;
    nextp[i] = v;
  }
  if (i == 0) row_ptr[n] = E;
}

// XCD-binned scatter (see R4 notes): keeps each perm region's writes on one XCD L2.
#define SP_EDGES_PER_BLOCK 2048
__global__ __launch_bounds__(256) void scatter_perm_binned(const int* __restrict__ dst,
                                                           int* __restrict__ nextp,
                                                           int* __restrict__ perm,
                                                           int E, int n_nodes) {
  int phase = blockIdx.x & 7;
  int chunk = blockIdx.x >> 3;
  int lo = (int)(((long long)phase * n_nodes) >> 3);
  int hi = (int)(((long long)(phase + 1) * n_nodes) >> 3);
  int base = chunk * SP_EDGES_PER_BLOCK + threadIdx.x * 8;
#pragma unroll
  for (int half = 0; half < 2; half++) {
    int b = base + half * 4;
    if (b >= E) break;
    int4 d;
    if (b + 3 < E) {
      d = *(const int4*)(dst + b);
    } else {
      d.x = dst[b];
      d.y = (b + 1 < E) ? dst[b + 1] : -1;
      d.z = (b + 2 < E) ? dst[b + 2] : -1;
      d.w = (b + 3 < E) ? dst[b + 3] : -1;
    }
    if (d.x >= lo && d.x < hi) { int p = atomicAdd(&nextp[d.x], 1); perm[p] = b + 0; }
    if (d.y >= lo && d.y < hi) { int p = atomicAdd(&nextp[d.y], 1); perm[p] = b + 1; }
    if (d.z >= lo && d.z < hi) { int p = atomicAdd(&nextp[d.z], 1); perm[p] = b + 2; }
    if (d.w >= lo && d.w < hi) { int p = atomicAdd(&nextp[d.w], 1); perm[p] = b + 3; }
  }
}

__global__ void gather_build(const int* __restrict__ perm, const int* __restrict__ epack0,
                             const float* __restrict__ edge_attr,
                             int* __restrict__ epack, float* __restrict__ eap, int E) {
  int idx = blockIdx.x * 256 + threadIdx.x;
  if (idx < E) {
    int e = perm[idx];
    epack[idx] = epack0[e];
    const float4* s = (const float4*)(edge_attr + (size_t)e * 8);
    float4 a0 = s[0], a1 = s[1];
    float4* d = (float4*)(eap + (size_t)idx * 8);
    d[0] = a0; d[1] = a1;
  }
}

// ---------------- gate-embedding @ W3 table ----------------
__global__ void gew_kernel(const float* __restrict__ gate_emb, const float* __restrict__ W_msg,
                           float* __restrict__ geW, int nrows) {
  int tid = threadIdx.x;
  int lane = tid & 63;
  int row = blockIdx.x * 4 + (tid >> 6);
  if (row >= nrows) return;
  int l = row / 20, t = row % 20;
  const float* ge = gate_emb + ((size_t)l * 20 + t) * 16;
  const float* W3 = W_msg + (size_t)l * 88 * 64 + 72 * 64;
  float acc = 0.f;
#pragma unroll
  for (int k = 0; k < 16; k++) acc = fmaf(ge[k], W3[(size_t)k * 64 + lane], acc);
  geW[(size_t)row * 64 + lane] = acc;
}

// ---------------- node embed ----------------
__global__ __launch_bounds__(256) void embed_kernel(const float* __restrict__ x,
                                                    const float* __restrict__ W,
                                                    const float* __restrict__ b,
                                                    const float* __restrict__ gamma,
                                                    const float* __restrict__ beta,
                                                    float* __restrict__ h, int n_nodes) {
  __shared__ float Ws[16 * 64];
  int tid = threadIdx.x;
  for (int i = tid; i < 16 * 64; i += 256) Ws[i] = W[i];
  __syncthreads();
  int lane = tid & 63;
  int n = blockIdx.x * 4 + (tid >> 6);
  if (n >= n_nodes) return;
  const float* xr = x + (size_t)n * 16;
  float acc = b[lane];
#pragma unroll
  for (int k = 0; k < 16; k++) acc = fmaf(xr[k], Ws[k * 64 + lane], acc);
  acc = fmaxf(acc, 0.f);
  float s = acc;
  for (int o = 32; o; o >>= 1) s += __shfl_xor(s, o);
  float mu = s * (1.f / 64.f);
  float d = acc - mu;
  float v = d * d;
  for (int o = 32; o; o >>= 1) v += __shfl_xor(v, o);
  float r = rsqrtf(v * (1.f / 64.f) + 1e-5f);
  h[(size_t)n * 64 + lane] = d * r * gamma[lane] + beta[lane];
}

// ---- tiled GEMM: C = A @ W (layer-0 hW); swizzled A tile, W from L1 ----
__global__ __launch_bounds__(256) void nodelin_kernel(const float* __restrict__ A,
                                                      const float* __restrict__ W,
                                                      float* __restrict__ C, int n_nodes) {
  __shared__ float As[64 * 64];
  int tid = threadIdx.x;
  int n0 = blockIdx.x * 64;
#pragma unroll
  for (int i = 0; i < 4; i++) {
    int flat = (tid + i * 256) * 4;
    int r = flat >> 6, k = flat & 63;
    float4 f = make_float4(0.f, 0.f, 0.f, 0.f);
    int n = n0 + r;
    if (n < n_nodes) f = *(const float4*)(A + (size_t)n * 64 + k);
    int rp = r ^ (((k >> 2) & 7) << 2);
    As[(k + 0) * 64 + rp] = f.x;
    As[(k + 1) * 64 + rp] = f.y;
    As[(k + 2) * 64 + rp] = f.z;
    As[(k + 3) * 64 + rp] = f.w;
  }
  __syncthreads();
  int tx = tid & 15, ty = tid >> 4;
  float acc[4][4] = {{0.f}};
  const float4* WV = (const float4*)W;
#pragma unroll 4
  for (int k = 0; k < 64; k++) {
    float4 a = *(const float4*)&As[k * 64 + ((ty * 4) ^ (((k >> 2) & 7) << 2))];
    float4 bb = WV[k * 16 + tx];
    float av[4] = {a.x, a.y, a.z, a.w};
    float bv[4] = {bb.x, bb.y, bb.z, bb.w};
#pragma unroll
    for (int i = 0; i < 4; i++)
#pragma unroll
      for (int j = 0; j < 4; j++) acc[i][j] = fmaf(av[i], bv[j], acc[i][j]);
  }
#pragma unroll
  for (int i = 0; i < 4; i++) {
    int n = n0 + ty * 4 + i;
    if (n < n_nodes) {
      float4 o = make_float4(acc[i][0], acc[i][1], acc[i][2], acc[i][3]);
      *(float4*)&C[(size_t)n * 64 + tx * 4] = o;
    }
  }
}

// -------- edge stage: __launch_bounds__(256,4) => VGPR cap 128, real ILP-4 --------
__global__ __launch_bounds__(256, 4) void edge_kernel(const float* __restrict__ hW,
                                                      const int* __restrict__ epack,
                                                      const float* __restrict__ eap,
                                                      const int* __restrict__ row_ptr,
                                                      const float* __restrict__ W_msg_l,
                                                      const float* __restrict__ b_msg_l,
                                                      const float* __restrict__ geW_l,
                                                      float* __restrict__ agg, int n_nodes) {
  int tid = threadIdx.x;
  int lane = tid & 63;
  int n = blockIdx.x * 4 + (tid >> 6);
  if (n >= n_nodes) return;
  float w2[8];
#pragma unroll
  for (int k = 0; k < 8; k++) w2[k] = W_msg_l[(size_t)(64 + k) * 64 + lane];
  float bm = b_msg_l[lane];
  int beg = rfl(row_ptr[n]);
  int end = rfl(row_ptr[n + 1]);
  float acc0 = 0.f, acc1 = 0.f, acc2 = 0.f, acc3 = 0.f;
  int idx = beg;
  for (; idx + 4 <= end; idx += 4) {
    // ---- issue ALL loads of the group before any consumer ----
    int p0 = rfl(epack[idx + 0]);
    int p1 = rfl(epack[idx + 1]);
    int p2 = rfl(epack[idx + 2]);
    int p3 = rfl(epack[idx + 3]);
    int s0 = p0 & 0xFFFFF, t0 = p0 >> 20;
    int s1 = p1 & 0xFFFFF, t1 = p1 >> 20;
    int s2 = p2 & 0xFFFFF, t2 = p2 >> 20;
    int s3 = p3 & 0xFFFFF, t3 = p3 >> 20;
    float g0 = hW[(size_t)s0 * 64 + lane];
    float g1 = hW[(size_t)s1 * 64 + lane];
    float g2 = hW[(size_t)s2 * 64 + lane];
    float g3 = hW[(size_t)s3 * 64 + lane];
    float e0 = geW_l[t0 * 64 + lane];
    float e1 = geW_l[t1 * 64 + lane];
    float e2 = geW_l[t2 * 64 + lane];
    float e3 = geW_l[t3 * 64 + lane];
    const float4* ep = (const float4*)(eap + (size_t)idx * 8);
    float4 a00 = ep[0], a01 = ep[1], a10 = ep[2], a11 = ep[3];
    float4 a20 = ep[4], a21 = ep[5], a30 = ep[6], a31 = ep[7];
    // ---- compute (4 independent chains, 4 accumulators) ----
    float v0 = g0 + e0 + bm;
    v0 = fmaf(a00.x, w2[0], v0); v0 = fmaf(a00.y, w2[1], v0);
    v0 = fmaf(a00.z, w2[2], v0); v0 = fmaf(a00.w, w2[3], v0);
    v0 = fmaf(a01.x, w2[4], v0); v0 = fmaf(a01.y, w2[5], v0);
    v0 = fmaf(a01.z, w2[6], v0); v0 = fmaf(a01.w, w2[7], v0);
    float v1 = g1 + e1 + bm;
    v1 = fmaf(a10.x, w2[0], v1); v1 = fmaf(a10.y, w2[1], v1);
    v1 = fmaf(a10.z, w2[2], v1); v1 = fmaf(a10.w, w2[3], v1);
    v1 = fmaf(a11.x, w2[4], v1); v1 = fmaf(a11.y, w2[5], v1);
    v1 = fmaf(a11.z, w2[6], v1); v1 = fmaf(a11.w, w2[7], v1);
    float v2 = g2 + e2 + bm;
    v2 = fmaf(a20.x, w2[0], v2); v2 = fmaf(a20.y, w2[1], v2);
    v2 = fmaf(a20.z, w2[2], v2); v2 = fmaf(a20.w, w2[3], v2);
    v2 = fmaf(a21.x, w2[4], v2); v2 = fmaf(a21.y, w2[5], v2);
    v2 = fmaf(a21.z, w2[6], v2); v2 = fmaf(a21.w, w2[7], v2);
    float v3 = g3 + e3 + bm;
    v3 = fmaf(a30.x, w2[0], v3); v3 = fmaf(a30.y, w2[1], v3);
    v3 = fmaf(a30.z, w2[2], v3); v3 = fmaf(a30.w, w2[3], v3);
    v3 = fmaf(a31.x, w2[4], v3); v3 = fmaf(a31.y, w2[5], v3);
    v3 = fmaf(a31.z, w2[6], v3); v3 = fmaf(a31.w, w2[7], v3);
    acc0 += fmaxf(v0, 0.f);
    acc1 += fmaxf(v1, 0.f);
    acc2 += fmaxf(v2, 0.f);
    acc3 += fmaxf(v3, 0.f);
  }
  for (; idx < end; idx++) {
    int p = rfl(epack[idx]);
    int s = p & 0xFFFFF, t = p >> 20;
    const float4* ep = (const float4*)(eap + (size_t)idx * 8);
    float4 a0 = ep[0], a1 = ep[1];
    float g = hW[(size_t)s * 64 + lane];
    float v = g + geW_l[t * 64 + lane] + bm;
    v = fmaf(a0.x, w2[0], v); v = fmaf(a0.y, w2[1], v);
    v = fmaf(a0.z, w2[2], v); v = fmaf(a0.w, w2[3], v);
    v = fmaf(a1.x, w2[4], v); v = fmaf(a1.y, w2[5], v);
    v = fmaf(a1.z, w2[6], v); v = fmaf(a1.w, w2[7], v);
    acc0 += fmaxf(v, 0.f);
  }
  agg[(size_t)n * 64 + lane] = (acc0 + acc1) + (acc2 + acc3);
}

// -------- fused update + next-layer hW --------
__global__ __launch_bounds__(256) void update_fused_kernel(const float* __restrict__ h,
                                                           const float* __restrict__ agg,
                                                           const float* __restrict__ Wu,
                                                           const float* __restrict__ bu,
                                                           const float* __restrict__ W1next,
                                                           float* __restrict__ h_out,
                                                           float* __restrict__ hW_out,
                                                           int n_nodes) {
  __shared__ float As[128 * 64];
  int tid = threadIdx.x;
  int n0 = blockIdx.x * 64;
#pragma unroll
  for (int i = 0; i < 8; i++) {
    int flat = (tid + i * 256) * 4;
    int r = flat >> 7, k = flat & 127;
    float4 f = make_float4(0.f, 0.f, 0.f, 0.f);
    int n = n0 + r;
    if (n < n_nodes) {
      const float* sp = (k < 64) ? (h + (size_t)n * 64 + k) : (agg + (size_t)n * 64 + (k - 64));
      f = *(const float4*)sp;
    }
    int rp = r ^ (((k >> 2) & 7) << 2);
    As[(k + 0) * 64 + rp] = f.x;
    As[(k + 1) * 64 + rp] = f.y;
    As[(k + 2) * 64 + rp] = f.z;
    As[(k + 3) * 64 + rp] = f.w;
  }
  __syncthreads();
  int tx = tid & 15, ty = tid >> 4;
  float acc[4][4] = {{0.f}};
  const float4* WuV = (const float4*)Wu;
#pragma unroll 4
  for (int k = 0; k < 128; k++) {
    float4 a = *(const float4*)&As[k * 64 + ((ty * 4) ^ (((k >> 2) & 7) << 2))];
    float4 bb = WuV[k * 16 + tx];
    float av[4] = {a.x, a.y, a.z, a.w};
    float bv[4] = {bb.x, bb.y, bb.z, bb.w};
#pragma unroll
    for (int i = 0; i < 4; i++)
#pragma unroll
      for (int j = 0; j < 4; j++) acc[i][j] = fmaf(av[i], bv[j], acc[i][j]);
  }
  float hnew[4][4];
  float4 bv4 = *(const float4*)&bu[tx * 4];
#pragma unroll
  for (int i = 0; i < 4; i++) {
    int n = n0 + ty * 4 + i;
    if (n < n_nodes) {
      float4 hv = *(const float4*)&h[(size_t)n * 64 + tx * 4];
      hnew[i][0] = hv.x + acc[i][0] + bv4.x;
      hnew[i][1] = hv.y + acc[i][1] + bv4.y;
      hnew[i][2] = hv.z + acc[i][2] + bv4.z;
      hnew[i][3] = hv.w + acc[i][3] + bv4.w;
      float4 o = make_float4(hnew[i][0], hnew[i][1], hnew[i][2], hnew[i][3]);
      *(float4*)&h_out[(size_t)n * 64 + tx * 4] = o;
    } else {
      hnew[i][0] = hnew[i][1] = hnew[i][2] = hnew[i][3] = 0.f;
    }
  }
  if (W1next) {
    __syncthreads();
#pragma unroll
    for (int i = 0; i < 4; i++) {
      float4 o = make_float4(hnew[i][0], hnew[i][1], hnew[i][2], hnew[i][3]);
      *(float4*)&As[(ty * 4 + i) * 68 + tx * 4] = o;
    }
    __syncthreads();
    float acc2[4][4] = {{0.f}};
    const float4* W1V = (const float4*)W1next;
#pragma unroll 4
    for (int k = 0; k < 64; k++) {
      float av[4];
#pragma unroll
      for (int i = 0; i < 4; i++) av[i] = As[(ty * 4 + i) * 68 + k];
      float4 bb = W1V[k * 16 + tx];
      float bv[4] = {bb.x, bb.y, bb.z, bb.w};
#pragma unroll
      for (int i = 0; i < 4; i++)
#pragma unroll
        for (int j = 0; j < 4; j++) acc2[i][j] = fmaf(av[i], bv[j], acc2[i][j]);
    }
#pragma unroll
    for (int i = 0; i < 4; i++) {
      int n = n0 + ty * 4 + i;
      if (n < n_nodes) {
        float4 o = make_float4(acc2[i][0], acc2[i][1], acc2[i][2], acc2[i][3]);
        *(float4*)&hW_out[(size_t)n * 64 + tx * 4] = o;
      }
    }
  }
}

// ---------------- fused pooling + head MLP (one block per graph) ----------------
__global__ __launch_bounds__(256) void pool_mlp_kernel(
    const float* __restrict__ h, const int* __restrict__ batch,
    const float* __restrict__ glob,
    const float* __restrict__ W_gproj, const float* __restrict__ b_gproj,
    const float* __restrict__ g_gln, const float* __restrict__ b_gln,
    const float* __restrict__ W_c1, const float* __restrict__ b_c1,
    const float* __restrict__ g_cln, const float* __restrict__ b_cln,
    const float* __restrict__ W_c2, const float* __restrict__ b_c2,
    const float* __restrict__ W_head, const float* __restrict__ b_head,
    float* __restrict__ out, int n_nodes) {
  int b = blockIdx.x;
  int tid = threadIdx.x;
  int lane = tid & 63, wave = tid >> 6;
  __shared__ int se[2];
  if (tid < 2) se[tid] = lower_bound_dev(batch, n_nodes, b + tid);
  __syncthreads();
  int start = se[0], end = se[1];
  // ---- pooling ----
  float s = 0.f, m = -INFINITY;
  for (int i = start + wave; i < end; i += 4) {
    float v = h[(size_t)i * 64 + lane];
    s += v;
    m = fmaxf(m, v);
  }
  __shared__ float ss[4][64], mm[4][64];
  __shared__ float c[256];
  __shared__ float c1s[128];
  __shared__ float c2s[64];
  __shared__ float sred[2][2];
  ss[wave][lane] = s;
  mm[wave][lane] = m;
  __syncthreads();
  if (wave == 0) {
    float sum = ss[0][lane] + ss[1][lane] + ss[2][lane] + ss[3][lane];
    float mx = fmaxf(fmaxf(mm[0][lane], mm[1][lane]), fmaxf(mm[2][lane], mm[3][lane]));
    int cnt = end - start;
    float mean = (cnt > 0) ? sum / (float)cnt : 0.f;
    if (cnt == 0) { mx = 0.f; sum = 0.f; }
    c[lane] = mean;
    c[64 + lane] = mx;
    c[128 + lane] = sum;
  } else if (wave == 1) {
    // global proj + LN (64 lanes of wave 1)
    const float* gf = glob + (size_t)b * 32;
    float acc = b_gproj[lane];
#pragma unroll
    for (int k = 0; k < 32; k++) acc = fmaf(gf[k], W_gproj[(size_t)k * 64 + lane], acc);
    acc = fmaxf(acc, 0.f);
    float sg = acc;
    for (int o = 32; o; o >>= 1) sg += __shfl_xor(sg, o);
    float mu = sg * (1.f / 64.f);
    float d = acc - mu;
    float vv = d * d;
    for (int o = 32; o; o >>= 1) vv += __shfl_xor(vv, o);
    float r = rsqrtf(vv * (1.f / 64.f) + 1e-5f);
    c[192 + lane] = d * r * g_gln[lane] + b_gln[lane];
  }
  __syncthreads();
  // ---- c1 = relu(c @ W_c1 + b) ; LN over 128 ----
  float acc1v = 0.f;
  if (tid < 128) {
    acc1v = b_c1[tid];
    for (int k = 0; k < 256; k++) acc1v = fmaf(c[k], W_c1[(size_t)k * 128 + tid], acc1v);
    acc1v = fmaxf(acc1v, 0.f);
    float srd = acc1v;
    for (int o = 32; o; o >>= 1) srd += __shfl_xor(srd, o);
    if (lane == 0) sred[0][wave] = srd;
  }
  __syncthreads();
  float mu = (sred[0][0] + sred[0][1]) * (1.f / 128.f);
  float d1 = 0.f;
  if (tid < 128) {
    d1 = acc1v - mu;
    float vv = d1 * d1;
    for (int o = 32; o; o >>= 1) vv += __shfl_xor(vv, o);
    if (lane == 0) sred[1][wave] = vv;
  }
  __syncthreads();
  float var = (sred[1][0] + sred[1][1]) * (1.f / 128.f);
  if (tid < 128) c1s[tid] = d1 * rsqrtf(var + 1e-5f) * g_cln[tid] + b_cln[tid];
  __syncthreads();
  if (tid < 64) {
    float a2 = b_c2[tid];
    for (int k = 0; k < 128; k++) a2 = fmaf(c1s[k], W_c2[(size_t)k * 64 + tid], a2);
    c2s[tid] = fmaxf(a2, 0.f);
  }
  __syncthreads();
  if (tid < 9) {
    float a3 = b_head[tid];
#pragma unroll
    for (int k = 0; k < 64; k++) a3 = fmaf(c2s[k], W_head[(size_t)k * 9 + tid], a3);
    out[(size_t)b * 9 + tid] = a3;
  }
}

extern "C" void kernel_launch(void* const* d_in, const int* in_sizes, int n_in,
                              void* d_out, int out_size, void* d_ws, size_t ws_size,
                              hipStream_t stream) {
  const float* x       = (const float*)d_in[0];
  const int* edge_index= (const int*)d_in[1];
  const float* edge_attr=(const float*)d_in[2];
  const int* gtype     = (const int*)d_in[3];
  const int* batch     = (const int*)d_in[4];
  const float* glob    = (const float*)d_in[5];
  const float* W_embed = (const float*)d_in[6];
  const float* b_embed = (const float*)d_in[7];
  const float* g_eln   = (const float*)d_in[8];
  const float* b_eln   = (const float*)d_in[9];
  const float* gate_emb= (const float*)d_in[10];
  const float* W_msg   = (const float*)d_in[11];
  const float* b_msg   = (const float*)d_in[12];
  const float* W_upd   = (const float*)d_in[13];
  const float* b_upd   = (const float*)d_in[14];
  const float* W_gproj = (const float*)d_in[15];
  const float* b_gproj = (const float*)d_in[16];
  const float* g_gln   = (const float*)d_in[17];
  const float* b_gln   = (const float*)d_in[18];
  const float* W_c1    = (const float*)d_in[19];
  const float* b_c1    = (const float*)d_in[20];
  const float* g_cln   = (const float*)d_in[21];
  const float* b_cln   = (const float*)d_in[22];
  const float* W_c2    = (const float*)d_in[23];
  const float* b_c2    = (const float*)d_in[24];
  const float* W_head  = (const float*)d_in[25];
  const float* b_head  = (const float*)d_in[26];

  const int N = in_sizes[0] / 16;
  const int E = in_sizes[1] / 2;
  const int B = in_sizes[5] / 32;
  const int L = in_sizes[12] / 64;

  const int* src = edge_index;
  const int* dst = edge_index + E;

  char* ws = (char*)d_ws;
  size_t off = 0;
  auto alloc = [&](size_t bytes) -> void* {
    void* p = ws + off;
    off += (bytes + 255) & ~(size_t)255;
    return p;
  };
  float* h      = (float*)alloc((size_t)N * 64 * 4);
  float* hW     = (float*)alloc((size_t)N * 64 * 4);
  float* agg    = (float*)alloc((size_t)N * 64 * 4);
  float* geW    = (float*)alloc((size_t)L * 20 * 64 * 4);
  int nC4 = (N + 3) / 4;
  int* counts   = (int*)alloc((size_t)nC4 * 16);
  int* row_ptr  = (int*)alloc((size_t)(N + 1) * 4);
  int* nextp    = (int*)alloc((size_t)N * 4);
  int nb = (N + 1023) / 1024;
  int* blocksums= (int*)alloc((size_t)nb * 4);
  int* perm     = (int*)alloc((size_t)E * 4);
  int* epack0   = (int*)alloc((size_t)E * 4);
  int* epack    = (int*)alloc((size_t)E * 4);
  float* eap    = (float*)alloc((size_t)E * 8 * 4);

  zero_kernel<<<(nC4 + 255) / 256, 256, 0, stream>>>((int4*)counts, nC4);
  count_pack_kernel<<<(E + 255) / 256, 256, 0, stream>>>(dst, src, gtype, counts, epack0, E);
  scan_phase1<<<nb, 256, 0, stream>>>(counts, row_ptr, blocksums, N);
  scan_phase2<<<1, 64, 0, stream>>>(blocksums, nb);
  scan_phase3<<<(N + 255) / 256, 256, 0, stream>>>(row_ptr, blocksums, nextp, N, E);
  {
    int nchunks = (E + SP_EDGES_PER_BLOCK - 1) / SP_EDGES_PER_BLOCK;
    scatter_perm_binned<<<nchunks * 8, 256, 0, stream>>>(dst, nextp, perm, E, N);
  }
  gather_build<<<(E + 255) / 256, 256, 0, stream>>>(perm, epack0, edge_attr, epack, eap, E);
  gew_kernel<<<(L * 20 + 3) / 4, 256, 0, stream>>>(gate_emb, W_msg, geW, L * 20);
  embed_kernel<<<(N + 3) / 4, 256, 0, stream>>>(x, W_embed, b_embed, g_eln, b_eln, h, N);

  nodelin_kernel<<<(N + 63) / 64, 256, 0, stream>>>(h, W_msg, hW, N);
  for (int l = 0; l < L; l++) {
    edge_kernel<<<(N + 3) / 4, 256, 0, stream>>>(hW, epack, eap, row_ptr,
                                                 W_msg + (size_t)l * 88 * 64, b_msg + (size_t)l * 64,
                                                 geW + (size_t)l * 20 * 64, agg, N);
    const float* W1next = (l + 1 < L) ? (W_msg + (size_t)(l + 1) * 88 * 64) : nullptr;
    update_fused_kernel<<<(N + 63) / 64, 256, 0, stream>>>(h, agg, W_upd + (size_t)l * 128 * 64,
                                                           b_upd + (size_t)l * 64, W1next, h, hW, N);
  }

  pool_mlp_kernel<<<B, 256, 0, stream>>>(h, batch, glob, W_gproj, b_gproj, g_gln, b_gln,
                                         W_c1, b_c1, g_cln, b_cln, W_c2, b_c2,
                                         W_head, b_head, (float*)d_out, N);
}

// Round 9
// 445.323 us; speedup vs baseline: 2.0307x; 1.0392x over previous
//
#include <hip/hip_runtime.h>

__device__ __forceinline__ int rfl(int v) { return __builtin_amdgcn_readfirstlane(v); }

__device__ __forceinline__ int lower_bound_dev(const int* __restrict__ a, int n, int v) {
  int lo = 0, hi = n;
  while (lo < hi) { int mid = (lo + hi) >> 1; if (a[mid] < v) lo = mid + 1; else hi = mid; }
  return lo;
}

// ---------------- fast zero ----------------
__global__ void zero_kernel(int4* __restrict__ p, int n4) {
  int i = blockIdx.x * 256 + threadIdx.x;
  if (i < n4) p[i] = make_int4(0, 0, 0, 0);
}

// ---------------- CSR build ----------------
__global__ void count_pack_kernel(const int* __restrict__ dst, const int* __restrict__ src,
                                  const int* __restrict__ gt, int* __restrict__ counts,
                                  int* __restrict__ epack0, int E) {
  int e = blockIdx.x * 256 + threadIdx.x;
  if (e < E) {
    atomicAdd(&counts[dst[e]], 1);
    epack0[e] = (gt[e] << 20) | src[e];
  }
}

__global__ __launch_bounds__(256) void scan_phase1(const int* __restrict__ counts,
                                                   int* __restrict__ row_ptr,
                                                   int* __restrict__ blocksums, int n) {
  int tid = threadIdx.x;
  int i0 = blockIdx.x * 1024 + tid * 4;
  int4 c = make_int4(0, 0, 0, 0);
  if (i0 + 3 < n) {
    c = *(const int4*)(counts + i0);
  } else {
    if (i0 + 0 < n) c.x = counts[i0 + 0];
    if (i0 + 1 < n) c.y = counts[i0 + 1];
    if (i0 + 2 < n) c.z = counts[i0 + 2];
    if (i0 + 3 < n) c.w = counts[i0 + 3];
  }
  int s = c.x + c.y + c.z + c.w;
  int lane = tid & 63, wave = tid >> 6;
  int v = s;
  for (int o = 1; o < 64; o <<= 1) { int u = __shfl_up(v, o); if (lane >= o) v += u; }
  __shared__ int wsum[4];
  if (lane == 63) wsum[wave] = v;
  __syncthreads();
  int woff = 0;
  for (int w = 0; w < wave; w++) woff += wsum[w];
  int excl = woff + (v - s);
  if (tid == 255) blocksums[blockIdx.x] = woff + v;
  int p0 = excl, p1 = p0 + c.x, p2 = p1 + c.y, p3 = p2 + c.z;
  if (i0 + 3 < n) {
    *(int4*)(row_ptr + i0) = make_int4(p0, p1, p2, p3);
  } else {
    if (i0 + 0 < n) row_ptr[i0 + 0] = p0;
    if (i0 + 1 < n) row_ptr[i0 + 1] = p1;
    if (i0 + 2 < n) row_ptr[i0 + 2] = p2;
    if (i0 + 3 < n) row_ptr[i0 + 3] = p3;
  }
}

__global__ __launch_bounds__(64) void scan_phase2(int* __restrict__ blocksums, int nb) {
  int carry = 0;
  for (int base = 0; base < nb; base += 64) {
    int i = base + (int)threadIdx.x;
    int v = (i < nb) ? blocksums[i] : 0;
    int inc = v;
    for (int o = 1; o < 64; o <<= 1) { int u = __shfl_up(inc, o); if ((int)threadIdx.x >= o) inc += u; }
    if (i < nb) blocksums[i] = carry + inc - v;
    carry += __shfl(inc, 63);
  }
}

__global__ __launch_bounds__(256) void scan_phase3(int* __restrict__ row_ptr,
                                                   const int* __restrict__ blocksums,
                                                   int* __restrict__ nextp, int n, int E) {
  int i = blockIdx.x * 256 + threadIdx.x;
  if (i < n) {
    int v = row_ptr[i] + blocksums[i >> 10];
    row_ptr[i] = v;
    nextp[i] = v;
  }
  if (i == 0) row_ptr[n] = E;
}

// XCD-binned scatter (see R4 notes): keeps each perm region's writes on one XCD L2.
#define SP_EDGES_PER_BLOCK 2048
__global__ __launch_bounds__(256) void scatter_perm_binned(const int* __restrict__ dst,
                                                           int* __restrict__ nextp,
                                                           int* __restrict__ perm,
                                                           int E, int n_nodes) {
  int phase = blockIdx.x & 7;
  int chunk = blockIdx.x >> 3;
  int lo = (int)(((long long)phase * n_nodes) >> 3);
  int hi = (int)(((long long)(phase + 1) * n_nodes) >> 3);
  int base = chunk * SP_EDGES_PER_BLOCK + threadIdx.x * 8;
#pragma unroll
  for (int half = 0; half < 2; half++) {
    int b = base + half * 4;
    if (b >= E) break;
    int4 d;
    if (b + 3 < E) {
      d = *(const int4*)(dst + b);
    } else {
      d.x = dst[b];
      d.y = (b + 1 < E) ? dst[b + 1] : -1;
      d.z = (b + 2 < E) ? dst[b + 2] : -1;
      d.w = (b + 3 < E) ? dst[b + 3] : -1;
    }
    if (d.x >= lo && d.x < hi) { int p = atomicAdd(&nextp[d.x], 1); perm[p] = b + 0; }
    if (d.y >= lo && d.y < hi) { int p = atomicAdd(&nextp[d.y], 1); perm[p] = b + 1; }
    if (d.z >= lo && d.z < hi) { int p = atomicAdd(&nextp[d.z], 1); perm[p] = b + 2; }
    if (d.w >= lo && d.w < hi) { int p = atomicAdd(&nextp[d.w], 1); perm[p] = b + 3; }
  }
}

__global__ void gather_build(const int* __restrict__ perm, const int* __restrict__ epack0,
                             const float* __restrict__ edge_attr,
                             int* __restrict__ epack, float* __restrict__ eap, int E) {
  int idx = blockIdx.x * 256 + threadIdx.x;
  if (idx < E) {
    int e = perm[idx];
    epack[idx] = epack0[e];
    const float4* s = (const float4*)(edge_attr + (size_t)e * 8);
    float4 a0 = s[0], a1 = s[1];
    float4* d = (float4*)(eap + (size_t)idx * 8);
    d[0] = a0; d[1] = a1;
  }
}

// ---------------- gate-embedding @ W3 table ----------------
__global__ void gew_kernel(const float* __restrict__ gate_emb, const float* __restrict__ W_msg,
                           float* __restrict__ geW, int nrows) {
  int tid = threadIdx.x;
  int lane = tid & 63;
  int row = blockIdx.x * 4 + (tid >> 6);
  if (row >= nrows) return;
  int l = row / 20, t = row % 20;
  const float* ge = gate_emb + ((size_t)l * 20 + t) * 16;
  const float* W3 = W_msg + (size_t)l * 88 * 64 + 72 * 64;
  float acc = 0.f;
#pragma unroll
  for (int k = 0; k < 16; k++) acc = fmaf(ge[k], W3[(size_t)k * 64 + lane], acc);
  geW[(size_t)row * 64 + lane] = acc;
}

// ---------------- node embed ----------------
__global__ __launch_bounds__(256) void embed_kernel(const float* __restrict__ x,
                                                    const float* __restrict__ W,
                                                    const float* __restrict__ b,
                                                    const float* __restrict__ gamma,
                                                    const float* __restrict__ beta,
                                                    float* __restrict__ h, int n_nodes) {
  __shared__ float Ws[16 * 64];
  int tid = threadIdx.x;
  for (int i = tid; i < 16 * 64; i += 256) Ws[i] = W[i];
  __syncthreads();
  int lane = tid & 63;
  int n = blockIdx.x * 4 + (tid >> 6);
  if (n >= n_nodes) return;
  const float* xr = x + (size_t)n * 16;
  float acc = b[lane];
#pragma unroll
  for (int k = 0; k < 16; k++) acc = fmaf(xr[k], Ws[k * 64 + lane], acc);
  acc = fmaxf(acc, 0.f);
  float s = acc;
  for (int o = 32; o; o >>= 1) s += __shfl_xor(s, o);
  float mu = s * (1.f / 64.f);
  float d = acc - mu;
  float v = d * d;
  for (int o = 32; o; o >>= 1) v += __shfl_xor(v, o);
  float r = rsqrtf(v * (1.f / 64.f) + 1e-5f);
  h[(size_t)n * 64 + lane] = d * r * gamma[lane] + beta[lane];
}

// ---- tiled GEMM: C = A @ W (layer-0 hW); swizzled A tile, W from L1 ----
__global__ __launch_bounds__(256) void nodelin_kernel(const float* __restrict__ A,
                                                      const float* __restrict__ W,
                                                      float* __restrict__ C, int n_nodes) {
  __shared__ float As[64 * 64];
  int tid = threadIdx.x;
  int n0 = blockIdx.x * 64;
#pragma unroll
  for (int i = 0; i < 4; i++) {
    int flat = (tid + i * 256) * 4;
    int r = flat >> 6, k = flat & 63;
    float4 f = make_float4(0.f, 0.f, 0.f, 0.f);
    int n = n0 + r;
    if (n < n_nodes) f = *(const float4*)(A + (size_t)n * 64 + k);
    int rp = r ^ (((k >> 2) & 7) << 2);
    As[(k + 0) * 64 + rp] = f.x;
    As[(k + 1) * 64 + rp] = f.y;
    As[(k + 2) * 64 + rp] = f.z;
    As[(k + 3) * 64 + rp] = f.w;
  }
  __syncthreads();
  int tx = tid & 15, ty = tid >> 4;
  float acc[4][4] = {{0.f}};
  const float4* WV = (const float4*)W;
#pragma unroll 4
  for (int k = 0; k < 64; k++) {
    float4 a = *(const float4*)&As[k * 64 + ((ty * 4) ^ (((k >> 2) & 7) << 2))];
    float4 bb = WV[k * 16 + tx];
    float av[4] = {a.x, a.y, a.z, a.w};
    float bv[4] = {bb.x, bb.y, bb.z, bb.w};
#pragma unroll
    for (int i = 0; i < 4; i++)
#pragma unroll
      for (int j = 0; j < 4; j++) acc[i][j] = fmaf(av[i], bv[j], acc[i][j]);
  }
#pragma unroll
  for (int i = 0; i < 4; i++) {
    int n = n0 + ty * 4 + i;
    if (n < n_nodes) {
      float4 o = make_float4(acc[i][0], acc[i][1], acc[i][2], acc[i][3]);
      *(float4*)&C[(size_t)n * 64 + tx * 4] = o;
    }
  }
}

// -------- edge stage: __launch_bounds__(256,4) => VGPR cap 128, real ILP-4 --------
__global__ __launch_bounds__(256, 4) void edge_kernel(const float* __restrict__ hW,
                                                      const int* __restrict__ epack,
                                                      const float* __restrict__ eap,
                                                      const int* __restrict__ row_ptr,
                                                      const float* __restrict__ W_msg_l,
                                                      const float* __restrict__ b_msg_l,
                                                      const float* __restrict__ geW_l,
                                                      float* __restrict__ agg, int n_nodes) {
  int tid = threadIdx.x;
  int lane = tid & 63;
  int n = blockIdx.x * 4 + (tid >> 6);
  if (n >= n_nodes) return;
  float w2[8];
#pragma unroll
  for (int k = 0; k < 8; k++) w2[k] = W_msg_l[(size_t)(64 + k) * 64 + lane];
  float bm = b_msg_l[lane];
  int beg = rfl(row_ptr[n]);
  int end = rfl(row_ptr[n + 1]);
  float acc0 = 0.f, acc1 = 0.f, acc2 = 0.f, acc3 = 0.f;
  int idx = beg;
  for (; idx + 4 <= end; idx += 4) {
    int p0 = rfl(epack[idx + 0]);
    int p1 = rfl(epack[idx + 1]);
    int p2 = rfl(epack[idx + 2]);
    int p3 = rfl(epack[idx + 3]);
    int s0 = p0 & 0xFFFFF, t0 = p0 >> 20;
    int s1 = p1 & 0xFFFFF, t1 = p1 >> 20;
    int s2 = p2 & 0xFFFFF, t2 = p2 >> 20;
    int s3 = p3 & 0xFFFFF, t3 = p3 >> 20;
    float g0 = hW[(size_t)s0 * 64 + lane];
    float g1 = hW[(size_t)s1 * 64 + lane];
    float g2 = hW[(size_t)s2 * 64 + lane];
    float g3 = hW[(size_t)s3 * 64 + lane];
    float e0 = geW_l[t0 * 64 + lane];
    float e1 = geW_l[t1 * 64 + lane];
    float e2 = geW_l[t2 * 64 + lane];
    float e3 = geW_l[t3 * 64 + lane];
    const float4* ep = (const float4*)(eap + (size_t)idx * 8);
    float4 a00 = ep[0], a01 = ep[1], a10 = ep[2], a11 = ep[3];
    float4 a20 = ep[4], a21 = ep[5], a30 = ep[6], a31 = ep[7];
    float v0 = g0 + e0 + bm;
    v0 = fmaf(a00.x, w2[0], v0); v0 = fmaf(a00.y, w2[1], v0);
    v0 = fmaf(a00.z, w2[2], v0); v0 = fmaf(a00.w, w2[3], v0);
    v0 = fmaf(a01.x, w2[4], v0); v0 = fmaf(a01.y, w2[5], v0);
    v0 = fmaf(a01.z, w2[6], v0); v0 = fmaf(a01.w, w2[7], v0);
    float v1 = g1 + e1 + bm;
    v1 = fmaf(a10.x, w2[0], v1); v1 = fmaf(a10.y, w2[1], v1);
    v1 = fmaf(a10.z, w2[2], v1); v1 = fmaf(a10.w, w2[3], v1);
    v1 = fmaf(a11.x, w2[4], v1); v1 = fmaf(a11.y, w2[5], v1);
    v1 = fmaf(a11.z, w2[6], v1); v1 = fmaf(a11.w, w2[7], v1);
    float v2 = g2 + e2 + bm;
    v2 = fmaf(a20.x, w2[0], v2); v2 = fmaf(a20.y, w2[1], v2);
    v2 = fmaf(a20.z, w2[2], v2); v2 = fmaf(a20.w, w2[3], v2);
    v2 = fmaf(a21.x, w2[4], v2); v2 = fmaf(a21.y, w2[5], v2);
    v2 = fmaf(a21.z, w2[6], v2); v2 = fmaf(a21.w, w2[7], v2);
    float v3 = g3 + e3 + bm;
    v3 = fmaf(a30.x, w2[0], v3); v3 = fmaf(a30.y, w2[1], v3);
    v3 = fmaf(a30.z, w2[2], v3); v3 = fmaf(a30.w, w2[3], v3);
    v3 = fmaf(a31.x, w2[4], v3); v3 = fmaf(a31.y, w2[5], v3);
    v3 = fmaf(a31.z, w2[6], v3); v3 = fmaf(a31.w, w2[7], v3);
    acc0 += fmaxf(v0, 0.f);
    acc1 += fmaxf(v1, 0.f);
    acc2 += fmaxf(v2, 0.f);
    acc3 += fmaxf(v3, 0.f);
  }
  for (; idx < end; idx++) {
    int p = rfl(epack[idx]);
    int s = p & 0xFFFFF, t = p >> 20;
    const float4* ep = (const float4*)(eap + (size_t)idx * 8);
    float4 a0 = ep[0], a1 = ep[1];
    float g = hW[(size_t)s * 64 + lane];
    float v = g + geW_l[t * 64 + lane] + bm;
    v = fmaf(a0.x, w2[0], v); v = fmaf(a0.y, w2[1], v);
    v = fmaf(a0.z, w2[2], v); v = fmaf(a0.w, w2[3], v);
    v = fmaf(a1.x, w2[4], v); v = fmaf(a1.y, w2[5], v);
    v = fmaf(a1.z, w2[6], v); v = fmaf(a1.w, w2[7], v);
    acc0 += fmaxf(v, 0.f);
  }
  agg[(size_t)n * 64 + lane] = (acc0 + acc1) + (acc2 + acc3);
}

// -------- fused update + next-layer hW --------
__global__ __launch_bounds__(256) void update_fused_kernel(const float* __restrict__ h,
                                                           const float* __restrict__ agg,
                                                           const float* __restrict__ Wu,
                                                           const float* __restrict__ bu,
                                                           const float* __restrict__ W1next,
                                                           float* __restrict__ h_out,
                                                           float* __restrict__ hW_out,
                                                           int n_nodes) {
  __shared__ float As[128 * 64];
  int tid = threadIdx.x;
  int n0 = blockIdx.x * 64;
#pragma unroll
  for (int i = 0; i < 8; i++) {
    int flat = (tid + i * 256) * 4;
    int r = flat >> 7, k = flat & 127;
    float4 f = make_float4(0.f, 0.f, 0.f, 0.f);
    int n = n0 + r;
    if (n < n_nodes) {
      const float* sp = (k < 64) ? (h + (size_t)n * 64 + k) : (agg + (size_t)n * 64 + (k - 64));
      f = *(const float4*)sp;
    }
    int rp = r ^ (((k >> 2) & 7) << 2);
    As[(k + 0) * 64 + rp] = f.x;
    As[(k + 1) * 64 + rp] = f.y;
    As[(k + 2) * 64 + rp] = f.z;
    As[(k + 3) * 64 + rp] = f.w;
  }
  __syncthreads();
  int tx = tid & 15, ty = tid >> 4;
  float acc[4][4] = {{0.f}};
  const float4* WuV = (const float4*)Wu;
#pragma unroll 4
  for (int k = 0; k < 128; k++) {
    float4 a = *(const float4*)&As[k * 64 + ((ty * 4) ^ (((k >> 2) & 7) << 2))];
    float4 bb = WuV[k * 16 + tx];
    float av[4] = {a.x, a.y, a.z, a.w};
    float bv[4] = {bb.x, bb.y, bb.z, bb.w};
#pragma unroll
    for (int i = 0; i < 4; i++)
#pragma unroll
      for (int j = 0; j < 4; j++) acc[i][j] = fmaf(av[i], bv[j], acc[i][j]);
  }
  float hnew[4][4];
  float4 bv4 = *(const float4*)&bu[tx * 4];
#pragma unroll
  for (int i = 0; i < 4; i++) {
    int n = n0 + ty * 4 + i;
    if (n < n_nodes) {
      float4 hv = *(const float4*)&h[(size_t)n * 64 + tx * 4];
      hnew[i][0] = hv.x + acc[i][0] + bv4.x;
      hnew[i][1] = hv.y + acc[i][1] + bv4.y;
      hnew[i][2] = hv.z + acc[i][2] + bv4.z;
      hnew[i][3] = hv.w + acc[i][3] + bv4.w;
      float4 o = make_float4(hnew[i][0], hnew[i][1], hnew[i][2], hnew[i][3]);
      *(float4*)&h_out[(size_t)n * 64 + tx * 4] = o;
    } else {
      hnew[i][0] = hnew[i][1] = hnew[i][2] = hnew[i][3] = 0.f;
    }
  }
  if (W1next) {
    __syncthreads();
#pragma unroll
    for (int i = 0; i < 4; i++) {
      float4 o = make_float4(hnew[i][0], hnew[i][1], hnew[i][2], hnew[i][3]);
      *(float4*)&As[(ty * 4 + i) * 68 + tx * 4] = o;
    }
    __syncthreads();
    float acc2[4][4] = {{0.f}};
    const float4* W1V = (const float4*)W1next;
#pragma unroll 4
    for (int k = 0; k < 64; k++) {
      float av[4];
#pragma unroll
      for (int i = 0; i < 4; i++) av[i] = As[(ty * 4 + i) * 68 + k];
      float4 bb = W1V[k * 16 + tx];
      float bv[4] = {bb.x, bb.y, bb.z, bb.w};
#pragma unroll
      for (int i = 0; i < 4; i++)
#pragma unroll
        for (int j = 0; j < 4; j++) acc2[i][j] = fmaf(av[i], bv[j], acc2[i][j]);
    }
#pragma unroll
    for (int i = 0; i < 4; i++) {
      int n = n0 + ty * 4 + i;
      if (n < n_nodes) {
        float4 o = make_float4(acc2[i][0], acc2[i][1], acc2[i][2], acc2[i][3]);
        *(float4*)&hW_out[(size_t)n * 64 + tx * 4] = o;
      }
    }
  }
}

// ------- pooling stage 1: B*PSPLIT blocks, each reduces 1/PSPLIT of a graph -------
#define PSPLIT 8
__global__ __launch_bounds__(256) void pool_partial(const float* __restrict__ h,
                                                    const int* __restrict__ batch,
                                                    float* __restrict__ partials, int n_nodes) {
  int b = blockIdx.x / PSPLIT;
  int p = blockIdx.x % PSPLIT;
  int tid = threadIdx.x;
  int lane = tid & 63, wave = tid >> 6;
  __shared__ int se[2];
  if (tid < 2) se[tid] = lower_bound_dev(batch, n_nodes, b + tid);
  __syncthreads();
  int start = se[0], len = se[1] - se[0];
  int c0 = start + (int)(((long long)p * len) / PSPLIT);
  int c1 = start + (int)(((long long)(p + 1) * len) / PSPLIT);
  float s = 0.f, m = -INFINITY;
  for (int i = c0 + wave; i < c1; i += 4) {
    float v = h[(size_t)i * 64 + lane];
    s += v;
    m = fmaxf(m, v);
  }
  __shared__ float ss[4][64], mm[4][64];
  ss[wave][lane] = s;
  mm[wave][lane] = m;
  __syncthreads();
  if (wave == 0) {
    float sum = ss[0][lane] + ss[1][lane] + ss[2][lane] + ss[3][lane];
    float mx = fmaxf(fmaxf(mm[0][lane], mm[1][lane]), fmaxf(mm[2][lane], mm[3][lane]));
    float* dst = partials + ((size_t)(b * PSPLIT + p) * 2) * 64;
    dst[lane] = sum;
    dst[64 + lane] = mx;
  }
}

// ------- pooling stage 2 + head MLP (one block per graph) -------
__global__ __launch_bounds__(256) void pool_mlp_final(
    const float* __restrict__ partials, const int* __restrict__ batch,
    const float* __restrict__ glob,
    const float* __restrict__ W_gproj, const float* __restrict__ b_gproj,
    const float* __restrict__ g_gln, const float* __restrict__ b_gln,
    const float* __restrict__ W_c1, const float* __restrict__ b_c1,
    const float* __restrict__ g_cln, const float* __restrict__ b_cln,
    const float* __restrict__ W_c2, const float* __restrict__ b_c2,
    const float* __restrict__ W_head, const float* __restrict__ b_head,
    float* __restrict__ out, int n_nodes) {
  int b = blockIdx.x;
  int tid = threadIdx.x;
  int lane = tid & 63, wave = tid >> 6;
  __shared__ int se[2];
  if (tid < 2) se[tid] = lower_bound_dev(batch, n_nodes, b + tid);
  __shared__ float c[256];
  __shared__ float c1s[128];
  __shared__ float c2s[64];
  __shared__ float sred[2][2];
  __syncthreads();
  int cnt = se[1] - se[0];
  if (wave == 0) {
    // combine PSPLIT partials
    const float* pp = partials + ((size_t)b * PSPLIT * 2) * 64;
    float sum = 0.f, mx = -INFINITY;
#pragma unroll
    for (int p = 0; p < PSPLIT; p++) {
      sum += pp[(size_t)p * 128 + lane];
      mx = fmaxf(mx, pp[(size_t)p * 128 + 64 + lane]);
    }
    float mean = (cnt > 0) ? sum / (float)cnt : 0.f;
    if (cnt == 0) { mx = 0.f; sum = 0.f; }
    c[lane] = mean;
    c[64 + lane] = mx;
    c[128 + lane] = sum;
  } else if (wave == 1) {
    const float* gf = glob + (size_t)b * 32;
    float acc = b_gproj[lane];
#pragma unroll
    for (int k = 0; k < 32; k++) acc = fmaf(gf[k], W_gproj[(size_t)k * 64 + lane], acc);
    acc = fmaxf(acc, 0.f);
    float sg = acc;
    for (int o = 32; o; o >>= 1) sg += __shfl_xor(sg, o);
    float mu = sg * (1.f / 64.f);
    float d = acc - mu;
    float vv = d * d;
    for (int o = 32; o; o >>= 1) vv += __shfl_xor(vv, o);
    float r = rsqrtf(vv * (1.f / 64.f) + 1e-5f);
    c[192 + lane] = d * r * g_gln[lane] + b_gln[lane];
  }
  __syncthreads();
  float acc1v = 0.f;
  if (tid < 128) {
    acc1v = b_c1[tid];
    for (int k = 0; k < 256; k++) acc1v = fmaf(c[k], W_c1[(size_t)k * 128 + tid], acc1v);
    acc1v = fmaxf(acc1v, 0.f);
    float srd = acc1v;
    for (int o = 32; o; o >>= 1) srd += __shfl_xor(srd, o);
    if (lane == 0) sred[0][wave] = srd;
  }
  __syncthreads();
  float mu = (sred[0][0] + sred[0][1]) * (1.f / 128.f);
  float d1 = 0.f;
  if (tid < 128) {
    d1 = acc1v - mu;
    float vv = d1 * d1;
    for (int o = 32; o; o >>= 1) vv += __shfl_xor(vv, o);
    if (lane == 0) sred[1][wave] = vv;
  }
  __syncthreads();
  float var = (sred[1][0] + sred[1][1]) * (1.f / 128.f);
  if (tid < 128) c1s[tid] = d1 * rsqrtf(var + 1e-5f) * g_cln[tid] + b_cln[tid];
  __syncthreads();
  if (tid < 64) {
    float a2 = b_c2[tid];
    for (int k = 0; k < 128; k++) a2 = fmaf(c1s[k], W_c2[(size_t)k * 64 + tid], a2);
    c2s[tid] = fmaxf(a2, 0.f);
  }
  __syncthreads();
  if (tid < 9) {
    float a3 = b_head[tid];
#pragma unroll
    for (int k = 0; k < 64; k++) a3 = fmaf(c2s[k], W_head[(size_t)k * 9 + tid], a3);
    out[(size_t)b * 9 + tid] = a3;
  }
}

extern "C" void kernel_launch(void* const* d_in, const int* in_sizes, int n_in,
                              void* d_out, int out_size, void* d_ws, size_t ws_size,
                              hipStream_t stream) {
  const float* x       = (const float*)d_in[0];
  const int* edge_index= (const int*)d_in[1];
  const float* edge_attr=(const float*)d_in[2];
  const int* gtype     = (const int*)d_in[3];
  const int* batch     = (const int*)d_in[4];
  const float* glob    = (const float*)d_in[5];
  const float* W_embed = (const float*)d_in[6];
  const float* b_embed = (const float*)d_in[7];
  const float* g_eln   = (const float*)d_in[8];
  const float* b_eln   = (const float*)d_in[9];
  const float* gate_emb= (const float*)d_in[10];
  const float* W_msg   = (const float*)d_in[11];
  const float* b_msg   = (const float*)d_in[12];
  const float* W_upd   = (const float*)d_in[13];
  const float* b_upd   = (const float*)d_in[14];
  const float* W_gproj = (const float*)d_in[15];
  const float* b_gproj = (const float*)d_in[16];
  const float* g_gln   = (const float*)d_in[17];
  const float* b_gln   = (const float*)d_in[18];
  const float* W_c1    = (const float*)d_in[19];
  const float* b_c1    = (const float*)d_in[20];
  const float* g_cln   = (const float*)d_in[21];
  const float* b_cln   = (const float*)d_in[22];
  const float* W_c2    = (const float*)d_in[23];
  const float* b_c2    = (const float*)d_in[24];
  const float* W_head  = (const float*)d_in[25];
  const float* b_head  = (const float*)d_in[26];

  const int N = in_sizes[0] / 16;
  const int E = in_sizes[1] / 2;
  const int B = in_sizes[5] / 32;
  const int L = in_sizes[12] / 64;

  const int* src = edge_index;
  const int* dst = edge_index + E;

  char* ws = (char*)d_ws;
  size_t off = 0;
  auto alloc = [&](size_t bytes) -> void* {
    void* p = ws + off;
    off += (bytes + 255) & ~(size_t)255;
    return p;
  };
  float* h      = (float*)alloc((size_t)N * 64 * 4);
  float* hW     = (float*)alloc((size_t)N * 64 * 4);
  float* agg    = (float*)alloc((size_t)N * 64 * 4);
  float* geW    = (float*)alloc((size_t)L * 20 * 64 * 4);
  float* partials = (float*)alloc((size_t)B * PSPLIT * 2 * 64 * 4);
  int nC4 = (N + 3) / 4;
  int* counts   = (int*)alloc((size_t)nC4 * 16);
  int* row_ptr  = (int*)alloc((size_t)(N + 1) * 4);
  int* nextp    = (int*)alloc((size_t)N * 4);
  int nb = (N + 1023) / 1024;
  int* blocksums= (int*)alloc((size_t)nb * 4);
  int* perm     = (int*)alloc((size_t)E * 4);
  int* epack0   = (int*)alloc((size_t)E * 4);
  int* epack    = (int*)alloc((size_t)E * 4);
  float* eap    = (float*)alloc((size_t)E * 8 * 4);

  zero_kernel<<<(nC4 + 255) / 256, 256, 0, stream>>>((int4*)counts, nC4);
  count_pack_kernel<<<(E + 255) / 256, 256, 0, stream>>>(dst, src, gtype, counts, epack0, E);
  scan_phase1<<<nb, 256, 0, stream>>>(counts, row_ptr, blocksums, N);
  scan_phase2<<<1, 64, 0, stream>>>(blocksums, nb);
  scan_phase3<<<(N + 255) / 256, 256, 0, stream>>>(row_ptr, blocksums, nextp, N, E);
  {
    int nchunks = (E + SP_EDGES_PER_BLOCK - 1) / SP_EDGES_PER_BLOCK;
    scatter_perm_binned<<<nchunks * 8, 256, 0, stream>>>(dst, nextp, perm, E, N);
  }
  gather_build<<<(E + 255) / 256, 256, 0, stream>>>(perm, epack0, edge_attr, epack, eap, E);
  gew_kernel<<<(L * 20 + 3) / 4, 256, 0, stream>>>(gate_emb, W_msg, geW, L * 20);
  embed_kernel<<<(N + 3) / 4, 256, 0, stream>>>(x, W_embed, b_embed, g_eln, b_eln, h, N);

  nodelin_kernel<<<(N + 63) / 64, 256, 0, stream>>>(h, W_msg, hW, N);
  for (int l = 0; l < L; l++) {
    edge_kernel<<<(N + 3) / 4, 256, 0, stream>>>(hW, epack, eap, row_ptr,
                                                 W_msg + (size_t)l * 88 * 64, b_msg + (size_t)l * 64,
                                                 geW + (size_t)l * 20 * 64, agg, N);
    const float* W1next = (l + 1 < L) ? (W_msg + (size_t)(l + 1) * 88 * 64) : nullptr;
    update_fused_kernel<<<(N + 63) / 64, 256, 0, stream>>>(h, agg, W_upd + (size_t)l * 128 * 64,
                                                           b_upd + (size_t)l * 64, W1next, h, hW, N);
  }

  pool_partial<<<B * PSPLIT, 256, 0, stream>>>(h, batch, partials, N);
  pool_mlp_final<<<B, 256, 0, stream>>>(partials, batch, glob, W_gproj, b_gproj, g_gln, b_gln,
                                        W_c1, b_c1, g_cln, b_cln, W_c2, b_c2,
                                        W_head, b_head, (float*)d_out, N);
}